// Round 3
// baseline (1051.202 us; speedup 1.0000x reference)
//
#include <hip/hip_runtime.h>

typedef __attribute__((ext_vector_type(8))) __bf16 bf16x8;
typedef __attribute__((ext_vector_type(4))) float f32x4;

#define MFMA16(a, b, c) __builtin_amdgcn_mfma_f32_16x16x32_bf16((a), (b), (c), 0, 0, 0)

// async global->LDS, 16B per lane; LDS dest = wave-uniform base + lane*16
#define ASYNC16(g, l) __builtin_amdgcn_global_load_lds( \
    (const __attribute__((address_space(1))) unsigned int*)(g), \
    (__attribute__((address_space(3))) unsigned int*)(l), 16, 0, 0)

// fp32 -> bf16 RTNE via compiler cast (lowers to v_cvt_pk_bf16_f32; cheaper
// than the 4-op integer round -- m240: scalar casts beat hand-written packing)
__device__ __forceinline__ unsigned short f2bf(float f) {
    return __builtin_bit_cast(unsigned short, (__bf16)f);
}

__device__ __forceinline__ float wave_sum(float v) {
#pragma unroll
    for (int off = 32; off; off >>= 1) v += __shfl_xor(v, off, 64);
    return v;
}
__device__ __forceinline__ float wave_max(float v) {
#pragma unroll
    for (int off = 32; off; off >>= 1) v = fmaxf(v, __shfl_xor(v, off, 64));
    return v;
}

// tanh-form GELU: x*sigmoid(1.5957691x + 0.0713548x^3).
__device__ __forceinline__ float gelu_fast(float v) {
    float z = v * fmaf(v * v, 0.0713548162f, 1.5957691216f);
    float e = __expf(-z);
    return v * __builtin_amdgcn_rcpf(1.f + e);
}

// ---------------- fp32 -> bf16 cast (weights) ----------------
__global__ __launch_bounds__(256) void k_cvt(const float* __restrict__ s,
                                             unsigned short* __restrict__ d, int n) {
    int i = (blockIdx.x * 256 + threadIdx.x) * 4;
    if (i >= n) return;
    float4 v = *reinterpret_cast<const float4*>(s + i);
    ushort4 o;
    o.x = f2bf(v.x); o.y = f2bf(v.y); o.z = f2bf(v.z); o.w = f2bf(v.w);
    *reinterpret_cast<ushort4*>(d + i) = o;
}

// ---------------- LN1 over C=256, one wave per pixel -> bf16 ----------------
__global__ __launch_bounds__(256) void k_ln_bf(const float* __restrict__ x,
                                               const float* __restrict__ g,
                                               const float* __restrict__ b,
                                               unsigned short* __restrict__ o) {
    int wave = threadIdx.x >> 6, lane = threadIdx.x & 63;
    long long pix = (long long)blockIdx.x * 4 + wave;
    const float* row = x + pix * 256;
    float4 v = *reinterpret_cast<const float4*>(row + lane * 4);
    float s = v.x + v.y + v.z + v.w;
    float s2 = v.x * v.x + v.y * v.y + v.z * v.z + v.w * v.w;
    s = wave_sum(s); s2 = wave_sum(s2);
    float mean = s * (1.f / 256.f);
    float rstd = rsqrtf(s2 * (1.f / 256.f) - mean * mean + 1e-5f);
    float4 gg = *reinterpret_cast<const float4*>(g + lane * 4);
    float4 bb = *reinterpret_cast<const float4*>(b + lane * 4);
    ushort4 ov;
    ov.x = f2bf((v.x - mean) * rstd * gg.x + bb.x);
    ov.y = f2bf((v.y - mean) * rstd * gg.y + bb.y);
    ov.z = f2bf((v.z - mean) * rstd * gg.z + bb.z);
    ov.w = f2bf((v.w - mean) * rstd * gg.w + bb.w);
    *reinterpret_cast<ushort4*>(o + pix * 256 + lane * 4) = ov;
}

// ---------------- down-proj v2: split-K(16) 128x128 LDS-staged MFMA GEMM ----------------
__global__ __launch_bounds__(256, 2) void k_gemm_down2(const unsigned short* __restrict__ xln,
                                                       const unsigned short* __restrict__ wd,
                                                       float* __restrict__ part) {
    __shared__ alignas(16) unsigned short As[128 * 64];
    __shared__ alignas(16) unsigned short Bs[128 * 64];
    int wave = threadIdx.x >> 6, lane = threadIdx.x & 63, quad = lane >> 4, l16 = lane & 15;
    int mt = blockIdx.x * 128, nt = blockIdx.y * 128, k0 = blockIdx.z * 1024;
    int wm = wave & 1, wn = wave >> 1;
    int srow = wave * 32 + (lane >> 3);   // staging row (+ i*8)
    int schunk = lane & 7;                // 16B chunk within 128B row
    f32x4 acc[4][4] = {};
    for (int s = 0; s < 16; s++) {
        int kg = k0 + s * 64;
        int p0 = kg >> 11, p1 = (kg >> 8) & 7, cbase = kg & 255;
#pragma unroll
        for (int i = 0; i < 4; i++) {
            int row = srow + i * 8;
            int m = mt + row;
            int bb = m >> 10, r0 = (m >> 5) & 31, r1 = m & 31;
            int c = cbase + ((schunk ^ (row & 7)) << 3);
            const unsigned short* g = xln +
                ((((long long)(bb * 256 + r0 * 8 + p0)) * 256 + (r1 * 8 + p1)) << 8) + c;
            ASYNC16(g, &As[(wave * 32 + i * 8) * 64]);
        }
#pragma unroll
        for (int i = 0; i < 4; i++) {
            int row = srow + i * 8;
            int n = nt + row;
            const unsigned short* g = wd + (long long)n * 16384 + kg + ((schunk ^ (row & 7)) << 3);
            ASYNC16(g, &Bs[(wave * 32 + i * 8) * 64]);
        }
        __syncthreads();
#pragma unroll
        for (int sub = 0; sub < 2; sub++) {
            int c = sub * 4 + quad;
            bf16x8 af[4], bfr[4];
#pragma unroll
            for (int mi = 0; mi < 4; mi++) {
                int row = wm * 64 + mi * 16 + l16;
                af[mi] = *reinterpret_cast<const bf16x8*>(&As[row * 64 + ((c ^ (row & 7)) << 3)]);
            }
#pragma unroll
            for (int ni = 0; ni < 4; ni++) {
                int row = wn * 64 + ni * 16 + l16;
                bfr[ni] = *reinterpret_cast<const bf16x8*>(&Bs[row * 64 + ((c ^ (row & 7)) << 3)]);
            }
#pragma unroll
            for (int mi = 0; mi < 4; mi++)
#pragma unroll
                for (int ni = 0; ni < 4; ni++)
                    acc[mi][ni] = MFMA16(af[mi], bfr[ni], acc[mi][ni]);
        }
        __syncthreads();
    }
    float* pb = part + (long long)blockIdx.z * 524288;
#pragma unroll
    for (int mi = 0; mi < 4; mi++)
#pragma unroll
        for (int ni = 0; ni < 4; ni++) {
            int n = nt + wn * 64 + ni * 16 + l16;
#pragma unroll
            for (int r = 0; r < 4; r++) {
                int m = mt + wm * 64 + mi * 16 + quad * 4 + r;
                pb[(long long)m * 256 + n] = acc[mi][ni][r];
            }
        }
}

// ---------------- split-K reduce + bias + bf16 ----------------
__global__ __launch_bounds__(256) void k_red(const float* __restrict__ part,
                                             const float* __restrict__ bd,
                                             unsigned short* __restrict__ y) {
    int i = (blockIdx.x * 256 + threadIdx.x) * 4;
    float4 s = {0.f, 0.f, 0.f, 0.f};
#pragma unroll
    for (int p = 0; p < 16; p++) {
        float4 v = *reinterpret_cast<const float4*>(part + (long long)p * 524288 + i);
        s.x += v.x; s.y += v.y; s.z += v.z; s.w += v.w;
    }
    int n = i & 255;
    float4 bb = *reinterpret_cast<const float4*>(bd + n);
    ushort4 o;
    o.x = f2bf(s.x + bb.x); o.y = f2bf(s.y + bb.y);
    o.z = f2bf(s.z + bb.z); o.w = f2bf(s.w + bb.w);
    *reinterpret_cast<ushort4*>(y + i) = o;
}

// ---------------- qkv: [2048,256]x[768,256]^T, scatter to q, k, v^T (bf16) ----------------
__global__ __launch_bounds__(256) void k_gemm_qkv(const unsigned short* __restrict__ yd,
                                                  const unsigned short* __restrict__ wq,
                                                  const float* __restrict__ bq,
                                                  unsigned short* __restrict__ q,
                                                  unsigned short* __restrict__ k,
                                                  unsigned short* __restrict__ vT) {
    int wave = threadIdx.x >> 6, lane = threadIdx.x & 63, quad = lane >> 4, l16 = lane & 15;
    int m0 = blockIdx.x * 64 + wave * 16;
    int n0 = blockIdx.y * 64;
    const unsigned short* arow = yd + (long long)(m0 + l16) * 256;
    f32x4 acc[4] = {};
    for (int kb = 0; kb < 256; kb += 32) {
        bf16x8 a = *reinterpret_cast<const bf16x8*>(arow + kb + quad * 8);
#pragma unroll
        for (int ni = 0; ni < 4; ni++) {
            bf16x8 bv = *reinterpret_cast<const bf16x8*>(wq + (long long)(n0 + ni * 16 + l16) * 256 + kb + quad * 8);
            acc[ni] = MFMA16(a, bv, acc[ni]);
        }
    }
#pragma unroll
    for (int ni = 0; ni < 4; ni++) {
        int n = n0 + ni * 16 + l16;
        float bias = bq[n];
        int t = n >> 8, h = (n >> 5) & 7, d = n & 31;
#pragma unroll
        for (int r = 0; r < 4; r++) {
            int m = m0 + quad * 4 + r;
            int bh = ((m >> 10) << 3) | h;
            int l = m & 1023;
            unsigned short val = f2bf(acc[ni][r] + bias);
            if (t == 0)      q[((long long)bh * 1024 + l) * 32 + d] = val;
            else if (t == 1) k[((long long)bh * 1024 + l) * 32 + d] = val;
            else             vT[((long long)bh * 32 + d) * 1024 + l] = val;
        }
    }
}

// ---------------- scores: S = scale*q@k^T + rpe (fp32) ----------------
__global__ __launch_bounds__(256) void k_score(const unsigned short* __restrict__ q,
                                               const unsigned short* __restrict__ k,
                                               const float* __restrict__ rpe,
                                               float* __restrict__ S) {
    int wave = threadIdx.x >> 6, lane = threadIdx.x & 63, quad = lane >> 4, l16 = lane & 15;
    int m0 = blockIdx.x * 64 + wave * 16;
    int n0 = blockIdx.y * 64;
    int bh = blockIdx.z;
    const unsigned short* qb = q + (long long)bh * 1024 * 32;
    const unsigned short* kb = k + (long long)bh * 1024 * 32;
    bf16x8 a = *reinterpret_cast<const bf16x8*>(qb + (m0 + l16) * 32 + quad * 8);
    f32x4 acc[4] = {};
#pragma unroll
    for (int ni = 0; ni < 4; ni++) {
        bf16x8 bv = *reinterpret_cast<const bf16x8*>(kb + (n0 + ni * 16 + l16) * 32 + quad * 8);
        acc[ni] = MFMA16(a, bv, acc[ni]);
    }
    int h = bh & 7;
    const float scale = 0.17677669529663687f;  // 1/sqrt(32)
    float* Sb = S + (long long)bh * 1024 * 1024;
#pragma unroll
    for (int ni = 0; ni < 4; ni++) {
        int kj = n0 + ni * 16 + l16;
        int kj0 = kj >> 5, kj1 = kj & 31;
#pragma unroll
        for (int r = 0; r < 4; r++) {
            int qi = m0 + quad * 4 + r;
            int qi0 = qi >> 5, qi1 = qi & 31;
            int idx = (qi0 - kj0 + 31) * 63 + (qi1 - kj1 + 31);
            Sb[(long long)qi * 1024 + kj] = acc[ni][r] * scale + rpe[idx * 8 + h];
        }
    }
}

// ---------------- row softmax over 1024, one wave per row -> bf16 P ----------------
__global__ __launch_bounds__(256) void k_softmax(const float* __restrict__ S,
                                                 unsigned short* __restrict__ P) {
    int wave = threadIdx.x >> 6, lane = threadIdx.x & 63;
    long long row = (long long)blockIdx.x * 4 + wave;
    const float* s = S + row * 1024;
    float4 v[4];
    float mx = -3.4e38f;
#pragma unroll
    for (int i = 0; i < 4; i++) {
        v[i] = *reinterpret_cast<const float4*>(s + i * 256 + lane * 4);
        mx = fmaxf(mx, fmaxf(fmaxf(v[i].x, v[i].y), fmaxf(v[i].z, v[i].w)));
    }
    mx = wave_max(mx);
    float sum = 0.f;
#pragma unroll
    for (int i = 0; i < 4; i++) {
        v[i].x = __expf(v[i].x - mx); v[i].y = __expf(v[i].y - mx);
        v[i].z = __expf(v[i].z - mx); v[i].w = __expf(v[i].w - mx);
        sum += v[i].x + v[i].y + v[i].z + v[i].w;
    }
    sum = wave_sum(sum);
    float inv = 1.f / sum;
#pragma unroll
    for (int i = 0; i < 4; i++) {
        ushort4 o;
        o.x = f2bf(v[i].x * inv); o.y = f2bf(v[i].y * inv);
        o.z = f2bf(v[i].z * inv); o.w = f2bf(v[i].w * inv);
        *reinterpret_cast<ushort4*>(P + row * 1024 + i * 256 + lane * 4) = o;
    }
}

// ---------------- O = P@V per (b,h), K=1024 -> token-major obf ----------------
__global__ __launch_bounds__(256) void k_pv(const unsigned short* __restrict__ P,
                                            const unsigned short* __restrict__ vT,
                                            unsigned short* __restrict__ o) {
    int wave = threadIdx.x >> 6, lane = threadIdx.x & 63, quad = lane >> 4, l16 = lane & 15;
    int m0 = blockIdx.x * 64 + wave * 16;
    int bh = blockIdx.y;
    const unsigned short* Pb = P + (long long)bh * 1024 * 1024;
    const unsigned short* vb = vT + (long long)bh * 32 * 1024;
    f32x4 acc[2] = {};
    for (int kb = 0; kb < 1024; kb += 32) {
        bf16x8 a = *reinterpret_cast<const bf16x8*>(Pb + (long long)(m0 + l16) * 1024 + kb + quad * 8);
#pragma unroll
        for (int ni = 0; ni < 2; ni++) {
            bf16x8 bv = *reinterpret_cast<const bf16x8*>(vb + (long long)(ni * 16 + l16) * 1024 + kb + quad * 8);
            acc[ni] = MFMA16(a, bv, acc[ni]);
        }
    }
    int b_ = bh >> 3, h = bh & 7;
#pragma unroll
    for (int ni = 0; ni < 2; ni++) {
        int d = ni * 16 + l16;
#pragma unroll
        for (int r = 0; r < 4; r++) {
            int l = m0 + quad * 4 + r;
            o[(long long)(b_ * 1024 + l) * 256 + h * 32 + d] = f2bf(acc[ni][r]);
        }
    }
}

// ---------------- proj: [2048,256]x[256,256]^T -> bf16 ----------------
__global__ __launch_bounds__(256) void k_gemm_proj(const unsigned short* __restrict__ a_,
                                                   const unsigned short* __restrict__ w,
                                                   const float* __restrict__ bias,
                                                   unsigned short* __restrict__ y) {
    int wave = threadIdx.x >> 6, lane = threadIdx.x & 63, quad = lane >> 4, l16 = lane & 15;
    int m0 = blockIdx.x * 64 + wave * 16;
    int n0 = blockIdx.y * 64;
    const unsigned short* arow = a_ + (long long)(m0 + l16) * 256;
    f32x4 acc[4] = {};
    for (int kb = 0; kb < 256; kb += 32) {
        bf16x8 a = *reinterpret_cast<const bf16x8*>(arow + kb + quad * 8);
#pragma unroll
        for (int ni = 0; ni < 4; ni++) {
            bf16x8 bv = *reinterpret_cast<const bf16x8*>(w + (long long)(n0 + ni * 16 + l16) * 256 + kb + quad * 8);
            acc[ni] = MFMA16(a, bv, acc[ni]);
        }
    }
#pragma unroll
    for (int ni = 0; ni < 4; ni++) {
        int n = n0 + ni * 16 + l16;
        float bv = bias[n];
#pragma unroll
        for (int r = 0; r < 4; r++)
            y[(long long)(m0 + quad * 4 + r) * 256 + n] = f2bf(acc[ni][r] + bv);
    }
}

// ---------------- up-proj + fold + residual: x2 = x + fold(oproj @ w_up^T + b_up) ----------------
__global__ __launch_bounds__(256) void k_up_fold(const unsigned short* __restrict__ a_,
                                                 const unsigned short* __restrict__ w,
                                                 const float* __restrict__ bup,
                                                 const float* __restrict__ x,
                                                 float* __restrict__ out) {
    int wave = threadIdx.x >> 6, lane = threadIdx.x & 63, quad = lane >> 4, l16 = lane & 15;
    int m0 = blockIdx.x * 64 + wave * 16;
    int n0 = blockIdx.y * 64;
    const unsigned short* arow = a_ + (long long)(m0 + l16) * 256;
    f32x4 acc[4] = {};
    for (int kb = 0; kb < 256; kb += 32) {
        bf16x8 a = *reinterpret_cast<const bf16x8*>(arow + kb + quad * 8);
#pragma unroll
        for (int ni = 0; ni < 4; ni++) {
            bf16x8 bv = *reinterpret_cast<const bf16x8*>(w + (long long)(n0 + ni * 16 + l16) * 256 + kb + quad * 8);
            acc[ni] = MFMA16(a, bv, acc[ni]);
        }
    }
#pragma unroll
    for (int ni = 0; ni < 4; ni++) {
        int n = n0 + ni * 16 + l16;
        float bias = bup[n];
        int p0 = n >> 11, p1 = (n >> 8) & 7, c = n & 255;
#pragma unroll
        for (int r = 0; r < 4; r++) {
            int m = m0 + quad * 4 + r;
            int bb = m >> 10, r0 = (m >> 5) & 31, r1 = m & 31;
            long long addr = ((long long)bb << 24) + (long long)(r0 * 8 + p0) * 65536 + (r1 * 8 + p1) * 256 + c;
            out[addr] = x[addr] + acc[ni][r] + bias;
        }
    }
}

// ---------------- fused LN2 + MLP + residual, in-place on d_out ----------------
// v4: revert the v3 phase-merge (it spilled: ~130 live regs -> scratch ->
// FETCH 137->660MB, 1.8x slower). Keep the clean fc1->gelu->fc2 convoy but
// raise occupancy 16->24 waves/CU: MID processed in 8 chunks of 128, so
// Hc shrinks to 64x128 bf16 (16KB); LDS = 32+16 = 48KB -> 3 blocks/CU.
// fc1 per-wave slice is 16 cols -> acc1[4] (16 regs); total live regs
// ~75-80 incl AGPR accumulators, fits the 85-reg budget of 6 waves/SIMD
// (__launch_bounds__(512,6)). The third co-resident block fills the
// barrier-drain stalls the 2-block version spent 55% of its cycles in.
// Note: SQ_LDS_BANK_CONFLICT here is structural (4/ds_read_b128,
// layout-independent -- measured exactly 2^23/2^24 across 3 layouts);
// both the XOR-swizzled Aln and 256B-row Hc reads are true <=2-way.
#define SWZA(r, c) ((((r) << 9) + ((c) << 1)) ^ (((r) & 7) << 4))
#define SWZH(r, c) ((((r) << 8) + ((c) << 1)) ^ (((r) & 7) << 4))
__global__ __launch_bounds__(512, 6) void k_mlp(float* __restrict__ xio,
                                                const float* __restrict__ g2,
                                                const float* __restrict__ b2,
                                                const unsigned short* __restrict__ w1,
                                                const float* __restrict__ bfc1,
                                                const unsigned short* __restrict__ w2,
                                                const float* __restrict__ bfc2) {
    __shared__ alignas(16) char Aln[64 * 512];
    __shared__ alignas(16) char Hc[64 * 256];
    int wave = threadIdx.x >> 6, lane = threadIdx.x & 63, quad = lane >> 4, l16 = lane & 15;
    long long m0 = (long long)blockIdx.x * 64;
    float4 gg = *reinterpret_cast<const float4*>(g2 + lane * 4);
    float4 bb = *reinterpret_cast<const float4*>(b2 + lane * 4);
#pragma unroll
    for (int i = 0; i < 8; i++) {
        int p = wave * 8 + i;
        float4 v = *reinterpret_cast<const float4*>(xio + (m0 + p) * 256 + lane * 4);
        float s = v.x + v.y + v.z + v.w;
        float s2 = v.x * v.x + v.y * v.y + v.z * v.z + v.w * v.w;
        s = wave_sum(s); s2 = wave_sum(s2);
        float mean = s * (1.f / 256.f);
        float rstd = rsqrtf(s2 * (1.f / 256.f) - mean * mean + 1e-5f);
        ushort4 o;
        o.x = f2bf((v.x - mean) * rstd * gg.x + bb.x);
        o.y = f2bf((v.y - mean) * rstd * gg.y + bb.y);
        o.z = f2bf((v.z - mean) * rstd * gg.z + bb.z);
        o.w = f2bf((v.w - mean) * rstd * gg.w + bb.w);
        *reinterpret_cast<ushort4*>(Aln + SWZA(p, lane * 4)) = o;  // XOR bits>=4 keep 8B align
    }
    __syncthreads();
    f32x4 acc2[4][2] = {};
    for (int ch = 0; ch < 8; ch++) {
        f32x4 acc1[4] = {};
        const unsigned short* w1c = w1 + (long long)(ch * 128 + wave * 16 + l16) * 256;
#pragma unroll
        for (int kb = 0; kb < 256; kb += 32) {
            bf16x8 bv = *reinterpret_cast<const bf16x8*>(w1c + kb + quad * 8);
#pragma unroll
            for (int mi = 0; mi < 4; mi++) {
                bf16x8 aa = *reinterpret_cast<const bf16x8*>(Aln + SWZA(mi * 16 + l16, kb + quad * 8));
                acc1[mi] = MFMA16(aa, bv, acc1[mi]);
            }
        }
        {
            int n = ch * 128 + wave * 16 + l16;
            float bias = bfc1[n];
            int col = wave * 16 + l16;
#pragma unroll
            for (int mi = 0; mi < 4; mi++)
#pragma unroll
                for (int r = 0; r < 4; r++)
                    *reinterpret_cast<unsigned short*>(Hc + SWZH(mi * 16 + quad * 4 + r, col)) =
                        f2bf(gelu_fast(acc1[mi][r] + bias));
        }
        __syncthreads();
        const unsigned short* w2c = w2 + (long long)(wave * 32) * 1024 + ch * 128;
#pragma unroll
        for (int kb = 0; kb < 128; kb += 32) {
            bf16x8 ah[4];
#pragma unroll
            for (int mi = 0; mi < 4; mi++)
                ah[mi] = *reinterpret_cast<const bf16x8*>(Hc + SWZH(mi * 16 + l16, kb + quad * 8));
#pragma unroll
            for (int ni = 0; ni < 2; ni++) {
                bf16x8 bv = *reinterpret_cast<const bf16x8*>(w2c + (long long)(ni * 16 + l16) * 1024 + kb + quad * 8);
#pragma unroll
                for (int mi = 0; mi < 4; mi++)
                    acc2[mi][ni] = MFMA16(ah[mi], bv, acc2[mi][ni]);
            }
        }
        __syncthreads();  // Hc dead; safe to overwrite next chunk
    }
#pragma unroll
    for (int ni = 0; ni < 2; ni++) {
        int n = wave * 32 + ni * 16 + l16;
        float bias = bfc2[n];
#pragma unroll
        for (int mi = 0; mi < 4; mi++) {
#pragma unroll
            for (int r = 0; r < 4; r++) {
                long long row = m0 + mi * 16 + quad * 4 + r;
                float xv = xio[row * 256 + n];
                xio[row * 256 + n] = xv + acc2[mi][ni][r] + bias;
            }
        }
    }
}

extern "C" void kernel_launch(void* const* d_in, const int* in_sizes, int n_in,
                              void* d_out, int out_size, void* d_ws, size_t ws_size,
                              hipStream_t stream) {
    const float* x      = (const float*)d_in[0];
    const float* ln1_g  = (const float*)d_in[1];
    const float* ln1_b  = (const float*)d_in[2];
    const float* ln2_g  = (const float*)d_in[3];
    const float* ln2_b  = (const float*)d_in[4];
    const float* rpe    = (const float*)d_in[5];
    const float* w_down = (const float*)d_in[6];
    const float* b_down = (const float*)d_in[7];
    const float* w_up   = (const float*)d_in[8];
    const float* b_up   = (const float*)d_in[9];
    const float* w_qkv  = (const float*)d_in[10];
    const float* b_qkv  = (const float*)d_in[11];
    const float* w_proj = (const float*)d_in[12];
    const float* b_proj = (const float*)d_in[13];
    const float* w_fc1  = (const float*)d_in[14];
    const float* b_fc1  = (const float*)d_in[15];
    const float* w_fc2  = (const float*)d_in[16];
    const float* b_fc2  = (const float*)d_in[17];
    float* out = (float*)d_out;

    char* wp = (char*)d_ws;
    auto alloc = [&](size_t bytes) { void* p = (void*)wp; wp += (bytes + 255) & ~(size_t)255; return p; };
    unsigned short* wdown_bf = (unsigned short*)alloc(4194304 * 2);
    unsigned short* wup_bf   = (unsigned short*)alloc(4194304 * 2);
    unsigned short* wqkv_bf  = (unsigned short*)alloc(196608 * 2);
    unsigned short* wproj_bf = (unsigned short*)alloc(65536 * 2);
    unsigned short* wfc1_bf  = (unsigned short*)alloc(262144 * 2);
    unsigned short* wfc2_bf  = (unsigned short*)alloc(262144 * 2);
    unsigned short* ydown    = (unsigned short*)alloc(524288 * 2);
    unsigned short* qb       = (unsigned short*)alloc(524288 * 2);
    unsigned short* kb       = (unsigned short*)alloc(524288 * 2);
    unsigned short* vT       = (unsigned short*)alloc(524288 * 2);
    unsigned short* obf      = (unsigned short*)alloc(524288 * 2);
    unsigned short* oproj    = (unsigned short*)alloc(524288 * 2);

    // Big temporaries live inside d_out (134.2 MB); all dead before k_up_fold
    // overwrites the whole buffer with x2.
    unsigned short* xln = (unsigned short*)d_out;
    float* S            = (float*)d_out;
    unsigned short* P   = (unsigned short*)((char*)d_out + 67108864);
    float* part         = (float*)((char*)d_out + 100663296);

    k_cvt<<<4096, 256, 0, stream>>>(w_down, wdown_bf, 4194304);
    k_cvt<<<4096, 256, 0, stream>>>(w_up, wup_bf, 4194304);
    k_cvt<<<192, 256, 0, stream>>>(w_qkv, wqkv_bf, 196608);
    k_cvt<<<64, 256, 0, stream>>>(w_proj, wproj_bf, 65536);
    k_cvt<<<256, 256, 0, stream>>>(w_fc1, wfc1_bf, 262144);
    k_cvt<<<256, 256, 0, stream>>>(w_fc2, wfc2_bf, 262144);

    k_ln_bf<<<32768, 256, 0, stream>>>(x, ln1_g, ln1_b, xln);
    k_gemm_down2<<<dim3(16, 2, 16), 256, 0, stream>>>(xln, wdown_bf, part);
    k_red<<<512, 256, 0, stream>>>(part, b_down, ydown);
    k_gemm_qkv<<<dim3(32, 12), 256, 0, stream>>>(ydown, wqkv_bf, b_qkv, qb, kb, vT);
    k_score<<<dim3(16, 16, 16), 256, 0, stream>>>(qb, kb, rpe, S);
    k_softmax<<<4096, 256, 0, stream>>>(S, P);
    k_pv<<<dim3(16, 16), 256, 0, stream>>>(P, vT, obf);
    k_gemm_proj<<<dim3(32, 4), 256, 0, stream>>>(obf, wproj_bf, b_proj, oproj);
    k_up_fold<<<dim3(32, 256), 256, 0, stream>>>(oproj, wup_bf, b_up, x, out);
    k_mlp<<<2048, 512, 0, stream>>>(out, ln2_g, ln2_b, wfc1_bf, b_fc1, wfc2_bf, b_fc2);
}

// Round 4
// 685.090 us; speedup vs baseline: 1.5344x; 1.5344x over previous
//
#include <hip/hip_runtime.h>

typedef __attribute__((ext_vector_type(8))) __bf16 bf16x8;
typedef __attribute__((ext_vector_type(4))) float f32x4;

#define MFMA16(a, b, c) __builtin_amdgcn_mfma_f32_16x16x32_bf16((a), (b), (c), 0, 0, 0)

// async global->LDS, 16B per lane; LDS dest = wave-uniform base + lane*16
#define ASYNC16(g, l) __builtin_amdgcn_global_load_lds( \
    (const __attribute__((address_space(1))) unsigned int*)(g), \
    (__attribute__((address_space(3))) unsigned int*)(l), 16, 0, 0)

// fp32 -> bf16 RTNE via compiler cast (lowers to v_cvt_pk_bf16_f32; cheaper
// than the 4-op integer round -- m240: scalar casts beat hand-written packing)
__device__ __forceinline__ unsigned short f2bf(float f) {
    return __builtin_bit_cast(unsigned short, (__bf16)f);
}

__device__ __forceinline__ float wave_sum(float v) {
#pragma unroll
    for (int off = 32; off; off >>= 1) v += __shfl_xor(v, off, 64);
    return v;
}
__device__ __forceinline__ float wave_max(float v) {
#pragma unroll
    for (int off = 32; off; off >>= 1) v = fmaxf(v, __shfl_xor(v, off, 64));
    return v;
}

// tanh-form GELU: x*sigmoid(1.5957691x + 0.0713548x^3).
__device__ __forceinline__ float gelu_fast(float v) {
    float z = v * fmaf(v * v, 0.0713548162f, 1.5957691216f);
    float e = __expf(-z);
    return v * __builtin_amdgcn_rcpf(1.f + e);
}

// ---------------- fp32 -> bf16 cast (weights) ----------------
__global__ __launch_bounds__(256) void k_cvt(const float* __restrict__ s,
                                             unsigned short* __restrict__ d, int n) {
    int i = (blockIdx.x * 256 + threadIdx.x) * 4;
    if (i >= n) return;
    float4 v = *reinterpret_cast<const float4*>(s + i);
    ushort4 o;
    o.x = f2bf(v.x); o.y = f2bf(v.y); o.z = f2bf(v.z); o.w = f2bf(v.w);
    *reinterpret_cast<ushort4*>(d + i) = o;
}

// ---------------- LN1 over C=256, one wave per pixel -> bf16 ----------------
__global__ __launch_bounds__(256) void k_ln_bf(const float* __restrict__ x,
                                               const float* __restrict__ g,
                                               const float* __restrict__ b,
                                               unsigned short* __restrict__ o) {
    int wave = threadIdx.x >> 6, lane = threadIdx.x & 63;
    long long pix = (long long)blockIdx.x * 4 + wave;
    const float* row = x + pix * 256;
    float4 v = *reinterpret_cast<const float4*>(row + lane * 4);
    float s = v.x + v.y + v.z + v.w;
    float s2 = v.x * v.x + v.y * v.y + v.z * v.z + v.w * v.w;
    s = wave_sum(s); s2 = wave_sum(s2);
    float mean = s * (1.f / 256.f);
    float rstd = rsqrtf(s2 * (1.f / 256.f) - mean * mean + 1e-5f);
    float4 gg = *reinterpret_cast<const float4*>(g + lane * 4);
    float4 bb = *reinterpret_cast<const float4*>(b + lane * 4);
    ushort4 ov;
    ov.x = f2bf((v.x - mean) * rstd * gg.x + bb.x);
    ov.y = f2bf((v.y - mean) * rstd * gg.y + bb.y);
    ov.z = f2bf((v.z - mean) * rstd * gg.z + bb.z);
    ov.w = f2bf((v.w - mean) * rstd * gg.w + bb.w);
    *reinterpret_cast<ushort4*>(o + pix * 256 + lane * 4) = ov;
}

// ---------------- down-proj v2: split-K(16) 128x128 LDS-staged MFMA GEMM ----------------
__global__ __launch_bounds__(256, 2) void k_gemm_down2(const unsigned short* __restrict__ xln,
                                                       const unsigned short* __restrict__ wd,
                                                       float* __restrict__ part) {
    __shared__ alignas(16) unsigned short As[128 * 64];
    __shared__ alignas(16) unsigned short Bs[128 * 64];
    int wave = threadIdx.x >> 6, lane = threadIdx.x & 63, quad = lane >> 4, l16 = lane & 15;
    int mt = blockIdx.x * 128, nt = blockIdx.y * 128, k0 = blockIdx.z * 1024;
    int wm = wave & 1, wn = wave >> 1;
    int srow = wave * 32 + (lane >> 3);   // staging row (+ i*8)
    int schunk = lane & 7;                // 16B chunk within 128B row
    f32x4 acc[4][4] = {};
    for (int s = 0; s < 16; s++) {
        int kg = k0 + s * 64;
        int p0 = kg >> 11, p1 = (kg >> 8) & 7, cbase = kg & 255;
#pragma unroll
        for (int i = 0; i < 4; i++) {
            int row = srow + i * 8;
            int m = mt + row;
            int bb = m >> 10, r0 = (m >> 5) & 31, r1 = m & 31;
            int c = cbase + ((schunk ^ (row & 7)) << 3);
            const unsigned short* g = xln +
                ((((long long)(bb * 256 + r0 * 8 + p0)) * 256 + (r1 * 8 + p1)) << 8) + c;
            ASYNC16(g, &As[(wave * 32 + i * 8) * 64]);
        }
#pragma unroll
        for (int i = 0; i < 4; i++) {
            int row = srow + i * 8;
            int n = nt + row;
            const unsigned short* g = wd + (long long)n * 16384 + kg + ((schunk ^ (row & 7)) << 3);
            ASYNC16(g, &Bs[(wave * 32 + i * 8) * 64]);
        }
        __syncthreads();
#pragma unroll
        for (int sub = 0; sub < 2; sub++) {
            int c = sub * 4 + quad;
            bf16x8 af[4], bfr[4];
#pragma unroll
            for (int mi = 0; mi < 4; mi++) {
                int row = wm * 64 + mi * 16 + l16;
                af[mi] = *reinterpret_cast<const bf16x8*>(&As[row * 64 + ((c ^ (row & 7)) << 3)]);
            }
#pragma unroll
            for (int ni = 0; ni < 4; ni++) {
                int row = wn * 64 + ni * 16 + l16;
                bfr[ni] = *reinterpret_cast<const bf16x8*>(&Bs[row * 64 + ((c ^ (row & 7)) << 3)]);
            }
#pragma unroll
            for (int mi = 0; mi < 4; mi++)
#pragma unroll
                for (int ni = 0; ni < 4; ni++)
                    acc[mi][ni] = MFMA16(af[mi], bfr[ni], acc[mi][ni]);
        }
        __syncthreads();
    }
    float* pb = part + (long long)blockIdx.z * 524288;
#pragma unroll
    for (int mi = 0; mi < 4; mi++)
#pragma unroll
        for (int ni = 0; ni < 4; ni++) {
            int n = nt + wn * 64 + ni * 16 + l16;
#pragma unroll
            for (int r = 0; r < 4; r++) {
                int m = mt + wm * 64 + mi * 16 + quad * 4 + r;
                pb[(long long)m * 256 + n] = acc[mi][ni][r];
            }
        }
}

// ---------------- split-K reduce + bias + bf16 ----------------
__global__ __launch_bounds__(256) void k_red(const float* __restrict__ part,
                                             const float* __restrict__ bd,
                                             unsigned short* __restrict__ y) {
    int i = (blockIdx.x * 256 + threadIdx.x) * 4;
    float4 s = {0.f, 0.f, 0.f, 0.f};
#pragma unroll
    for (int p = 0; p < 16; p++) {
        float4 v = *reinterpret_cast<const float4*>(part + (long long)p * 524288 + i);
        s.x += v.x; s.y += v.y; s.z += v.z; s.w += v.w;
    }
    int n = i & 255;
    float4 bb = *reinterpret_cast<const float4*>(bd + n);
    ushort4 o;
    o.x = f2bf(s.x + bb.x); o.y = f2bf(s.y + bb.y);
    o.z = f2bf(s.z + bb.z); o.w = f2bf(s.w + bb.w);
    *reinterpret_cast<ushort4*>(y + i) = o;
}

// ---------------- qkv: [2048,256]x[768,256]^T, scatter to q, k, v^T (bf16) ----------------
__global__ __launch_bounds__(256) void k_gemm_qkv(const unsigned short* __restrict__ yd,
                                                  const unsigned short* __restrict__ wq,
                                                  const float* __restrict__ bq,
                                                  unsigned short* __restrict__ q,
                                                  unsigned short* __restrict__ k,
                                                  unsigned short* __restrict__ vT) {
    int wave = threadIdx.x >> 6, lane = threadIdx.x & 63, quad = lane >> 4, l16 = lane & 15;
    int m0 = blockIdx.x * 64 + wave * 16;
    int n0 = blockIdx.y * 64;
    const unsigned short* arow = yd + (long long)(m0 + l16) * 256;
    f32x4 acc[4] = {};
    for (int kb = 0; kb < 256; kb += 32) {
        bf16x8 a = *reinterpret_cast<const bf16x8*>(arow + kb + quad * 8);
#pragma unroll
        for (int ni = 0; ni < 4; ni++) {
            bf16x8 bv = *reinterpret_cast<const bf16x8*>(wq + (long long)(n0 + ni * 16 + l16) * 256 + kb + quad * 8);
            acc[ni] = MFMA16(a, bv, acc[ni]);
        }
    }
#pragma unroll
    for (int ni = 0; ni < 4; ni++) {
        int n = n0 + ni * 16 + l16;
        float bias = bq[n];
        int t = n >> 8, h = (n >> 5) & 7, d = n & 31;
#pragma unroll
        for (int r = 0; r < 4; r++) {
            int m = m0 + quad * 4 + r;
            int bh = ((m >> 10) << 3) | h;
            int l = m & 1023;
            unsigned short val = f2bf(acc[ni][r] + bias);
            if (t == 0)      q[((long long)bh * 1024 + l) * 32 + d] = val;
            else if (t == 1) k[((long long)bh * 1024 + l) * 32 + d] = val;
            else             vT[((long long)bh * 32 + d) * 1024 + l] = val;
        }
    }
}

// ---------------- scores: S = scale*q@k^T + rpe (fp32) ----------------
__global__ __launch_bounds__(256) void k_score(const unsigned short* __restrict__ q,
                                               const unsigned short* __restrict__ k,
                                               const float* __restrict__ rpe,
                                               float* __restrict__ S) {
    int wave = threadIdx.x >> 6, lane = threadIdx.x & 63, quad = lane >> 4, l16 = lane & 15;
    int m0 = blockIdx.x * 64 + wave * 16;
    int n0 = blockIdx.y * 64;
    int bh = blockIdx.z;
    const unsigned short* qb = q + (long long)bh * 1024 * 32;
    const unsigned short* kb = k + (long long)bh * 1024 * 32;
    bf16x8 a = *reinterpret_cast<const bf16x8*>(qb + (m0 + l16) * 32 + quad * 8);
    f32x4 acc[4] = {};
#pragma unroll
    for (int ni = 0; ni < 4; ni++) {
        bf16x8 bv = *reinterpret_cast<const bf16x8*>(kb + (n0 + ni * 16 + l16) * 32 + quad * 8);
        acc[ni] = MFMA16(a, bv, acc[ni]);
    }
    int h = bh & 7;
    const float scale = 0.17677669529663687f;  // 1/sqrt(32)
    float* Sb = S + (long long)bh * 1024 * 1024;
#pragma unroll
    for (int ni = 0; ni < 4; ni++) {
        int kj = n0 + ni * 16 + l16;
        int kj0 = kj >> 5, kj1 = kj & 31;
#pragma unroll
        for (int r = 0; r < 4; r++) {
            int qi = m0 + quad * 4 + r;
            int qi0 = qi >> 5, qi1 = qi & 31;
            int idx = (qi0 - kj0 + 31) * 63 + (qi1 - kj1 + 31);
            Sb[(long long)qi * 1024 + kj] = acc[ni][r] * scale + rpe[idx * 8 + h];
        }
    }
}

// ---------------- row softmax over 1024, one wave per row -> bf16 P ----------------
__global__ __launch_bounds__(256) void k_softmax(const float* __restrict__ S,
                                                 unsigned short* __restrict__ P) {
    int wave = threadIdx.x >> 6, lane = threadIdx.x & 63;
    long long row = (long long)blockIdx.x * 4 + wave;
    const float* s = S + row * 1024;
    float4 v[4];
    float mx = -3.4e38f;
#pragma unroll
    for (int i = 0; i < 4; i++) {
        v[i] = *reinterpret_cast<const float4*>(s + i * 256 + lane * 4);
        mx = fmaxf(mx, fmaxf(fmaxf(v[i].x, v[i].y), fmaxf(v[i].z, v[i].w)));
    }
    mx = wave_max(mx);
    float sum = 0.f;
#pragma unroll
    for (int i = 0; i < 4; i++) {
        v[i].x = __expf(v[i].x - mx); v[i].y = __expf(v[i].y - mx);
        v[i].z = __expf(v[i].z - mx); v[i].w = __expf(v[i].w - mx);
        sum += v[i].x + v[i].y + v[i].z + v[i].w;
    }
    sum = wave_sum(sum);
    float inv = 1.f / sum;
#pragma unroll
    for (int i = 0; i < 4; i++) {
        ushort4 o;
        o.x = f2bf(v[i].x * inv); o.y = f2bf(v[i].y * inv);
        o.z = f2bf(v[i].z * inv); o.w = f2bf(v[i].w * inv);
        *reinterpret_cast<ushort4*>(P + row * 1024 + i * 256 + lane * 4) = o;
    }
}

// ---------------- O = P@V per (b,h), K=1024 -> token-major obf ----------------
__global__ __launch_bounds__(256) void k_pv(const unsigned short* __restrict__ P,
                                            const unsigned short* __restrict__ vT,
                                            unsigned short* __restrict__ o) {
    int wave = threadIdx.x >> 6, lane = threadIdx.x & 63, quad = lane >> 4, l16 = lane & 15;
    int m0 = blockIdx.x * 64 + wave * 16;
    int bh = blockIdx.y;
    const unsigned short* Pb = P + (long long)bh * 1024 * 1024;
    const unsigned short* vb = vT + (long long)bh * 32 * 1024;
    f32x4 acc[2] = {};
    for (int kb = 0; kb < 1024; kb += 32) {
        bf16x8 a = *reinterpret_cast<const bf16x8*>(Pb + (long long)(m0 + l16) * 1024 + kb + quad * 8);
#pragma unroll
        for (int ni = 0; ni < 2; ni++) {
            bf16x8 bv = *reinterpret_cast<const bf16x8*>(vb + (long long)(ni * 16 + l16) * 1024 + kb + quad * 8);
            acc[ni] = MFMA16(a, bv, acc[ni]);
        }
    }
    int b_ = bh >> 3, h = bh & 7;
#pragma unroll
    for (int ni = 0; ni < 2; ni++) {
        int d = ni * 16 + l16;
#pragma unroll
        for (int r = 0; r < 4; r++) {
            int l = m0 + quad * 4 + r;
            o[(long long)(b_ * 1024 + l) * 256 + h * 32 + d] = f2bf(acc[ni][r]);
        }
    }
}

// ---------------- proj: [2048,256]x[256,256]^T -> bf16 ----------------
__global__ __launch_bounds__(256) void k_gemm_proj(const unsigned short* __restrict__ a_,
                                                   const unsigned short* __restrict__ w,
                                                   const float* __restrict__ bias,
                                                   unsigned short* __restrict__ y) {
    int wave = threadIdx.x >> 6, lane = threadIdx.x & 63, quad = lane >> 4, l16 = lane & 15;
    int m0 = blockIdx.x * 64 + wave * 16;
    int n0 = blockIdx.y * 64;
    const unsigned short* arow = a_ + (long long)(m0 + l16) * 256;
    f32x4 acc[4] = {};
    for (int kb = 0; kb < 256; kb += 32) {
        bf16x8 a = *reinterpret_cast<const bf16x8*>(arow + kb + quad * 8);
#pragma unroll
        for (int ni = 0; ni < 4; ni++) {
            bf16x8 bv = *reinterpret_cast<const bf16x8*>(w + (long long)(n0 + ni * 16 + l16) * 256 + kb + quad * 8);
            acc[ni] = MFMA16(a, bv, acc[ni]);
        }
    }
#pragma unroll
    for (int ni = 0; ni < 4; ni++) {
        int n = n0 + ni * 16 + l16;
        float bv = bias[n];
#pragma unroll
        for (int r = 0; r < 4; r++)
            y[(long long)(m0 + quad * 4 + r) * 256 + n] = f2bf(acc[ni][r] + bv);
    }
}

// ---------------- up-proj + fold + residual: x2 = x + fold(oproj @ w_up^T + b_up) ----------------
__global__ __launch_bounds__(256) void k_up_fold(const unsigned short* __restrict__ a_,
                                                 const unsigned short* __restrict__ w,
                                                 const float* __restrict__ bup,
                                                 const float* __restrict__ x,
                                                 float* __restrict__ out) {
    int wave = threadIdx.x >> 6, lane = threadIdx.x & 63, quad = lane >> 4, l16 = lane & 15;
    int m0 = blockIdx.x * 64 + wave * 16;
    int n0 = blockIdx.y * 64;
    const unsigned short* arow = a_ + (long long)(m0 + l16) * 256;
    f32x4 acc[4] = {};
    for (int kb = 0; kb < 256; kb += 32) {
        bf16x8 a = *reinterpret_cast<const bf16x8*>(arow + kb + quad * 8);
#pragma unroll
        for (int ni = 0; ni < 4; ni++) {
            bf16x8 bv = *reinterpret_cast<const bf16x8*>(w + (long long)(n0 + ni * 16 + l16) * 256 + kb + quad * 8);
            acc[ni] = MFMA16(a, bv, acc[ni]);
        }
    }
#pragma unroll
    for (int ni = 0; ni < 4; ni++) {
        int n = n0 + ni * 16 + l16;
        float bias = bup[n];
        int p0 = n >> 11, p1 = (n >> 8) & 7, c = n & 255;
#pragma unroll
        for (int r = 0; r < 4; r++) {
            int m = m0 + quad * 4 + r;
            int bb = m >> 10, r0 = (m >> 5) & 31, r1 = m & 31;
            long long addr = ((long long)bb << 24) + (long long)(r0 * 8 + p0) * 65536 + (r1 * 8 + p1) * 256 + c;
            out[addr] = x[addr] + acc[ni][r] + bias;
        }
    }
}

// ---------------- fused LN2 + MLP + residual, in-place on d_out ----------------
// v5 = v4 structure with __launch_bounds__(512, 4).
// v4's spill was the (512,6) register budget: 512-reg SIMD file / 6 waves
// = 85 regs/wave < the ~90 this body needs -> accumulators went to scratch
// (FETCH 1.28GB). At min-waves=4 the budget is 128 (v2 measured 60 actual,
// this body is lighter: acc1[4] not acc1[4][2]), so no spill is possible,
// and occupancy is then LDS-limited: 48KB/block -> 3 blocks/CU = 24
// waves/CU (vs v2's 16). Fallback if actual regs land in 86..128: 2
// blocks/CU = v2 occupancy + 8 extra barriers (bounded ~v2+20us).
#define SWZA(r, c) ((((r) << 9) + ((c) << 1)) ^ (((r) & 7) << 4))
#define SWZH(r, c) ((((r) << 8) + ((c) << 1)) ^ (((r) & 7) << 4))
__global__ __launch_bounds__(512, 4) void k_mlp(float* __restrict__ xio,
                                                const float* __restrict__ g2,
                                                const float* __restrict__ b2,
                                                const unsigned short* __restrict__ w1,
                                                const float* __restrict__ bfc1,
                                                const unsigned short* __restrict__ w2,
                                                const float* __restrict__ bfc2) {
    __shared__ alignas(16) char Aln[64 * 512];
    __shared__ alignas(16) char Hc[64 * 256];
    int wave = threadIdx.x >> 6, lane = threadIdx.x & 63, quad = lane >> 4, l16 = lane & 15;
    long long m0 = (long long)blockIdx.x * 64;
    float4 gg = *reinterpret_cast<const float4*>(g2 + lane * 4);
    float4 bb = *reinterpret_cast<const float4*>(b2 + lane * 4);
#pragma unroll
    for (int i = 0; i < 8; i++) {
        int p = wave * 8 + i;
        float4 v = *reinterpret_cast<const float4*>(xio + (m0 + p) * 256 + lane * 4);
        float s = v.x + v.y + v.z + v.w;
        float s2 = v.x * v.x + v.y * v.y + v.z * v.z + v.w * v.w;
        s = wave_sum(s); s2 = wave_sum(s2);
        float mean = s * (1.f / 256.f);
        float rstd = rsqrtf(s2 * (1.f / 256.f) - mean * mean + 1e-5f);
        ushort4 o;
        o.x = f2bf((v.x - mean) * rstd * gg.x + bb.x);
        o.y = f2bf((v.y - mean) * rstd * gg.y + bb.y);
        o.z = f2bf((v.z - mean) * rstd * gg.z + bb.z);
        o.w = f2bf((v.w - mean) * rstd * gg.w + bb.w);
        *reinterpret_cast<ushort4*>(Aln + SWZA(p, lane * 4)) = o;  // XOR bits>=4 keep 8B align
    }
    __syncthreads();
    f32x4 acc2[4][2] = {};
    for (int ch = 0; ch < 8; ch++) {
        f32x4 acc1[4] = {};
        const unsigned short* w1c = w1 + (long long)(ch * 128 + wave * 16 + l16) * 256;
#pragma unroll
        for (int kb = 0; kb < 256; kb += 32) {
            bf16x8 bv = *reinterpret_cast<const bf16x8*>(w1c + kb + quad * 8);
#pragma unroll
            for (int mi = 0; mi < 4; mi++) {
                bf16x8 aa = *reinterpret_cast<const bf16x8*>(Aln + SWZA(mi * 16 + l16, kb + quad * 8));
                acc1[mi] = MFMA16(aa, bv, acc1[mi]);
            }
        }
        {
            int n = ch * 128 + wave * 16 + l16;
            float bias = bfc1[n];
            int col = wave * 16 + l16;
#pragma unroll
            for (int mi = 0; mi < 4; mi++)
#pragma unroll
                for (int r = 0; r < 4; r++)
                    *reinterpret_cast<unsigned short*>(Hc + SWZH(mi * 16 + quad * 4 + r, col)) =
                        f2bf(gelu_fast(acc1[mi][r] + bias));
        }
        __syncthreads();
        const unsigned short* w2c = w2 + (long long)(wave * 32) * 1024 + ch * 128;
#pragma unroll
        for (int kb = 0; kb < 128; kb += 32) {
            bf16x8 ah[4];
#pragma unroll
            for (int mi = 0; mi < 4; mi++)
                ah[mi] = *reinterpret_cast<const bf16x8*>(Hc + SWZH(mi * 16 + l16, kb + quad * 8));
#pragma unroll
            for (int ni = 0; ni < 2; ni++) {
                bf16x8 bv = *reinterpret_cast<const bf16x8*>(w2c + (long long)(ni * 16 + l16) * 1024 + kb + quad * 8);
#pragma unroll
                for (int mi = 0; mi < 4; mi++)
                    acc2[mi][ni] = MFMA16(ah[mi], bv, acc2[mi][ni]);
            }
        }
        __syncthreads();  // Hc dead; safe to overwrite next chunk
    }
#pragma unroll
    for (int ni = 0; ni < 2; ni++) {
        int n = wave * 32 + ni * 16 + l16;
        float bias = bfc2[n];
#pragma unroll
        for (int mi = 0; mi < 4; mi++) {
#pragma unroll
            for (int r = 0; r < 4; r++) {
                long long row = m0 + mi * 16 + quad * 4 + r;
                float xv = xio[row * 256 + n];
                xio[row * 256 + n] = xv + acc2[mi][ni][r] + bias;
            }
        }
    }
}

extern "C" void kernel_launch(void* const* d_in, const int* in_sizes, int n_in,
                              void* d_out, int out_size, void* d_ws, size_t ws_size,
                              hipStream_t stream) {
    const float* x      = (const float*)d_in[0];
    const float* ln1_g  = (const float*)d_in[1];
    const float* ln1_b  = (const float*)d_in[2];
    const float* ln2_g  = (const float*)d_in[3];
    const float* ln2_b  = (const float*)d_in[4];
    const float* rpe    = (const float*)d_in[5];
    const float* w_down = (const float*)d_in[6];
    const float* b_down = (const float*)d_in[7];
    const float* w_up   = (const float*)d_in[8];
    const float* b_up   = (const float*)d_in[9];
    const float* w_qkv  = (const float*)d_in[10];
    const float* b_qkv  = (const float*)d_in[11];
    const float* w_proj = (const float*)d_in[12];
    const float* b_proj = (const float*)d_in[13];
    const float* w_fc1  = (const float*)d_in[14];
    const float* b_fc1  = (const float*)d_in[15];
    const float* w_fc2  = (const float*)d_in[16];
    const float* b_fc2  = (const float*)d_in[17];
    float* out = (float*)d_out;

    char* wp = (char*)d_ws;
    auto alloc = [&](size_t bytes) { void* p = (void*)wp; wp += (bytes + 255) & ~(size_t)255; return p; };
    unsigned short* wdown_bf = (unsigned short*)alloc(4194304 * 2);
    unsigned short* wup_bf   = (unsigned short*)alloc(4194304 * 2);
    unsigned short* wqkv_bf  = (unsigned short*)alloc(196608 * 2);
    unsigned short* wproj_bf = (unsigned short*)alloc(65536 * 2);
    unsigned short* wfc1_bf  = (unsigned short*)alloc(262144 * 2);
    unsigned short* wfc2_bf  = (unsigned short*)alloc(262144 * 2);
    unsigned short* ydown    = (unsigned short*)alloc(524288 * 2);
    unsigned short* qb       = (unsigned short*)alloc(524288 * 2);
    unsigned short* kb       = (unsigned short*)alloc(524288 * 2);
    unsigned short* vT       = (unsigned short*)alloc(524288 * 2);
    unsigned short* obf      = (unsigned short*)alloc(524288 * 2);
    unsigned short* oproj    = (unsigned short*)alloc(524288 * 2);

    // Big temporaries live inside d_out (134.2 MB); all dead before k_up_fold
    // overwrites the whole buffer with x2.
    unsigned short* xln = (unsigned short*)d_out;
    float* S            = (float*)d_out;
    unsigned short* P   = (unsigned short*)((char*)d_out + 67108864);
    float* part         = (float*)((char*)d_out + 100663296);

    k_cvt<<<4096, 256, 0, stream>>>(w_down, wdown_bf, 4194304);
    k_cvt<<<4096, 256, 0, stream>>>(w_up, wup_bf, 4194304);
    k_cvt<<<192, 256, 0, stream>>>(w_qkv, wqkv_bf, 196608);
    k_cvt<<<64, 256, 0, stream>>>(w_proj, wproj_bf, 65536);
    k_cvt<<<256, 256, 0, stream>>>(w_fc1, wfc1_bf, 262144);
    k_cvt<<<256, 256, 0, stream>>>(w_fc2, wfc2_bf, 262144);

    k_ln_bf<<<32768, 256, 0, stream>>>(x, ln1_g, ln1_b, xln);
    k_gemm_down2<<<dim3(16, 2, 16), 256, 0, stream>>>(xln, wdown_bf, part);
    k_red<<<512, 256, 0, stream>>>(part, b_down, ydown);
    k_gemm_qkv<<<dim3(32, 12), 256, 0, stream>>>(ydown, wqkv_bf, b_qkv, qb, kb, vT);
    k_score<<<dim3(16, 16, 16), 256, 0, stream>>>(qb, kb, rpe, S);
    k_softmax<<<4096, 256, 0, stream>>>(S, P);
    k_pv<<<dim3(16, 16), 256, 0, stream>>>(P, vT, obf);
    k_gemm_proj<<<dim3(32, 4), 256, 0, stream>>>(obf, wproj_bf, b_proj, oproj);
    k_up_fold<<<dim3(32, 256), 256, 0, stream>>>(oproj, wup_bf, b_up, x, out);
    k_mlp<<<2048, 512, 0, stream>>>(out, ln2_g, ln2_b, wfc1_bf, b_fc1, wfc2_bf, b_fc2);
}

// Round 5
// 609.236 us; speedup vs baseline: 1.7254x; 1.1245x over previous
//
#include <hip/hip_runtime.h>

typedef __attribute__((ext_vector_type(8))) __bf16 bf16x8;
typedef __attribute__((ext_vector_type(4))) float f32x4;

#define MFMA16(a, b, c) __builtin_amdgcn_mfma_f32_16x16x32_bf16((a), (b), (c), 0, 0, 0)

// async global->LDS, 16B per lane; LDS dest = wave-uniform base + lane*16
#define ASYNC16(g, l) __builtin_amdgcn_global_load_lds( \
    (const __attribute__((address_space(1))) unsigned int*)(g), \
    (__attribute__((address_space(3))) unsigned int*)(l), 16, 0, 0)

// fp32 -> bf16 RTNE via compiler cast
__device__ __forceinline__ unsigned short f2bf(float f) {
    return __builtin_bit_cast(unsigned short, (__bf16)f);
}

__device__ __forceinline__ float wave_sum(float v) {
#pragma unroll
    for (int off = 32; off; off >>= 1) v += __shfl_xor(v, off, 64);
    return v;
}
__device__ __forceinline__ float wave_max(float v) {
#pragma unroll
    for (int off = 32; off; off >>= 1) v = fmaxf(v, __shfl_xor(v, off, 64));
    return v;
}

// tanh-form GELU: x*sigmoid(1.5957691x + 0.0713548x^3).
__device__ __forceinline__ float gelu_fast(float v) {
    float z = v * fmaf(v * v, 0.0713548162f, 1.5957691216f);
    float e = __expf(-z);
    return v * __builtin_amdgcn_rcpf(1.f + e);
}

// ---------------- fp32 -> bf16 cast (weights) ----------------
__global__ __launch_bounds__(256) void k_cvt(const float* __restrict__ s,
                                             unsigned short* __restrict__ d, int n) {
    int i = (blockIdx.x * 256 + threadIdx.x) * 4;
    if (i >= n) return;
    float4 v = *reinterpret_cast<const float4*>(s + i);
    ushort4 o;
    o.x = f2bf(v.x); o.y = f2bf(v.y); o.z = f2bf(v.z); o.w = f2bf(v.w);
    *reinterpret_cast<ushort4*>(d + i) = o;
}

// ---------------- LN1 over C=256, one wave per pixel -> bf16 ----------------
__global__ __launch_bounds__(256) void k_ln_bf(const float* __restrict__ x,
                                               const float* __restrict__ g,
                                               const float* __restrict__ b,
                                               unsigned short* __restrict__ o) {
    int wave = threadIdx.x >> 6, lane = threadIdx.x & 63;
    long long pix = (long long)blockIdx.x * 4 + wave;
    const float* row = x + pix * 256;
    float4 v = *reinterpret_cast<const float4*>(row + lane * 4);
    float s = v.x + v.y + v.z + v.w;
    float s2 = v.x * v.x + v.y * v.y + v.z * v.z + v.w * v.w;
    s = wave_sum(s); s2 = wave_sum(s2);
    float mean = s * (1.f / 256.f);
    float rstd = rsqrtf(s2 * (1.f / 256.f) - mean * mean + 1e-5f);
    float4 gg = *reinterpret_cast<const float4*>(g + lane * 4);
    float4 bb = *reinterpret_cast<const float4*>(b + lane * 4);
    ushort4 ov;
    ov.x = f2bf((v.x - mean) * rstd * gg.x + bb.x);
    ov.y = f2bf((v.y - mean) * rstd * gg.y + bb.y);
    ov.z = f2bf((v.z - mean) * rstd * gg.z + bb.z);
    ov.w = f2bf((v.w - mean) * rstd * gg.w + bb.w);
    *reinterpret_cast<ushort4*>(o + pix * 256 + lane * 4) = ov;
}

// ---------------- down-proj v2: split-K(16) 128x128 LDS-staged MFMA GEMM ----------------
__global__ __launch_bounds__(256, 2) void k_gemm_down2(const unsigned short* __restrict__ xln,
                                                       const unsigned short* __restrict__ wd,
                                                       float* __restrict__ part) {
    __shared__ alignas(16) unsigned short As[128 * 64];
    __shared__ alignas(16) unsigned short Bs[128 * 64];
    int wave = threadIdx.x >> 6, lane = threadIdx.x & 63, quad = lane >> 4, l16 = lane & 15;
    int mt = blockIdx.x * 128, nt = blockIdx.y * 128, k0 = blockIdx.z * 1024;
    int wm = wave & 1, wn = wave >> 1;
    int srow = wave * 32 + (lane >> 3);   // staging row (+ i*8)
    int schunk = lane & 7;                // 16B chunk within 128B row
    f32x4 acc[4][4] = {};
    for (int s = 0; s < 16; s++) {
        int kg = k0 + s * 64;
        int p0 = kg >> 11, p1 = (kg >> 8) & 7, cbase = kg & 255;
#pragma unroll
        for (int i = 0; i < 4; i++) {
            int row = srow + i * 8;
            int m = mt + row;
            int bb = m >> 10, r0 = (m >> 5) & 31, r1 = m & 31;
            int c = cbase + ((schunk ^ (row & 7)) << 3);
            const unsigned short* g = xln +
                ((((long long)(bb * 256 + r0 * 8 + p0)) * 256 + (r1 * 8 + p1)) << 8) + c;
            ASYNC16(g, &As[(wave * 32 + i * 8) * 64]);
        }
#pragma unroll
        for (int i = 0; i < 4; i++) {
            int row = srow + i * 8;
            int n = nt + row;
            const unsigned short* g = wd + (long long)n * 16384 + kg + ((schunk ^ (row & 7)) << 3);
            ASYNC16(g, &Bs[(wave * 32 + i * 8) * 64]);
        }
        __syncthreads();
#pragma unroll
        for (int sub = 0; sub < 2; sub++) {
            int c = sub * 4 + quad;
            bf16x8 af[4], bfr[4];
#pragma unroll
            for (int mi = 0; mi < 4; mi++) {
                int row = wm * 64 + mi * 16 + l16;
                af[mi] = *reinterpret_cast<const bf16x8*>(&As[row * 64 + ((c ^ (row & 7)) << 3)]);
            }
#pragma unroll
            for (int ni = 0; ni < 4; ni++) {
                int row = wn * 64 + ni * 16 + l16;
                bfr[ni] = *reinterpret_cast<const bf16x8*>(&Bs[row * 64 + ((c ^ (row & 7)) << 3)]);
            }
#pragma unroll
            for (int mi = 0; mi < 4; mi++)
#pragma unroll
                for (int ni = 0; ni < 4; ni++)
                    acc[mi][ni] = MFMA16(af[mi], bfr[ni], acc[mi][ni]);
        }
        __syncthreads();
    }
    float* pb = part + (long long)blockIdx.z * 524288;
#pragma unroll
    for (int mi = 0; mi < 4; mi++)
#pragma unroll
        for (int ni = 0; ni < 4; ni++) {
            int n = nt + wn * 64 + ni * 16 + l16;
#pragma unroll
            for (int r = 0; r < 4; r++) {
                int m = mt + wm * 64 + mi * 16 + quad * 4 + r;
                pb[(long long)m * 256 + n] = acc[mi][ni][r];
            }
        }
}

// ---------------- split-K reduce + bias + bf16 ----------------
__global__ __launch_bounds__(256) void k_red(const float* __restrict__ part,
                                             const float* __restrict__ bd,
                                             unsigned short* __restrict__ y) {
    int i = (blockIdx.x * 256 + threadIdx.x) * 4;
    float4 s = {0.f, 0.f, 0.f, 0.f};
#pragma unroll
    for (int p = 0; p < 16; p++) {
        float4 v = *reinterpret_cast<const float4*>(part + (long long)p * 524288 + i);
        s.x += v.x; s.y += v.y; s.z += v.z; s.w += v.w;
    }
    int n = i & 255;
    float4 bb = *reinterpret_cast<const float4*>(bd + n);
    ushort4 o;
    o.x = f2bf(s.x + bb.x); o.y = f2bf(s.y + bb.y);
    o.z = f2bf(s.z + bb.z); o.w = f2bf(s.w + bb.w);
    *reinterpret_cast<ushort4*>(y + i) = o;
}

// ---------------- qkv: [2048,256]x[768,256]^T, scatter to q, k, v^T (bf16) ----------------
__global__ __launch_bounds__(256) void k_gemm_qkv(const unsigned short* __restrict__ yd,
                                                  const unsigned short* __restrict__ wq,
                                                  const float* __restrict__ bq,
                                                  unsigned short* __restrict__ q,
                                                  unsigned short* __restrict__ k,
                                                  unsigned short* __restrict__ vT) {
    int wave = threadIdx.x >> 6, lane = threadIdx.x & 63, quad = lane >> 4, l16 = lane & 15;
    int m0 = blockIdx.x * 64 + wave * 16;
    int n0 = blockIdx.y * 64;
    const unsigned short* arow = yd + (long long)(m0 + l16) * 256;
    f32x4 acc[4] = {};
    for (int kb = 0; kb < 256; kb += 32) {
        bf16x8 a = *reinterpret_cast<const bf16x8*>(arow + kb + quad * 8);
#pragma unroll
        for (int ni = 0; ni < 4; ni++) {
            bf16x8 bv = *reinterpret_cast<const bf16x8*>(wq + (long long)(n0 + ni * 16 + l16) * 256 + kb + quad * 8);
            acc[ni] = MFMA16(a, bv, acc[ni]);
        }
    }
#pragma unroll
    for (int ni = 0; ni < 4; ni++) {
        int n = n0 + ni * 16 + l16;
        float bias = bq[n];
        int t = n >> 8, h = (n >> 5) & 7, d = n & 31;
#pragma unroll
        for (int r = 0; r < 4; r++) {
            int m = m0 + quad * 4 + r;
            int bh = ((m >> 10) << 3) | h;
            int l = m & 1023;
            unsigned short val = f2bf(acc[ni][r] + bias);
            if (t == 0)      q[((long long)bh * 1024 + l) * 32 + d] = val;
            else if (t == 1) k[((long long)bh * 1024 + l) * 32 + d] = val;
            else             vT[((long long)bh * 32 + d) * 1024 + l] = val;
        }
    }
}

// ---------------- fused flash attention: S=scale*qk^T+rpe, softmax, O=P@V ----------------
// Replaces k_score + k_softmax + k_pv: kills the 201 MB S/P HBM round-trip.
// Swapped QK^T (S^T = mfma(K, Q)) makes each lane hold S values of ONE q-row
// (qi = l16): row max/sum = 2x shfl_xor(16/32). P^T is r-contiguous in kj ->
// 4x ds_write_b64 into a per-wave 2KB XOR-swizzled tile, read back b128 as
// the PV B-fragment. Per-wave private LDS -> zero barriers. O accumulates
// O^T[d][qi] fp32 with online rescale; one divide at the end.
__global__ __launch_bounds__(256) void k_attn(const unsigned short* __restrict__ q,
                                              const unsigned short* __restrict__ k,
                                              const unsigned short* __restrict__ vT,
                                              const float* __restrict__ rpe,
                                              unsigned short* __restrict__ o) {
    __shared__ alignas(16) char Pl[4][16 * 128];   // per-wave [16 qi][64 kj] bf16, swizzled
    int wave = threadIdx.x >> 6, lane = threadIdx.x & 63, quad = lane >> 4, l16 = lane & 15;
    int bh = blockIdx.y, h = bh & 7;
    int m0 = blockIdx.x * 64 + wave * 16;
    const unsigned short* qb = q + (long long)bh * 32768;
    const unsigned short* kb = k + (long long)bh * 32768;
    const unsigned short* vb = vT + (long long)bh * 32768;
    char* pl = Pl[wave];
    const float scale = 0.17677669529663687f;  // 1/sqrt(32)
    int qi = m0 + l16;
    int qi0 = qi >> 5, qi1 = qi & 31;
    bf16x8 bq = *reinterpret_cast<const bf16x8*>(qb + qi * 32 + quad * 8);
    f32x4 o0 = {0.f, 0.f, 0.f, 0.f}, o1 = {0.f, 0.f, 0.f, 0.f};
    float m_run = -3.0e38f, l_run = 0.f;
    int swz = (l16 & 7) << 4;
    for (int t = 0; t < 16; t++) {
        // S^T tile: D[kj = t*64+ni*16+quad*4+r][qi = m0+l16]
        f32x4 st[4];
#pragma unroll
        for (int ni = 0; ni < 4; ni++) {
            bf16x8 ak = *reinterpret_cast<const bf16x8*>(kb + (t * 64 + ni * 16 + l16) * 32 + quad * 8);
            f32x4 z = {0.f, 0.f, 0.f, 0.f};
            st[ni] = MFMA16(ak, bq, z);
        }
        float vals[16];
        float tmax = -3.0e38f;
#pragma unroll
        for (int ni = 0; ni < 4; ni++)
#pragma unroll
            for (int r = 0; r < 4; r++) {
                int kj = t * 64 + ni * 16 + quad * 4 + r;
                int kj0 = kj >> 5, kj1 = kj & 31;
                int idx = (qi0 - kj0 + 31) * 63 + (qi1 - kj1 + 31);
                float sv = st[ni][r] * scale + rpe[idx * 8 + h];
                vals[ni * 4 + r] = sv;
                tmax = fmaxf(tmax, sv);
            }
        // row(=qi) reductions live across quads: lanes l16, l16+16, l16+32, l16+48
        tmax = fmaxf(tmax, __shfl_xor(tmax, 16, 64));
        tmax = fmaxf(tmax, __shfl_xor(tmax, 32, 64));
        float m_new = fmaxf(m_run, tmax);
        float fac = __expf(m_run - m_new);    // first tile: exp(-3e38-..) -> 0
        float tsum = 0.f;
#pragma unroll
        for (int ni = 0; ni < 4; ni++) {
            ushort4 w4;
            float p0v = __expf(vals[ni * 4 + 0] - m_new);
            float p1v = __expf(vals[ni * 4 + 1] - m_new);
            float p2v = __expf(vals[ni * 4 + 2] - m_new);
            float p3v = __expf(vals[ni * 4 + 3] - m_new);
            tsum += p0v + p1v + p2v + p3v;
            w4.x = f2bf(p0v); w4.y = f2bf(p1v); w4.z = f2bf(p2v); w4.w = f2bf(p3v);
            // P[qi=l16][kj = ni*16+quad*4 + 0..3] -> bytes (ni*32+quad*8), swizzled
            *reinterpret_cast<ushort4*>(pl + l16 * 128 + ((ni * 32 + quad * 8) ^ swz)) = w4;
        }
        tsum += __shfl_xor(tsum, 16, 64);
        tsum += __shfl_xor(tsum, 32, 64);
        l_run = l_run * fac + tsum;
        m_run = m_new;
#pragma unroll
        for (int r = 0; r < 4; r++) { o0[r] *= fac; o1[r] *= fac; }
        // PV: O^T[d][qi] += mfma(A=V^T rows d, B=P rows qi)
#pragma unroll
        for (int kk = 0; kk < 2; kk++) {
            bf16x8 pb = *reinterpret_cast<const bf16x8*>(pl + l16 * 128 + ((kk * 64 + quad * 16) ^ swz));
            bf16x8 av0 = *reinterpret_cast<const bf16x8*>(vb + (long long)(l16) * 1024 + t * 64 + kk * 32 + quad * 8);
            bf16x8 av1 = *reinterpret_cast<const bf16x8*>(vb + (long long)(16 + l16) * 1024 + t * 64 + kk * 32 + quad * 8);
            o0 = MFMA16(av0, pb, o0);
            o1 = MFMA16(av1, pb, o1);
        }
    }
    float inv = 1.f / l_run;
    int b_ = bh >> 3;
    long long base = ((long long)(b_ * 1024 + qi)) * 256 + h * 32;
    ushort4 w0, w1;
    w0.x = f2bf(o0[0] * inv); w0.y = f2bf(o0[1] * inv);
    w0.z = f2bf(o0[2] * inv); w0.w = f2bf(o0[3] * inv);
    w1.x = f2bf(o1[0] * inv); w1.y = f2bf(o1[1] * inv);
    w1.z = f2bf(o1[2] * inv); w1.w = f2bf(o1[3] * inv);
    *reinterpret_cast<ushort4*>(o + base + quad * 4) = w0;        // d = quad*4+r
    *reinterpret_cast<ushort4*>(o + base + 16 + quad * 4) = w1;   // d = 16+quad*4+r
}

// ---------------- proj: [2048,256]x[256,256]^T -> bf16 ----------------
__global__ __launch_bounds__(256) void k_gemm_proj(const unsigned short* __restrict__ a_,
                                                   const unsigned short* __restrict__ w,
                                                   const float* __restrict__ bias,
                                                   unsigned short* __restrict__ y) {
    int wave = threadIdx.x >> 6, lane = threadIdx.x & 63, quad = lane >> 4, l16 = lane & 15;
    int m0 = blockIdx.x * 64 + wave * 16;
    int n0 = blockIdx.y * 64;
    const unsigned short* arow = a_ + (long long)(m0 + l16) * 256;
    f32x4 acc[4] = {};
    for (int kb = 0; kb < 256; kb += 32) {
        bf16x8 a = *reinterpret_cast<const bf16x8*>(arow + kb + quad * 8);
#pragma unroll
        for (int ni = 0; ni < 4; ni++) {
            bf16x8 bv = *reinterpret_cast<const bf16x8*>(w + (long long)(n0 + ni * 16 + l16) * 256 + kb + quad * 8);
            acc[ni] = MFMA16(a, bv, acc[ni]);
        }
    }
#pragma unroll
    for (int ni = 0; ni < 4; ni++) {
        int n = n0 + ni * 16 + l16;
        float bv = bias[n];
#pragma unroll
        for (int r = 0; r < 4; r++)
            y[(long long)(m0 + quad * 4 + r) * 256 + n] = f2bf(acc[ni][r] + bv);
    }
}

// ---------------- up-proj + fold + residual: x2 = x + fold(oproj @ w_up^T + b_up) ----------------
__global__ __launch_bounds__(256) void k_up_fold(const unsigned short* __restrict__ a_,
                                                 const unsigned short* __restrict__ w,
                                                 const float* __restrict__ bup,
                                                 const float* __restrict__ x,
                                                 float* __restrict__ out) {
    int wave = threadIdx.x >> 6, lane = threadIdx.x & 63, quad = lane >> 4, l16 = lane & 15;
    int m0 = blockIdx.x * 64 + wave * 16;
    int n0 = blockIdx.y * 64;
    const unsigned short* arow = a_ + (long long)(m0 + l16) * 256;
    f32x4 acc[4] = {};
    for (int kb = 0; kb < 256; kb += 32) {
        bf16x8 a = *reinterpret_cast<const bf16x8*>(arow + kb + quad * 8);
#pragma unroll
        for (int ni = 0; ni < 4; ni++) {
            bf16x8 bv = *reinterpret_cast<const bf16x8*>(w + (long long)(n0 + ni * 16 + l16) * 256 + kb + quad * 8);
            acc[ni] = MFMA16(a, bv, acc[ni]);
        }
    }
#pragma unroll
    for (int ni = 0; ni < 4; ni++) {
        int n = n0 + ni * 16 + l16;
        float bias = bup[n];
        int p0 = n >> 11, p1 = (n >> 8) & 7, c = n & 255;
#pragma unroll
        for (int r = 0; r < 4; r++) {
            int m = m0 + quad * 4 + r;
            int bb = m >> 10, r0 = (m >> 5) & 31, r1 = m & 31;
            long long addr = ((long long)bb << 24) + (long long)(r0 * 8 + p0) * 65536 + (r1 * 8 + p1) * 256 + c;
            out[addr] = x[addr] + acc[ni][r] + bias;
        }
    }
}

// ---------------- fused LN2 + MLP + residual, in-place on d_out ----------------
// v6 == v2 exactly (316 us, FETCH 137MB, no spill) -- the proven local
// optimum of this structure. v3 (phase merge), v4 ((512,6)) both spilled;
// v5 (8x128 chunks) added barriers + L2 thrash. Do not touch again without
// a register-budget proof: live regs must stay <= 512/min_waves incl AGPRs.
#define LP 264  // 256 + 8 pad: row stride 528 B -> bank step 4, 2-way max (free)
__global__ __launch_bounds__(512, 4) void k_mlp(float* __restrict__ xio,
                                                const float* __restrict__ g2,
                                                const float* __restrict__ b2,
                                                const unsigned short* __restrict__ w1,
                                                const float* __restrict__ bfc1,
                                                const unsigned short* __restrict__ w2,
                                                const float* __restrict__ bfc2) {
    __shared__ unsigned short Aln[64 * LP];
    __shared__ unsigned short Hc[64 * LP];
    int wave = threadIdx.x >> 6, lane = threadIdx.x & 63, quad = lane >> 4, l16 = lane & 15;
    long long m0 = (long long)blockIdx.x * 64;
    float4 gg = *reinterpret_cast<const float4*>(g2 + lane * 4);
    float4 bb = *reinterpret_cast<const float4*>(b2 + lane * 4);
#pragma unroll
    for (int i = 0; i < 8; i++) {
        int p = wave * 8 + i;
        float4 v = *reinterpret_cast<const float4*>(xio + (m0 + p) * 256 + lane * 4);
        float s = v.x + v.y + v.z + v.w;
        float s2 = v.x * v.x + v.y * v.y + v.z * v.z + v.w * v.w;
        s = wave_sum(s); s2 = wave_sum(s2);
        float mean = s * (1.f / 256.f);
        float rstd = rsqrtf(s2 * (1.f / 256.f) - mean * mean + 1e-5f);
        ushort4 o;
        o.x = f2bf((v.x - mean) * rstd * gg.x + bb.x);
        o.y = f2bf((v.y - mean) * rstd * gg.y + bb.y);
        o.z = f2bf((v.z - mean) * rstd * gg.z + bb.z);
        o.w = f2bf((v.w - mean) * rstd * gg.w + bb.w);
        *reinterpret_cast<ushort4*>(&Aln[p * LP + lane * 4]) = o;
    }
    __syncthreads();
    f32x4 acc2[4][2] = {};
    for (int ch = 0; ch < 4; ch++) {
        f32x4 acc1[4][2] = {};
        for (int kb = 0; kb < 256; kb += 32) {
            bf16x8 af[4];
#pragma unroll
            for (int mi = 0; mi < 4; mi++)
                af[mi] = *reinterpret_cast<const bf16x8*>(&Aln[(mi * 16 + l16) * LP + kb + quad * 8]);
#pragma unroll
            for (int ni = 0; ni < 2; ni++) {
                bf16x8 bv = *reinterpret_cast<const bf16x8*>(w1 + (long long)(ch * 256 + wave * 32 + ni * 16 + l16) * 256 + kb + quad * 8);
#pragma unroll
                for (int mi = 0; mi < 4; mi++)
                    acc1[mi][ni] = MFMA16(af[mi], bv, acc1[mi][ni]);
            }
        }
#pragma unroll
        for (int ni = 0; ni < 2; ni++) {
            int n = ch * 256 + wave * 32 + ni * 16 + l16;
            float bias = bfc1[n];
            int col = wave * 32 + ni * 16 + l16;
#pragma unroll
            for (int mi = 0; mi < 4; mi++) {
#pragma unroll
                for (int r = 0; r < 4; r++) {
                    float vv = acc1[mi][ni][r] + bias;
                    Hc[(mi * 16 + quad * 4 + r) * LP + col] = f2bf(gelu_fast(vv));
                }
            }
        }
        __syncthreads();
        for (int kb = 0; kb < 256; kb += 32) {
            bf16x8 af[4];
#pragma unroll
            for (int mi = 0; mi < 4; mi++)
                af[mi] = *reinterpret_cast<const bf16x8*>(&Hc[(mi * 16 + l16) * LP + kb + quad * 8]);
#pragma unroll
            for (int ni = 0; ni < 2; ni++) {
                bf16x8 bv = *reinterpret_cast<const bf16x8*>(w2 + (long long)(wave * 32 + ni * 16 + l16) * 1024 + ch * 256 + kb + quad * 8);
#pragma unroll
                for (int mi = 0; mi < 4; mi++)
                    acc2[mi][ni] = MFMA16(af[mi], bv, acc2[mi][ni]);
            }
        }
        __syncthreads();
    }
#pragma unroll
    for (int ni = 0; ni < 2; ni++) {
        int n = wave * 32 + ni * 16 + l16;
        float bias = bfc2[n];
#pragma unroll
        for (int mi = 0; mi < 4; mi++) {
#pragma unroll
            for (int r = 0; r < 4; r++) {
                long long row = m0 + mi * 16 + quad * 4 + r;
                float xv = xio[row * 256 + n];
                xio[row * 256 + n] = xv + acc2[mi][ni][r] + bias;
            }
        }
    }
}

extern "C" void kernel_launch(void* const* d_in, const int* in_sizes, int n_in,
                              void* d_out, int out_size, void* d_ws, size_t ws_size,
                              hipStream_t stream) {
    const float* x      = (const float*)d_in[0];
    const float* ln1_g  = (const float*)d_in[1];
    const float* ln1_b  = (const float*)d_in[2];
    const float* ln2_g  = (const float*)d_in[3];
    const float* ln2_b  = (const float*)d_in[4];
    const float* rpe    = (const float*)d_in[5];
    const float* w_down = (const float*)d_in[6];
    const float* b_down = (const float*)d_in[7];
    const float* w_up   = (const float*)d_in[8];
    const float* b_up   = (const float*)d_in[9];
    const float* w_qkv  = (const float*)d_in[10];
    const float* b_qkv  = (const float*)d_in[11];
    const float* w_proj = (const float*)d_in[12];
    const float* b_proj = (const float*)d_in[13];
    const float* w_fc1  = (const float*)d_in[14];
    const float* b_fc1  = (const float*)d_in[15];
    const float* w_fc2  = (const float*)d_in[16];
    const float* b_fc2  = (const float*)d_in[17];
    float* out = (float*)d_out;

    char* wp = (char*)d_ws;
    auto alloc = [&](size_t bytes) { void* p = (void*)wp; wp += (bytes + 255) & ~(size_t)255; return p; };
    unsigned short* wdown_bf = (unsigned short*)alloc(4194304 * 2);
    unsigned short* wup_bf   = (unsigned short*)alloc(4194304 * 2);
    unsigned short* wqkv_bf  = (unsigned short*)alloc(196608 * 2);
    unsigned short* wproj_bf = (unsigned short*)alloc(65536 * 2);
    unsigned short* wfc1_bf  = (unsigned short*)alloc(262144 * 2);
    unsigned short* wfc2_bf  = (unsigned short*)alloc(262144 * 2);
    unsigned short* ydown    = (unsigned short*)alloc(524288 * 2);
    unsigned short* qb       = (unsigned short*)alloc(524288 * 2);
    unsigned short* kb       = (unsigned short*)alloc(524288 * 2);
    unsigned short* vT       = (unsigned short*)alloc(524288 * 2);
    unsigned short* obf      = (unsigned short*)alloc(524288 * 2);
    unsigned short* oproj    = (unsigned short*)alloc(524288 * 2);

    // Big temporaries live inside d_out (134.2 MB); all dead before k_up_fold
    // overwrites the whole buffer with x2.
    //   xln:  [0, 67.1 MB)        -- dead after k_gemm_down2
    //   part: [100.7, 134.2 MB)   -- 16 x 2 MB fp32 split-K partials
    unsigned short* xln = (unsigned short*)d_out;
    float* part         = (float*)((char*)d_out + 100663296);

    k_cvt<<<4096, 256, 0, stream>>>(w_down, wdown_bf, 4194304);
    k_cvt<<<4096, 256, 0, stream>>>(w_up, wup_bf, 4194304);
    k_cvt<<<192, 256, 0, stream>>>(w_qkv, wqkv_bf, 196608);
    k_cvt<<<64, 256, 0, stream>>>(w_proj, wproj_bf, 65536);
    k_cvt<<<256, 256, 0, stream>>>(w_fc1, wfc1_bf, 262144);
    k_cvt<<<256, 256, 0, stream>>>(w_fc2, wfc2_bf, 262144);

    k_ln_bf<<<32768, 256, 0, stream>>>(x, ln1_g, ln1_b, xln);
    k_gemm_down2<<<dim3(16, 2, 16), 256, 0, stream>>>(xln, wdown_bf, part);
    k_red<<<512, 256, 0, stream>>>(part, b_down, ydown);
    k_gemm_qkv<<<dim3(32, 12), 256, 0, stream>>>(ydown, wqkv_bf, b_qkv, qb, kb, vT);
    k_attn<<<dim3(16, 16), 256, 0, stream>>>(qb, kb, vT, rpe, obf);
    k_gemm_proj<<<dim3(32, 4), 256, 0, stream>>>(obf, wproj_bf, b_proj, oproj);
    k_up_fold<<<dim3(32, 256), 256, 0, stream>>>(oproj, wup_bf, b_up, x, out);
    k_mlp<<<2048, 512, 0, stream>>>(out, ln2_g, ln2_b, wfc1_bf, b_fc1, wfc2_bf, b_fc2);
}

// Round 6
// 607.811 us; speedup vs baseline: 1.7295x; 1.0023x over previous
//
#include <hip/hip_runtime.h>

typedef __attribute__((ext_vector_type(8))) __bf16 bf16x8;
typedef __attribute__((ext_vector_type(4))) float f32x4;

#define MFMA16(a, b, c) __builtin_amdgcn_mfma_f32_16x16x32_bf16((a), (b), (c), 0, 0, 0)

// async global->LDS, 16B per lane; LDS dest = wave-uniform base + lane*16
#define ASYNC16(g, l) __builtin_amdgcn_global_load_lds( \
    (const __attribute__((address_space(1))) unsigned int*)(g), \
    (__attribute__((address_space(3))) unsigned int*)(l), 16, 0, 0)

// fp32 -> bf16 RTNE via compiler cast
__device__ __forceinline__ unsigned short f2bf(float f) {
    return __builtin_bit_cast(unsigned short, (__bf16)f);
}

__device__ __forceinline__ float wave_sum(float v) {
#pragma unroll
    for (int off = 32; off; off >>= 1) v += __shfl_xor(v, off, 64);
    return v;
}

// tanh-form GELU: x*sigmoid(1.5957691x + 0.0713548x^3).
__device__ __forceinline__ float gelu_fast(float v) {
    float z = v * fmaf(v * v, 0.0713548162f, 1.5957691216f);
    float e = __expf(-z);
    return v * __builtin_amdgcn_rcpf(1.f + e);
}

// ---------------- fused preamble: all 6 weight casts + LN1, one launch ----------------
// Replaces 6x k_cvt + k_ln_bf (7 dispatches -> 1): inter-dispatch gaps were
// ~3-5us each (calibrated from the r4->r5 delta).
__global__ __launch_bounds__(256) void k_pre(const float* __restrict__ wdown, const float* __restrict__ wup,
                                             const float* __restrict__ wqkv, const float* __restrict__ wproj,
                                             const float* __restrict__ wfc1, const float* __restrict__ wfc2,
                                             unsigned short* __restrict__ dwdown, unsigned short* __restrict__ dwup,
                                             unsigned short* __restrict__ dwqkv, unsigned short* __restrict__ dwproj,
                                             unsigned short* __restrict__ dwfc1, unsigned short* __restrict__ dwfc2,
                                             const float* __restrict__ x, const float* __restrict__ g,
                                             const float* __restrict__ b, unsigned short* __restrict__ xln) {
    int bid = blockIdx.x;
    if (bid < 8960) {
        // weight casts: 9,175,040 elements total, 1024 per block
        int i = (bid * 256 + threadIdx.x) * 4;
        const float* s; unsigned short* d; int off;
        if (i < 4194304)      { s = wdown; d = dwdown; off = i; }
        else if (i < 8388608) { s = wup;   d = dwup;   off = i - 4194304; }
        else if (i < 8585216) { s = wqkv;  d = dwqkv;  off = i - 8388608; }
        else if (i < 8650752) { s = wproj; d = dwproj; off = i - 8585216; }
        else if (i < 8912896) { s = wfc1;  d = dwfc1;  off = i - 8650752; }
        else                  { s = wfc2;  d = dwfc2;  off = i - 8912896; }
        float4 v = *reinterpret_cast<const float4*>(s + off);
        ushort4 o;
        o.x = f2bf(v.x); o.y = f2bf(v.y); o.z = f2bf(v.z); o.w = f2bf(v.w);
        *reinterpret_cast<ushort4*>(d + off) = o;
    } else {
        // LN1 over C=256, one wave per pixel -> bf16
        int wave = threadIdx.x >> 6, lane = threadIdx.x & 63;
        long long pix = (long long)(bid - 8960) * 4 + wave;
        const float* row = x + pix * 256;
        float4 v = *reinterpret_cast<const float4*>(row + lane * 4);
        float s = v.x + v.y + v.z + v.w;
        float s2 = v.x * v.x + v.y * v.y + v.z * v.z + v.w * v.w;
        s = wave_sum(s); s2 = wave_sum(s2);
        float mean = s * (1.f / 256.f);
        float rstd = rsqrtf(s2 * (1.f / 256.f) - mean * mean + 1e-5f);
        float4 gg = *reinterpret_cast<const float4*>(g + lane * 4);
        float4 bb = *reinterpret_cast<const float4*>(b + lane * 4);
        ushort4 ov;
        ov.x = f2bf((v.x - mean) * rstd * gg.x + bb.x);
        ov.y = f2bf((v.y - mean) * rstd * gg.y + bb.y);
        ov.z = f2bf((v.z - mean) * rstd * gg.z + bb.z);
        ov.w = f2bf((v.w - mean) * rstd * gg.w + bb.w);
        *reinterpret_cast<ushort4*>(xln + pix * 256 + lane * 4) = ov;
    }
}

// ---------------- down-proj v2: split-K(16) 128x128 LDS-staged MFMA GEMM ----------------
__global__ __launch_bounds__(256, 2) void k_gemm_down2(const unsigned short* __restrict__ xln,
                                                       const unsigned short* __restrict__ wd,
                                                       float* __restrict__ part) {
    __shared__ alignas(16) unsigned short As[128 * 64];
    __shared__ alignas(16) unsigned short Bs[128 * 64];
    int wave = threadIdx.x >> 6, lane = threadIdx.x & 63, quad = lane >> 4, l16 = lane & 15;
    int mt = blockIdx.x * 128, nt = blockIdx.y * 128, k0 = blockIdx.z * 1024;
    int wm = wave & 1, wn = wave >> 1;
    int srow = wave * 32 + (lane >> 3);   // staging row (+ i*8)
    int schunk = lane & 7;                // 16B chunk within 128B row
    f32x4 acc[4][4] = {};
    for (int s = 0; s < 16; s++) {
        int kg = k0 + s * 64;
        int p0 = kg >> 11, p1 = (kg >> 8) & 7, cbase = kg & 255;
#pragma unroll
        for (int i = 0; i < 4; i++) {
            int row = srow + i * 8;
            int m = mt + row;
            int bb = m >> 10, r0 = (m >> 5) & 31, r1 = m & 31;
            int c = cbase + ((schunk ^ (row & 7)) << 3);
            const unsigned short* g = xln +
                ((((long long)(bb * 256 + r0 * 8 + p0)) * 256 + (r1 * 8 + p1)) << 8) + c;
            ASYNC16(g, &As[(wave * 32 + i * 8) * 64]);
        }
#pragma unroll
        for (int i = 0; i < 4; i++) {
            int row = srow + i * 8;
            int n = nt + row;
            const unsigned short* g = wd + (long long)n * 16384 + kg + ((schunk ^ (row & 7)) << 3);
            ASYNC16(g, &Bs[(wave * 32 + i * 8) * 64]);
        }
        __syncthreads();
#pragma unroll
        for (int sub = 0; sub < 2; sub++) {
            int c = sub * 4 + quad;
            bf16x8 af[4], bfr[4];
#pragma unroll
            for (int mi = 0; mi < 4; mi++) {
                int row = wm * 64 + mi * 16 + l16;
                af[mi] = *reinterpret_cast<const bf16x8*>(&As[row * 64 + ((c ^ (row & 7)) << 3)]);
            }
#pragma unroll
            for (int ni = 0; ni < 4; ni++) {
                int row = wn * 64 + ni * 16 + l16;
                bfr[ni] = *reinterpret_cast<const bf16x8*>(&Bs[row * 64 + ((c ^ (row & 7)) << 3)]);
            }
#pragma unroll
            for (int mi = 0; mi < 4; mi++)
#pragma unroll
                for (int ni = 0; ni < 4; ni++)
                    acc[mi][ni] = MFMA16(af[mi], bfr[ni], acc[mi][ni]);
        }
        __syncthreads();
    }
    float* pb = part + (long long)blockIdx.z * 524288;
#pragma unroll
    for (int mi = 0; mi < 4; mi++)
#pragma unroll
        for (int ni = 0; ni < 4; ni++) {
            int n = nt + wn * 64 + ni * 16 + l16;
#pragma unroll
            for (int r = 0; r < 4; r++) {
                int m = mt + wm * 64 + mi * 16 + quad * 4 + r;
                pb[(long long)m * 256 + n] = acc[mi][ni][r];
            }
        }
}

// ---------------- split-K reduce + bias + bf16 ----------------
__global__ __launch_bounds__(256) void k_red(const float* __restrict__ part,
                                             const float* __restrict__ bd,
                                             unsigned short* __restrict__ y) {
    int i = (blockIdx.x * 256 + threadIdx.x) * 4;
    float4 s = {0.f, 0.f, 0.f, 0.f};
#pragma unroll
    for (int p = 0; p < 16; p++) {
        float4 v = *reinterpret_cast<const float4*>(part + (long long)p * 524288 + i);
        s.x += v.x; s.y += v.y; s.z += v.z; s.w += v.w;
    }
    int n = i & 255;
    float4 bb = *reinterpret_cast<const float4*>(bd + n);
    ushort4 o;
    o.x = f2bf(s.x + bb.x); o.y = f2bf(s.y + bb.y);
    o.z = f2bf(s.z + bb.z); o.w = f2bf(s.w + bb.w);
    *reinterpret_cast<ushort4*>(y + i) = o;
}

// ---------------- qkv: [2048,256]x[768,256]^T, scatter to q, k, v^T (bf16) ----------------
__global__ __launch_bounds__(256) void k_gemm_qkv(const unsigned short* __restrict__ yd,
                                                  const unsigned short* __restrict__ wq,
                                                  const float* __restrict__ bq,
                                                  unsigned short* __restrict__ q,
                                                  unsigned short* __restrict__ k,
                                                  unsigned short* __restrict__ vT) {
    int wave = threadIdx.x >> 6, lane = threadIdx.x & 63, quad = lane >> 4, l16 = lane & 15;
    int m0 = blockIdx.x * 64 + wave * 16;
    int n0 = blockIdx.y * 64;
    const unsigned short* arow = yd + (long long)(m0 + l16) * 256;
    f32x4 acc[4] = {};
    for (int kb = 0; kb < 256; kb += 32) {
        bf16x8 a = *reinterpret_cast<const bf16x8*>(arow + kb + quad * 8);
#pragma unroll
        for (int ni = 0; ni < 4; ni++) {
            bf16x8 bv = *reinterpret_cast<const bf16x8*>(wq + (long long)(n0 + ni * 16 + l16) * 256 + kb + quad * 8);
            acc[ni] = MFMA16(a, bv, acc[ni]);
        }
    }
#pragma unroll
    for (int ni = 0; ni < 4; ni++) {
        int n = n0 + ni * 16 + l16;
        float bias = bq[n];
        int t = n >> 8, h = (n >> 5) & 7, d = n & 31;
#pragma unroll
        for (int r = 0; r < 4; r++) {
            int m = m0 + quad * 4 + r;
            int bh = ((m >> 10) << 3) | h;
            int l = m & 1023;
            unsigned short val = f2bf(acc[ni][r] + bias);
            if (t == 0)      q[((long long)bh * 1024 + l) * 32 + d] = val;
            else if (t == 1) k[((long long)bh * 1024 + l) * 32 + d] = val;
            else             vT[((long long)bh * 32 + d) * 1024 + l] = val;
        }
    }
}

// ---------------- fused flash attention: S=scale*qk^T+rpe, softmax, O=P@V ----------------
__global__ __launch_bounds__(256) void k_attn(const unsigned short* __restrict__ q,
                                              const unsigned short* __restrict__ k,
                                              const unsigned short* __restrict__ vT,
                                              const float* __restrict__ rpe,
                                              unsigned short* __restrict__ o) {
    __shared__ alignas(16) char Pl[4][16 * 128];   // per-wave [16 qi][64 kj] bf16, swizzled
    int wave = threadIdx.x >> 6, lane = threadIdx.x & 63, quad = lane >> 4, l16 = lane & 15;
    int bh = blockIdx.y, h = bh & 7;
    int m0 = blockIdx.x * 64 + wave * 16;
    const unsigned short* qb = q + (long long)bh * 32768;
    const unsigned short* kb = k + (long long)bh * 32768;
    const unsigned short* vb = vT + (long long)bh * 32768;
    char* pl = Pl[wave];
    const float scale = 0.17677669529663687f;  // 1/sqrt(32)
    int qi = m0 + l16;
    int qi0 = qi >> 5, qi1 = qi & 31;
    bf16x8 bq = *reinterpret_cast<const bf16x8*>(qb + qi * 32 + quad * 8);
    f32x4 o0 = {0.f, 0.f, 0.f, 0.f}, o1 = {0.f, 0.f, 0.f, 0.f};
    float m_run = -3.0e38f, l_run = 0.f;
    int swz = (l16 & 7) << 4;
    for (int t = 0; t < 16; t++) {
        // S^T tile: D[kj = t*64+ni*16+quad*4+r][qi = m0+l16]
        f32x4 st[4];
        __builtin_amdgcn_s_setprio(1);
#pragma unroll
        for (int ni = 0; ni < 4; ni++) {
            bf16x8 ak = *reinterpret_cast<const bf16x8*>(kb + (t * 64 + ni * 16 + l16) * 32 + quad * 8);
            f32x4 z = {0.f, 0.f, 0.f, 0.f};
            st[ni] = MFMA16(ak, bq, z);
        }
        __builtin_amdgcn_s_setprio(0);
        float vals[16];
        float tmax = -3.0e38f;
#pragma unroll
        for (int ni = 0; ni < 4; ni++)
#pragma unroll
            for (int r = 0; r < 4; r++) {
                int kj = t * 64 + ni * 16 + quad * 4 + r;
                int kj0 = kj >> 5, kj1 = kj & 31;
                int idx = (qi0 - kj0 + 31) * 63 + (qi1 - kj1 + 31);
                float sv = st[ni][r] * scale + rpe[idx * 8 + h];
                vals[ni * 4 + r] = sv;
                tmax = fmaxf(tmax, sv);
            }
        // row(=qi) reductions live across quads: lanes l16, l16+16, l16+32, l16+48
        tmax = fmaxf(tmax, __shfl_xor(tmax, 16, 64));
        tmax = fmaxf(tmax, __shfl_xor(tmax, 32, 64));
        float m_new = fmaxf(m_run, tmax);
        float fac = __expf(m_run - m_new);    // first tile: exp(-3e38-..) -> 0
        float tsum = 0.f;
#pragma unroll
        for (int ni = 0; ni < 4; ni++) {
            ushort4 w4;
            float p0v = __expf(vals[ni * 4 + 0] - m_new);
            float p1v = __expf(vals[ni * 4 + 1] - m_new);
            float p2v = __expf(vals[ni * 4 + 2] - m_new);
            float p3v = __expf(vals[ni * 4 + 3] - m_new);
            tsum += p0v + p1v + p2v + p3v;
            w4.x = f2bf(p0v); w4.y = f2bf(p1v); w4.z = f2bf(p2v); w4.w = f2bf(p3v);
            *reinterpret_cast<ushort4*>(pl + l16 * 128 + ((ni * 32 + quad * 8) ^ swz)) = w4;
        }
        tsum += __shfl_xor(tsum, 16, 64);
        tsum += __shfl_xor(tsum, 32, 64);
        l_run = l_run * fac + tsum;
        m_run = m_new;
#pragma unroll
        for (int r = 0; r < 4; r++) { o0[r] *= fac; o1[r] *= fac; }
        // PV: O^T[d][qi] += mfma(A=V^T rows d, B=P rows qi)
#pragma unroll
        for (int kk = 0; kk < 2; kk++) {
            bf16x8 pb = *reinterpret_cast<const bf16x8*>(pl + l16 * 128 + ((kk * 64 + quad * 16) ^ swz));
            bf16x8 av0 = *reinterpret_cast<const bf16x8*>(vb + (long long)(l16) * 1024 + t * 64 + kk * 32 + quad * 8);
            bf16x8 av1 = *reinterpret_cast<const bf16x8*>(vb + (long long)(16 + l16) * 1024 + t * 64 + kk * 32 + quad * 8);
            __builtin_amdgcn_s_setprio(1);
            o0 = MFMA16(av0, pb, o0);
            o1 = MFMA16(av1, pb, o1);
            __builtin_amdgcn_s_setprio(0);
        }
    }
    float inv = 1.f / l_run;
    int b_ = bh >> 3;
    long long base = ((long long)(b_ * 1024 + qi)) * 256 + h * 32;
    ushort4 w0, w1;
    w0.x = f2bf(o0[0] * inv); w0.y = f2bf(o0[1] * inv);
    w0.z = f2bf(o0[2] * inv); w0.w = f2bf(o0[3] * inv);
    w1.x = f2bf(o1[0] * inv); w1.y = f2bf(o1[1] * inv);
    w1.z = f2bf(o1[2] * inv); w1.w = f2bf(o1[3] * inv);
    *reinterpret_cast<ushort4*>(o + base + quad * 4) = w0;        // d = quad*4+r
    *reinterpret_cast<ushort4*>(o + base + 16 + quad * 4) = w1;   // d = 16+quad*4+r
}

// ---------------- proj: [2048,256]x[256,256]^T -> bf16 ----------------
__global__ __launch_bounds__(256) void k_gemm_proj(const unsigned short* __restrict__ a_,
                                                   const unsigned short* __restrict__ w,
                                                   const float* __restrict__ bias,
                                                   unsigned short* __restrict__ y) {
    int wave = threadIdx.x >> 6, lane = threadIdx.x & 63, quad = lane >> 4, l16 = lane & 15;
    int m0 = blockIdx.x * 64 + wave * 16;
    int n0 = blockIdx.y * 64;
    const unsigned short* arow = a_ + (long long)(m0 + l16) * 256;
    f32x4 acc[4] = {};
    for (int kb = 0; kb < 256; kb += 32) {
        bf16x8 a = *reinterpret_cast<const bf16x8*>(arow + kb + quad * 8);
#pragma unroll
        for (int ni = 0; ni < 4; ni++) {
            bf16x8 bv = *reinterpret_cast<const bf16x8*>(w + (long long)(n0 + ni * 16 + l16) * 256 + kb + quad * 8);
            acc[ni] = MFMA16(a, bv, acc[ni]);
        }
    }
#pragma unroll
    for (int ni = 0; ni < 4; ni++) {
        int n = n0 + ni * 16 + l16;
        float bv = bias[n];
#pragma unroll
        for (int r = 0; r < 4; r++)
            y[(long long)(m0 + quad * 4 + r) * 256 + n] = f2bf(acc[ni][r] + bv);
    }
}

// ---------------- up-proj + fold + residual: x2 = x + fold(oproj @ w_up^T + b_up) ----------------
__global__ __launch_bounds__(256) void k_up_fold(const unsigned short* __restrict__ a_,
                                                 const unsigned short* __restrict__ w,
                                                 const float* __restrict__ bup,
                                                 const float* __restrict__ x,
                                                 float* __restrict__ out) {
    int wave = threadIdx.x >> 6, lane = threadIdx.x & 63, quad = lane >> 4, l16 = lane & 15;
    int m0 = blockIdx.x * 64 + wave * 16;
    int n0 = blockIdx.y * 64;
    const unsigned short* arow = a_ + (long long)(m0 + l16) * 256;
    f32x4 acc[4] = {};
    for (int kb = 0; kb < 256; kb += 32) {
        bf16x8 a = *reinterpret_cast<const bf16x8*>(arow + kb + quad * 8);
#pragma unroll
        for (int ni = 0; ni < 4; ni++) {
            bf16x8 bv = *reinterpret_cast<const bf16x8*>(w + (long long)(n0 + ni * 16 + l16) * 256 + kb + quad * 8);
            acc[ni] = MFMA16(a, bv, acc[ni]);
        }
    }
#pragma unroll
    for (int ni = 0; ni < 4; ni++) {
        int n = n0 + ni * 16 + l16;
        float bias = bup[n];
        int p0 = n >> 11, p1 = (n >> 8) & 7, c = n & 255;
#pragma unroll
        for (int r = 0; r < 4; r++) {
            int m = m0 + quad * 4 + r;
            int bb = m >> 10, r0 = (m >> 5) & 31, r1 = m & 31;
            long long addr = ((long long)bb << 24) + (long long)(r0 * 8 + p0) * 65536 + (r1 * 8 + p1) * 256 + c;
            out[addr] = x[addr] + acc[ni][r] + bias;
        }
    }
}

// ---------------- fused LN2 + MLP + residual, in-place on d_out ----------------
// v2 structure (proven local optimum: 316-320us, no spill). Added: T5
// s_setprio(1) around MFMA clusters -- the 2 independent blocks/CU are at
// different convoy phases (role diversity), so the MFMA-issuing block can
// win arbitration over the other block's load/VALU phase.
#define LP 264  // 256 + 8 pad: row stride 528 B -> bank step 4, 2-way max (free)
__global__ __launch_bounds__(512, 4) void k_mlp(float* __restrict__ xio,
                                                const float* __restrict__ g2,
                                                const float* __restrict__ b2,
                                                const unsigned short* __restrict__ w1,
                                                const float* __restrict__ bfc1,
                                                const unsigned short* __restrict__ w2,
                                                const float* __restrict__ bfc2) {
    __shared__ unsigned short Aln[64 * LP];
    __shared__ unsigned short Hc[64 * LP];
    int wave = threadIdx.x >> 6, lane = threadIdx.x & 63, quad = lane >> 4, l16 = lane & 15;
    long long m0 = (long long)blockIdx.x * 64;
    float4 gg = *reinterpret_cast<const float4*>(g2 + lane * 4);
    float4 bb = *reinterpret_cast<const float4*>(b2 + lane * 4);
#pragma unroll
    for (int i = 0; i < 8; i++) {
        int p = wave * 8 + i;
        float4 v = *reinterpret_cast<const float4*>(xio + (m0 + p) * 256 + lane * 4);
        float s = v.x + v.y + v.z + v.w;
        float s2 = v.x * v.x + v.y * v.y + v.z * v.z + v.w * v.w;
        s = wave_sum(s); s2 = wave_sum(s2);
        float mean = s * (1.f / 256.f);
        float rstd = rsqrtf(s2 * (1.f / 256.f) - mean * mean + 1e-5f);
        ushort4 o;
        o.x = f2bf((v.x - mean) * rstd * gg.x + bb.x);
        o.y = f2bf((v.y - mean) * rstd * gg.y + bb.y);
        o.z = f2bf((v.z - mean) * rstd * gg.z + bb.z);
        o.w = f2bf((v.w - mean) * rstd * gg.w + bb.w);
        *reinterpret_cast<ushort4*>(&Aln[p * LP + lane * 4]) = o;
    }
    __syncthreads();
    f32x4 acc2[4][2] = {};
    for (int ch = 0; ch < 4; ch++) {
        f32x4 acc1[4][2] = {};
        for (int kb = 0; kb < 256; kb += 32) {
            bf16x8 af[4];
#pragma unroll
            for (int mi = 0; mi < 4; mi++)
                af[mi] = *reinterpret_cast<const bf16x8*>(&Aln[(mi * 16 + l16) * LP + kb + quad * 8]);
#pragma unroll
            for (int ni = 0; ni < 2; ni++) {
                bf16x8 bv = *reinterpret_cast<const bf16x8*>(w1 + (long long)(ch * 256 + wave * 32 + ni * 16 + l16) * 256 + kb + quad * 8);
                __builtin_amdgcn_s_setprio(1);
#pragma unroll
                for (int mi = 0; mi < 4; mi++)
                    acc1[mi][ni] = MFMA16(af[mi], bv, acc1[mi][ni]);
                __builtin_amdgcn_s_setprio(0);
            }
        }
#pragma unroll
        for (int ni = 0; ni < 2; ni++) {
            int n = ch * 256 + wave * 32 + ni * 16 + l16;
            float bias = bfc1[n];
            int col = wave * 32 + ni * 16 + l16;
#pragma unroll
            for (int mi = 0; mi < 4; mi++) {
#pragma unroll
                for (int r = 0; r < 4; r++) {
                    float vv = acc1[mi][ni][r] + bias;
                    Hc[(mi * 16 + quad * 4 + r) * LP + col] = f2bf(gelu_fast(vv));
                }
            }
        }
        __syncthreads();
        for (int kb = 0; kb < 256; kb += 32) {
            bf16x8 af[4];
#pragma unroll
            for (int mi = 0; mi < 4; mi++)
                af[mi] = *reinterpret_cast<const bf16x8*>(&Hc[(mi * 16 + l16) * LP + kb + quad * 8]);
#pragma unroll
            for (int ni = 0; ni < 2; ni++) {
                bf16x8 bv = *reinterpret_cast<const bf16x8*>(w2 + (long long)(wave * 32 + ni * 16 + l16) * 1024 + ch * 256 + kb + quad * 8);
                __builtin_amdgcn_s_setprio(1);
#pragma unroll
                for (int mi = 0; mi < 4; mi++)
                    acc2[mi][ni] = MFMA16(af[mi], bv, acc2[mi][ni]);
                __builtin_amdgcn_s_setprio(0);
            }
        }
        __syncthreads();
    }
#pragma unroll
    for (int ni = 0; ni < 2; ni++) {
        int n = wave * 32 + ni * 16 + l16;
        float bias = bfc2[n];
#pragma unroll
        for (int mi = 0; mi < 4; mi++) {
#pragma unroll
            for (int r = 0; r < 4; r++) {
                long long row = m0 + mi * 16 + quad * 4 + r;
                float xv = xio[row * 256 + n];
                xio[row * 256 + n] = xv + acc2[mi][ni][r] + bias;
            }
        }
    }
}

extern "C" void kernel_launch(void* const* d_in, const int* in_sizes, int n_in,
                              void* d_out, int out_size, void* d_ws, size_t ws_size,
                              hipStream_t stream) {
    const float* x      = (const float*)d_in[0];
    const float* ln1_g  = (const float*)d_in[1];
    const float* ln1_b  = (const float*)d_in[2];
    const float* ln2_g  = (const float*)d_in[3];
    const float* ln2_b  = (const float*)d_in[4];
    const float* rpe    = (const float*)d_in[5];
    const float* w_down = (const float*)d_in[6];
    const float* b_down = (const float*)d_in[7];
    const float* w_up   = (const float*)d_in[8];
    const float* b_up   = (const float*)d_in[9];
    const float* w_qkv  = (const float*)d_in[10];
    const float* b_qkv  = (const float*)d_in[11];
    const float* w_proj = (const float*)d_in[12];
    const float* b_proj = (const float*)d_in[13];
    const float* w_fc1  = (const float*)d_in[14];
    const float* b_fc1  = (const float*)d_in[15];
    const float* w_fc2  = (const float*)d_in[16];
    const float* b_fc2  = (const float*)d_in[17];
    float* out = (float*)d_out;

    char* wp = (char*)d_ws;
    auto alloc = [&](size_t bytes) { void* p = (void*)wp; wp += (bytes + 255) & ~(size_t)255; return p; };
    unsigned short* wdown_bf = (unsigned short*)alloc(4194304 * 2);
    unsigned short* wup_bf   = (unsigned short*)alloc(4194304 * 2);
    unsigned short* wqkv_bf  = (unsigned short*)alloc(196608 * 2);
    unsigned short* wproj_bf = (unsigned short*)alloc(65536 * 2);
    unsigned short* wfc1_bf  = (unsigned short*)alloc(262144 * 2);
    unsigned short* wfc2_bf  = (unsigned short*)alloc(262144 * 2);
    unsigned short* ydown    = (unsigned short*)alloc(524288 * 2);
    unsigned short* qb       = (unsigned short*)alloc(524288 * 2);
    unsigned short* kb       = (unsigned short*)alloc(524288 * 2);
    unsigned short* vT       = (unsigned short*)alloc(524288 * 2);
    unsigned short* obf      = (unsigned short*)alloc(524288 * 2);
    unsigned short* oproj    = (unsigned short*)alloc(524288 * 2);

    // Big temporaries live inside d_out (134.2 MB); all dead before k_up_fold
    // overwrites the whole buffer with x2.
    //   xln:  [0, 67.1 MB)        -- dead after k_gemm_down2
    //   part: [100.7, 134.2 MB)   -- 16 x 2 MB fp32 split-K partials
    unsigned short* xln = (unsigned short*)d_out;
    float* part         = (float*)((char*)d_out + 100663296);

    // one preamble launch: 8960 cvt blocks + 32768 LN blocks
    k_pre<<<41728, 256, 0, stream>>>(w_down, w_up, w_qkv, w_proj, w_fc1, w_fc2,
                                     wdown_bf, wup_bf, wqkv_bf, wproj_bf, wfc1_bf, wfc2_bf,
                                     x, ln1_g, ln1_b, xln);
    k_gemm_down2<<<dim3(16, 2, 16), 256, 0, stream>>>(xln, wdown_bf, part);
    k_red<<<512, 256, 0, stream>>>(part, b_down, ydown);
    k_gemm_qkv<<<dim3(32, 12), 256, 0, stream>>>(ydown, wqkv_bf, b_qkv, qb, kb, vT);
    k_attn<<<dim3(16, 16), 256, 0, stream>>>(qb, kb, vT, rpe, obf);
    k_gemm_proj<<<dim3(32, 4), 256, 0, stream>>>(obf, wproj_bf, b_proj, oproj);
    k_up_fold<<<dim3(32, 256), 256, 0, stream>>>(oproj, wup_bf, b_up, x, out);
    k_mlp<<<2048, 512, 0, stream>>>(out, ln2_g, ln2_b, wfc1_bf, b_fc1, wfc2_bf, b_fc2);
}

// Round 7
// 506.262 us; speedup vs baseline: 2.0764x; 1.2006x over previous
//
#include <hip/hip_runtime.h>

typedef __attribute__((ext_vector_type(8))) __bf16 bf16x8;
typedef __attribute__((ext_vector_type(4))) float f32x4;

#define MFMA16(a, b, c) __builtin_amdgcn_mfma_f32_16x16x32_bf16((a), (b), (c), 0, 0, 0)

// async global->LDS, 16B per lane; LDS dest = wave-uniform base + lane*16
#define ASYNC16(g, l) __builtin_amdgcn_global_load_lds( \
    (const __attribute__((address_space(1))) unsigned int*)(g), \
    (__attribute__((address_space(3))) unsigned int*)(l), 16, 0, 0)

// fp32 -> bf16 RTNE via compiler cast
__device__ __forceinline__ unsigned short f2bf(float f) {
    return __builtin_bit_cast(unsigned short, (__bf16)f);
}

__device__ __forceinline__ float wave_sum(float v) {
#pragma unroll
    for (int off = 32; off; off >>= 1) v += __shfl_xor(v, off, 64);
    return v;
}

// tanh-form GELU: x*sigmoid(1.5957691x + 0.0713548x^3).
__device__ __forceinline__ float gelu_fast(float v) {
    float z = v * fmaf(v * v, 0.0713548162f, 1.5957691216f);
    float e = __expf(-z);
    return v * __builtin_amdgcn_rcpf(1.f + e);
}

// ---------------- fused preamble: all 6 weight casts + LN1, one launch ----------------
__global__ __launch_bounds__(256) void k_pre(const float* __restrict__ wdown, const float* __restrict__ wup,
                                             const float* __restrict__ wqkv, const float* __restrict__ wproj,
                                             const float* __restrict__ wfc1, const float* __restrict__ wfc2,
                                             unsigned short* __restrict__ dwdown, unsigned short* __restrict__ dwup,
                                             unsigned short* __restrict__ dwqkv, unsigned short* __restrict__ dwproj,
                                             unsigned short* __restrict__ dwfc1, unsigned short* __restrict__ dwfc2,
                                             const float* __restrict__ x, const float* __restrict__ g,
                                             const float* __restrict__ b, unsigned short* __restrict__ xln) {
    int bid = blockIdx.x;
    if (bid < 8960) {
        int i = (bid * 256 + threadIdx.x) * 4;
        const float* s; unsigned short* d; int off;
        if (i < 4194304)      { s = wdown; d = dwdown; off = i; }
        else if (i < 8388608) { s = wup;   d = dwup;   off = i - 4194304; }
        else if (i < 8585216) { s = wqkv;  d = dwqkv;  off = i - 8388608; }
        else if (i < 8650752) { s = wproj; d = dwproj; off = i - 8585216; }
        else if (i < 8912896) { s = wfc1;  d = dwfc1;  off = i - 8650752; }
        else                  { s = wfc2;  d = dwfc2;  off = i - 8912896; }
        float4 v = *reinterpret_cast<const float4*>(s + off);
        ushort4 o;
        o.x = f2bf(v.x); o.y = f2bf(v.y); o.z = f2bf(v.z); o.w = f2bf(v.w);
        *reinterpret_cast<ushort4*>(d + off) = o;
    } else {
        int wave = threadIdx.x >> 6, lane = threadIdx.x & 63;
        long long pix = (long long)(bid - 8960) * 4 + wave;
        const float* row = x + pix * 256;
        float4 v = *reinterpret_cast<const float4*>(row + lane * 4);
        float s = v.x + v.y + v.z + v.w;
        float s2 = v.x * v.x + v.y * v.y + v.z * v.z + v.w * v.w;
        s = wave_sum(s); s2 = wave_sum(s2);
        float mean = s * (1.f / 256.f);
        float rstd = rsqrtf(s2 * (1.f / 256.f) - mean * mean + 1e-5f);
        float4 gg = *reinterpret_cast<const float4*>(g + lane * 4);
        float4 bb = *reinterpret_cast<const float4*>(b + lane * 4);
        ushort4 ov;
        ov.x = f2bf((v.x - mean) * rstd * gg.x + bb.x);
        ov.y = f2bf((v.y - mean) * rstd * gg.y + bb.y);
        ov.z = f2bf((v.z - mean) * rstd * gg.z + bb.z);
        ov.w = f2bf((v.w - mean) * rstd * gg.w + bb.w);
        *reinterpret_cast<ushort4*>(xln + pix * 256 + lane * 4) = ov;
    }
}

// ---------------- down-proj v2: split-K(16) 128x128 LDS-staged MFMA GEMM ----------------
__global__ __launch_bounds__(256, 2) void k_gemm_down2(const unsigned short* __restrict__ xln,
                                                       const unsigned short* __restrict__ wd,
                                                       float* __restrict__ part) {
    __shared__ alignas(16) unsigned short As[128 * 64];
    __shared__ alignas(16) unsigned short Bs[128 * 64];
    int wave = threadIdx.x >> 6, lane = threadIdx.x & 63, quad = lane >> 4, l16 = lane & 15;
    int mt = blockIdx.x * 128, nt = blockIdx.y * 128, k0 = blockIdx.z * 1024;
    int wm = wave & 1, wn = wave >> 1;
    int srow = wave * 32 + (lane >> 3);   // staging row (+ i*8)
    int schunk = lane & 7;                // 16B chunk within 128B row
    f32x4 acc[4][4] = {};
    for (int s = 0; s < 16; s++) {
        int kg = k0 + s * 64;
        int p0 = kg >> 11, p1 = (kg >> 8) & 7, cbase = kg & 255;
#pragma unroll
        for (int i = 0; i < 4; i++) {
            int row = srow + i * 8;
            int m = mt + row;
            int bb = m >> 10, r0 = (m >> 5) & 31, r1 = m & 31;
            int c = cbase + ((schunk ^ (row & 7)) << 3);
            const unsigned short* g = xln +
                ((((long long)(bb * 256 + r0 * 8 + p0)) * 256 + (r1 * 8 + p1)) << 8) + c;
            ASYNC16(g, &As[(wave * 32 + i * 8) * 64]);
        }
#pragma unroll
        for (int i = 0; i < 4; i++) {
            int row = srow + i * 8;
            int n = nt + row;
            const unsigned short* g = wd + (long long)n * 16384 + kg + ((schunk ^ (row & 7)) << 3);
            ASYNC16(g, &Bs[(wave * 32 + i * 8) * 64]);
        }
        __syncthreads();
#pragma unroll
        for (int sub = 0; sub < 2; sub++) {
            int c = sub * 4 + quad;
            bf16x8 af[4], bfr[4];
#pragma unroll
            for (int mi = 0; mi < 4; mi++) {
                int row = wm * 64 + mi * 16 + l16;
                af[mi] = *reinterpret_cast<const bf16x8*>(&As[row * 64 + ((c ^ (row & 7)) << 3)]);
            }
#pragma unroll
            for (int ni = 0; ni < 4; ni++) {
                int row = wn * 64 + ni * 16 + l16;
                bfr[ni] = *reinterpret_cast<const bf16x8*>(&Bs[row * 64 + ((c ^ (row & 7)) << 3)]);
            }
#pragma unroll
            for (int mi = 0; mi < 4; mi++)
#pragma unroll
                for (int ni = 0; ni < 4; ni++)
                    acc[mi][ni] = MFMA16(af[mi], bfr[ni], acc[mi][ni]);
        }
        __syncthreads();
    }
    float* pb = part + (long long)blockIdx.z * 524288;
#pragma unroll
    for (int mi = 0; mi < 4; mi++)
#pragma unroll
        for (int ni = 0; ni < 4; ni++) {
            int n = nt + wn * 64 + ni * 16 + l16;
#pragma unroll
            for (int r = 0; r < 4; r++) {
                int m = mt + wm * 64 + mi * 16 + quad * 4 + r;
                pb[(long long)m * 256 + n] = acc[mi][ni][r];
            }
        }
}

// ---------------- split-K reduce + bias + bf16 ----------------
__global__ __launch_bounds__(256) void k_red(const float* __restrict__ part,
                                             const float* __restrict__ bd,
                                             unsigned short* __restrict__ y) {
    int i = (blockIdx.x * 256 + threadIdx.x) * 4;
    float4 s = {0.f, 0.f, 0.f, 0.f};
#pragma unroll
    for (int p = 0; p < 16; p++) {
        float4 v = *reinterpret_cast<const float4*>(part + (long long)p * 524288 + i);
        s.x += v.x; s.y += v.y; s.z += v.z; s.w += v.w;
    }
    int n = i & 255;
    float4 bb = *reinterpret_cast<const float4*>(bd + n);
    ushort4 o;
    o.x = f2bf(s.x + bb.x); o.y = f2bf(s.y + bb.y);
    o.z = f2bf(s.z + bb.z); o.w = f2bf(s.w + bb.w);
    *reinterpret_cast<ushort4*>(y + i) = o;
}

// ---------------- qkv: [2048,256]x[768,256]^T, scatter to q, k, v^T (bf16) ----------------
__global__ __launch_bounds__(256) void k_gemm_qkv(const unsigned short* __restrict__ yd,
                                                  const unsigned short* __restrict__ wq,
                                                  const float* __restrict__ bq,
                                                  unsigned short* __restrict__ q,
                                                  unsigned short* __restrict__ k,
                                                  unsigned short* __restrict__ vT) {
    int wave = threadIdx.x >> 6, lane = threadIdx.x & 63, quad = lane >> 4, l16 = lane & 15;
    int m0 = blockIdx.x * 64 + wave * 16;
    int n0 = blockIdx.y * 64;
    const unsigned short* arow = yd + (long long)(m0 + l16) * 256;
    f32x4 acc[4] = {};
    for (int kb = 0; kb < 256; kb += 32) {
        bf16x8 a = *reinterpret_cast<const bf16x8*>(arow + kb + quad * 8);
#pragma unroll
        for (int ni = 0; ni < 4; ni++) {
            bf16x8 bv = *reinterpret_cast<const bf16x8*>(wq + (long long)(n0 + ni * 16 + l16) * 256 + kb + quad * 8);
            acc[ni] = MFMA16(a, bv, acc[ni]);
        }
    }
#pragma unroll
    for (int ni = 0; ni < 4; ni++) {
        int n = n0 + ni * 16 + l16;
        float bias = bq[n];
        int t = n >> 8, h = (n >> 5) & 7, d = n & 31;
#pragma unroll
        for (int r = 0; r < 4; r++) {
            int m = m0 + quad * 4 + r;
            int bh = ((m >> 10) << 3) | h;
            int l = m & 1023;
            unsigned short val = f2bf(acc[ni][r] + bias);
            if (t == 0)      q[((long long)bh * 1024 + l) * 32 + d] = val;
            else if (t == 1) k[((long long)bh * 1024 + l) * 32 + d] = val;
            else             vT[((long long)bh * 32 + d) * 1024 + l] = val;
        }
    }
}

// ---------------- fused flash attention: S=scale*qk^T+rpe, softmax, O=P@V ----------------
__global__ __launch_bounds__(256) void k_attn(const unsigned short* __restrict__ q,
                                              const unsigned short* __restrict__ k,
                                              const unsigned short* __restrict__ vT,
                                              const float* __restrict__ rpe,
                                              unsigned short* __restrict__ o) {
    __shared__ alignas(16) char Pl[4][16 * 128];   // per-wave [16 qi][64 kj] bf16, swizzled
    int wave = threadIdx.x >> 6, lane = threadIdx.x & 63, quad = lane >> 4, l16 = lane & 15;
    int bh = blockIdx.y, h = bh & 7;
    int m0 = blockIdx.x * 64 + wave * 16;
    const unsigned short* qb = q + (long long)bh * 32768;
    const unsigned short* kb = k + (long long)bh * 32768;
    const unsigned short* vb = vT + (long long)bh * 32768;
    char* pl = Pl[wave];
    const float scale = 0.17677669529663687f;  // 1/sqrt(32)
    int qi = m0 + l16;
    int qi0 = qi >> 5, qi1 = qi & 31;
    bf16x8 bq = *reinterpret_cast<const bf16x8*>(qb + qi * 32 + quad * 8);
    f32x4 o0 = {0.f, 0.f, 0.f, 0.f}, o1 = {0.f, 0.f, 0.f, 0.f};
    float m_run = -3.0e38f, l_run = 0.f;
    int swz = (l16 & 7) << 4;
    for (int t = 0; t < 16; t++) {
        // S^T tile: D[kj = t*64+ni*16+quad*4+r][qi = m0+l16]
        f32x4 st[4];
        __builtin_amdgcn_s_setprio(1);
#pragma unroll
        for (int ni = 0; ni < 4; ni++) {
            bf16x8 ak = *reinterpret_cast<const bf16x8*>(kb + (t * 64 + ni * 16 + l16) * 32 + quad * 8);
            f32x4 z = {0.f, 0.f, 0.f, 0.f};
            st[ni] = MFMA16(ak, bq, z);
        }
        __builtin_amdgcn_s_setprio(0);
        float vals[16];
        float tmax = -3.0e38f;
#pragma unroll
        for (int ni = 0; ni < 4; ni++)
#pragma unroll
            for (int r = 0; r < 4; r++) {
                int kj = t * 64 + ni * 16 + quad * 4 + r;
                int kj0 = kj >> 5, kj1 = kj & 31;
                int idx = (qi0 - kj0 + 31) * 63 + (qi1 - kj1 + 31);
                float sv = st[ni][r] * scale + rpe[idx * 8 + h];
                vals[ni * 4 + r] = sv;
                tmax = fmaxf(tmax, sv);
            }
        tmax = fmaxf(tmax, __shfl_xor(tmax, 16, 64));
        tmax = fmaxf(tmax, __shfl_xor(tmax, 32, 64));
        float m_new = fmaxf(m_run, tmax);
        float fac = __expf(m_run - m_new);
        float tsum = 0.f;
#pragma unroll
        for (int ni = 0; ni < 4; ni++) {
            ushort4 w4;
            float p0v = __expf(vals[ni * 4 + 0] - m_new);
            float p1v = __expf(vals[ni * 4 + 1] - m_new);
            float p2v = __expf(vals[ni * 4 + 2] - m_new);
            float p3v = __expf(vals[ni * 4 + 3] - m_new);
            tsum += p0v + p1v + p2v + p3v;
            w4.x = f2bf(p0v); w4.y = f2bf(p1v); w4.z = f2bf(p2v); w4.w = f2bf(p3v);
            *reinterpret_cast<ushort4*>(pl + l16 * 128 + ((ni * 32 + quad * 8) ^ swz)) = w4;
        }
        tsum += __shfl_xor(tsum, 16, 64);
        tsum += __shfl_xor(tsum, 32, 64);
        l_run = l_run * fac + tsum;
        m_run = m_new;
#pragma unroll
        for (int r = 0; r < 4; r++) { o0[r] *= fac; o1[r] *= fac; }
#pragma unroll
        for (int kk = 0; kk < 2; kk++) {
            bf16x8 pb = *reinterpret_cast<const bf16x8*>(pl + l16 * 128 + ((kk * 64 + quad * 16) ^ swz));
            bf16x8 av0 = *reinterpret_cast<const bf16x8*>(vb + (long long)(l16) * 1024 + t * 64 + kk * 32 + quad * 8);
            bf16x8 av1 = *reinterpret_cast<const bf16x8*>(vb + (long long)(16 + l16) * 1024 + t * 64 + kk * 32 + quad * 8);
            __builtin_amdgcn_s_setprio(1);
            o0 = MFMA16(av0, pb, o0);
            o1 = MFMA16(av1, pb, o1);
            __builtin_amdgcn_s_setprio(0);
        }
    }
    float inv = 1.f / l_run;
    int b_ = bh >> 3;
    long long base = ((long long)(b_ * 1024 + qi)) * 256 + h * 32;
    ushort4 w0, w1;
    w0.x = f2bf(o0[0] * inv); w0.y = f2bf(o0[1] * inv);
    w0.z = f2bf(o0[2] * inv); w0.w = f2bf(o0[3] * inv);
    w1.x = f2bf(o1[0] * inv); w1.y = f2bf(o1[1] * inv);
    w1.z = f2bf(o1[2] * inv); w1.w = f2bf(o1[3] * inv);
    *reinterpret_cast<ushort4*>(o + base + quad * 4) = w0;
    *reinterpret_cast<ushort4*>(o + base + 16 + quad * 4) = w1;
}

// ---------------- proj: [2048,256]x[256,256]^T -> bf16 ----------------
__global__ __launch_bounds__(256) void k_gemm_proj(const unsigned short* __restrict__ a_,
                                                   const unsigned short* __restrict__ w,
                                                   const float* __restrict__ bias,
                                                   unsigned short* __restrict__ y) {
    int wave = threadIdx.x >> 6, lane = threadIdx.x & 63, quad = lane >> 4, l16 = lane & 15;
    int m0 = blockIdx.x * 64 + wave * 16;
    int n0 = blockIdx.y * 64;
    const unsigned short* arow = a_ + (long long)(m0 + l16) * 256;
    f32x4 acc[4] = {};
    for (int kb = 0; kb < 256; kb += 32) {
        bf16x8 a = *reinterpret_cast<const bf16x8*>(arow + kb + quad * 8);
#pragma unroll
        for (int ni = 0; ni < 4; ni++) {
            bf16x8 bv = *reinterpret_cast<const bf16x8*>(w + (long long)(n0 + ni * 16 + l16) * 256 + kb + quad * 8);
            acc[ni] = MFMA16(a, bv, acc[ni]);
        }
    }
#pragma unroll
    for (int ni = 0; ni < 4; ni++) {
        int n = n0 + ni * 16 + l16;
        float bv = bias[n];
#pragma unroll
        for (int r = 0; r < 4; r++)
            y[(long long)(m0 + quad * 4 + r) * 256 + n] = f2bf(acc[ni][r] + bv);
    }
}

// ---------------- up-proj + fold + residual v2: LDS-staged weight panel ----------------
// Old version was L2-issue-bound (~170-200 TF): per wave 32 global B-loads : 32
// MFMA, weights re-read 32x (~268 MB L2/L3). v2: each block stages its whole
// 128n x 256k weight panel (64 KB) into LDS ONCE (down2-style pre-swizzled
// source, rule 21: swizzle both sides or neither), then streams 512 m-rows of
// L2-resident oproj against it. Per kb-step: 1 A-load + 8 ds_read_b128 +
// 8 MFMA. Weight traffic 268 -> 33.6 MB; HBM floor = x read + out write =
// 268 MB fp32 (~43 us).
__global__ __launch_bounds__(256) void k_up_fold(const unsigned short* __restrict__ a_,
                                                 const unsigned short* __restrict__ w,
                                                 const float* __restrict__ bup,
                                                 const float* __restrict__ x,
                                                 float* __restrict__ out) {
    __shared__ alignas(16) unsigned short Bs[128 * 256];   // 64 KB
    int wave = threadIdx.x >> 6, lane = threadIdx.x & 63, quad = lane >> 4, l16 = lane & 15;
    int n0 = blockIdx.x * 128;
    int mbase = blockIdx.y * 512;
    // stage weight panel: 16 ASYNC16/wave; each issue fills 2 rows (1024 B).
    // LDS linear; global chunk pre-swizzled: LDS[r][cc] holds global chunk cc^(r&7).
#pragma unroll
    for (int i = 0; i < 16; i++) {
        int R = i * 8 + wave * 2;                 // wave-uniform row base
        int r = R + (lane >> 5);                  // this lane's row
        int cg = (lane & 31) ^ (r & 7);           // pre-swizzled 16B-chunk in global
        const unsigned short* g = w + (long long)(n0 + r) * 256 + cg * 8;
        ASYNC16(g, &Bs[R * 256]);
    }
    __syncthreads();
    // hoist per-n epilogue constants (n independent of s)
    float bias8[8];
#pragma unroll
    for (int ni = 0; ni < 8; ni++) bias8[ni] = bup[n0 + ni * 16 + l16];
    for (int s = 0; s < 8; s++) {
        int mr = mbase + s * 64 + wave * 16;
        const unsigned short* arow = a_ + (long long)(mr + l16) * 256;
        f32x4 acc[8] = {};
#pragma unroll
        for (int kb = 0; kb < 8; kb++) {
            bf16x8 a = *reinterpret_cast<const bf16x8*>(arow + kb * 32 + quad * 8);
#pragma unroll
            for (int ni = 0; ni < 8; ni++) {
                int nr = ni * 16 + l16;
                bf16x8 bv = *reinterpret_cast<const bf16x8*>(
                    &Bs[nr * 256 + (((kb * 4 + quad) ^ (nr & 7)) << 3)]);
                acc[ni] = MFMA16(a, bv, acc[ni]);
            }
        }
#pragma unroll
        for (int ni = 0; ni < 8; ni++) {
            int n = n0 + ni * 16 + l16;
            int p0 = n >> 11, p1 = (n >> 8) & 7, c = n & 255;
#pragma unroll
            for (int r = 0; r < 4; r++) {
                int m = mr + quad * 4 + r;
                int bb = m >> 10, r0 = (m >> 5) & 31, r1 = m & 31;
                long long addr = ((long long)bb << 24) + (long long)(r0 * 8 + p0) * 65536 + (r1 * 8 + p1) * 256 + c;
                out[addr] = x[addr] + acc[ni][r] + bias8[ni];
            }
        }
    }
}

// ---------------- fused LN2 + MLP + residual, in-place on d_out ----------------
// v2 structure (proven local optimum: 316-320us, no spill). setprio kept
// (measured null-neutral).
#define LP 264  // 256 + 8 pad: row stride 528 B -> bank step 4, 2-way max (free)
__global__ __launch_bounds__(512, 4) void k_mlp(float* __restrict__ xio,
                                                const float* __restrict__ g2,
                                                const float* __restrict__ b2,
                                                const unsigned short* __restrict__ w1,
                                                const float* __restrict__ bfc1,
                                                const unsigned short* __restrict__ w2,
                                                const float* __restrict__ bfc2) {
    __shared__ unsigned short Aln[64 * LP];
    __shared__ unsigned short Hc[64 * LP];
    int wave = threadIdx.x >> 6, lane = threadIdx.x & 63, quad = lane >> 4, l16 = lane & 15;
    long long m0 = (long long)blockIdx.x * 64;
    float4 gg = *reinterpret_cast<const float4*>(g2 + lane * 4);
    float4 bb = *reinterpret_cast<const float4*>(b2 + lane * 4);
#pragma unroll
    for (int i = 0; i < 8; i++) {
        int p = wave * 8 + i;
        float4 v = *reinterpret_cast<const float4*>(xio + (m0 + p) * 256 + lane * 4);
        float s = v.x + v.y + v.z + v.w;
        float s2 = v.x * v.x + v.y * v.y + v.z * v.z + v.w * v.w;
        s = wave_sum(s); s2 = wave_sum(s2);
        float mean = s * (1.f / 256.f);
        float rstd = rsqrtf(s2 * (1.f / 256.f) - mean * mean + 1e-5f);
        ushort4 o;
        o.x = f2bf((v.x - mean) * rstd * gg.x + bb.x);
        o.y = f2bf((v.y - mean) * rstd * gg.y + bb.y);
        o.z = f2bf((v.z - mean) * rstd * gg.z + bb.z);
        o.w = f2bf((v.w - mean) * rstd * gg.w + bb.w);
        *reinterpret_cast<ushort4*>(&Aln[p * LP + lane * 4]) = o;
    }
    __syncthreads();
    f32x4 acc2[4][2] = {};
    for (int ch = 0; ch < 4; ch++) {
        f32x4 acc1[4][2] = {};
        for (int kb = 0; kb < 256; kb += 32) {
            bf16x8 af[4];
#pragma unroll
            for (int mi = 0; mi < 4; mi++)
                af[mi] = *reinterpret_cast<const bf16x8*>(&Aln[(mi * 16 + l16) * LP + kb + quad * 8]);
#pragma unroll
            for (int ni = 0; ni < 2; ni++) {
                bf16x8 bv = *reinterpret_cast<const bf16x8*>(w1 + (long long)(ch * 256 + wave * 32 + ni * 16 + l16) * 256 + kb + quad * 8);
                __builtin_amdgcn_s_setprio(1);
#pragma unroll
                for (int mi = 0; mi < 4; mi++)
                    acc1[mi][ni] = MFMA16(af[mi], bv, acc1[mi][ni]);
                __builtin_amdgcn_s_setprio(0);
            }
        }
#pragma unroll
        for (int ni = 0; ni < 2; ni++) {
            int n = ch * 256 + wave * 32 + ni * 16 + l16;
            float bias = bfc1[n];
            int col = wave * 32 + ni * 16 + l16;
#pragma unroll
            for (int mi = 0; mi < 4; mi++) {
#pragma unroll
                for (int r = 0; r < 4; r++) {
                    float vv = acc1[mi][ni][r] + bias;
                    Hc[(mi * 16 + quad * 4 + r) * LP + col] = f2bf(gelu_fast(vv));
                }
            }
        }
        __syncthreads();
        for (int kb = 0; kb < 256; kb += 32) {
            bf16x8 af[4];
#pragma unroll
            for (int mi = 0; mi < 4; mi++)
                af[mi] = *reinterpret_cast<const bf16x8*>(&Hc[(mi * 16 + l16) * LP + kb + quad * 8]);
#pragma unroll
            for (int ni = 0; ni < 2; ni++) {
                bf16x8 bv = *reinterpret_cast<const bf16x8*>(w2 + (long long)(wave * 32 + ni * 16 + l16) * 1024 + ch * 256 + kb + quad * 8);
                __builtin_amdgcn_s_setprio(1);
#pragma unroll
                for (int mi = 0; mi < 4; mi++)
                    acc2[mi][ni] = MFMA16(af[mi], bv, acc2[mi][ni]);
                __builtin_amdgcn_s_setprio(0);
            }
        }
        __syncthreads();
    }
#pragma unroll
    for (int ni = 0; ni < 2; ni++) {
        int n = wave * 32 + ni * 16 + l16;
        float bias = bfc2[n];
#pragma unroll
        for (int mi = 0; mi < 4; mi++) {
#pragma unroll
            for (int r = 0; r < 4; r++) {
                long long row = m0 + mi * 16 + quad * 4 + r;
                float xv = xio[row * 256 + n];
                xio[row * 256 + n] = xv + acc2[mi][ni][r] + bias;
            }
        }
    }
}

extern "C" void kernel_launch(void* const* d_in, const int* in_sizes, int n_in,
                              void* d_out, int out_size, void* d_ws, size_t ws_size,
                              hipStream_t stream) {
    const float* x      = (const float*)d_in[0];
    const float* ln1_g  = (const float*)d_in[1];
    const float* ln1_b  = (const float*)d_in[2];
    const float* ln2_g  = (const float*)d_in[3];
    const float* ln2_b  = (const float*)d_in[4];
    const float* rpe    = (const float*)d_in[5];
    const float* w_down = (const float*)d_in[6];
    const float* b_down = (const float*)d_in[7];
    const float* w_up   = (const float*)d_in[8];
    const float* b_up   = (const float*)d_in[9];
    const float* w_qkv  = (const float*)d_in[10];
    const float* b_qkv  = (const float*)d_in[11];
    const float* w_proj = (const float*)d_in[12];
    const float* b_proj = (const float*)d_in[13];
    const float* w_fc1  = (const float*)d_in[14];
    const float* b_fc1  = (const float*)d_in[15];
    const float* w_fc2  = (const float*)d_in[16];
    const float* b_fc2  = (const float*)d_in[17];
    float* out = (float*)d_out;

    char* wp = (char*)d_ws;
    auto alloc = [&](size_t bytes) { void* p = (void*)wp; wp += (bytes + 255) & ~(size_t)255; return p; };
    unsigned short* wdown_bf = (unsigned short*)alloc(4194304 * 2);
    unsigned short* wup_bf   = (unsigned short*)alloc(4194304 * 2);
    unsigned short* wqkv_bf  = (unsigned short*)alloc(196608 * 2);
    unsigned short* wproj_bf = (unsigned short*)alloc(65536 * 2);
    unsigned short* wfc1_bf  = (unsigned short*)alloc(262144 * 2);
    unsigned short* wfc2_bf  = (unsigned short*)alloc(262144 * 2);
    unsigned short* ydown    = (unsigned short*)alloc(524288 * 2);
    unsigned short* qb       = (unsigned short*)alloc(524288 * 2);
    unsigned short* kb       = (unsigned short*)alloc(524288 * 2);
    unsigned short* vT       = (unsigned short*)alloc(524288 * 2);
    unsigned short* obf      = (unsigned short*)alloc(524288 * 2);
    unsigned short* oproj    = (unsigned short*)alloc(524288 * 2);

    // Big temporaries live inside d_out (134.2 MB); all dead before k_up_fold
    // overwrites the whole buffer with x2.
    //   xln:  [0, 67.1 MB)        -- dead after k_gemm_down2
    //   part: [100.7, 134.2 MB)   -- 16 x 2 MB fp32 split-K partials
    unsigned short* xln = (unsigned short*)d_out;
    float* part         = (float*)((char*)d_out + 100663296);

    // one preamble launch: 8960 cvt blocks + 32768 LN blocks
    k_pre<<<41728, 256, 0, stream>>>(w_down, w_up, w_qkv, w_proj, w_fc1, w_fc2,
                                     wdown_bf, wup_bf, wqkv_bf, wproj_bf, wfc1_bf, wfc2_bf,
                                     x, ln1_g, ln1_b, xln);
    k_gemm_down2<<<dim3(16, 2, 16), 256, 0, stream>>>(xln, wdown_bf, part);
    k_red<<<512, 256, 0, stream>>>(part, b_down, ydown);
    k_gemm_qkv<<<dim3(32, 12), 256, 0, stream>>>(ydown, wqkv_bf, b_qkv, qb, kb, vT);
    k_attn<<<dim3(16, 16), 256, 0, stream>>>(qb, kb, vT, rpe, obf);
    k_gemm_proj<<<dim3(32, 4), 256, 0, stream>>>(obf, wproj_bf, b_proj, oproj);
    k_up_fold<<<dim3(128, 4), 256, 0, stream>>>(oproj, wup_bf, b_up, x, out);
    k_mlp<<<2048, 512, 0, stream>>>(out, ln2_g, ln2_b, wfc1_bf, b_fc1, wfc2_bf, b_fc2);
}

// Round 8
// 504.934 us; speedup vs baseline: 2.0819x; 1.0026x over previous
//
#include <hip/hip_runtime.h>

typedef __attribute__((ext_vector_type(8))) __bf16 bf16x8;
typedef __attribute__((ext_vector_type(4))) float f32x4;

#define MFMA16(a, b, c) __builtin_amdgcn_mfma_f32_16x16x32_bf16((a), (b), (c), 0, 0, 0)

// async global->LDS, 16B per lane; LDS dest = wave-uniform base + lane*16
#define ASYNC16(g, l) __builtin_amdgcn_global_load_lds( \
    (const __attribute__((address_space(1))) unsigned int*)(g), \
    (__attribute__((address_space(3))) unsigned int*)(l), 16, 0, 0)

// fp32 -> bf16 RTNE via compiler cast
__device__ __forceinline__ unsigned short f2bf(float f) {
    return __builtin_bit_cast(unsigned short, (__bf16)f);
}

__device__ __forceinline__ float wave_sum(float v) {
#pragma unroll
    for (int off = 32; off; off >>= 1) v += __shfl_xor(v, off, 64);
    return v;
}

// tanh-form GELU: x*sigmoid(1.5957691x + 0.0713548x^3).
__device__ __forceinline__ float gelu_fast(float v) {
    float z = v * fmaf(v * v, 0.0713548162f, 1.5957691216f);
    float e = __expf(-z);
    return v * __builtin_amdgcn_rcpf(1.f + e);
}

// ---------------- fused preamble: all 6 weight casts + LN1, one launch ----------------
__global__ __launch_bounds__(256) void k_pre(const float* __restrict__ wdown, const float* __restrict__ wup,
                                             const float* __restrict__ wqkv, const float* __restrict__ wproj,
                                             const float* __restrict__ wfc1, const float* __restrict__ wfc2,
                                             unsigned short* __restrict__ dwdown, unsigned short* __restrict__ dwup,
                                             unsigned short* __restrict__ dwqkv, unsigned short* __restrict__ dwproj,
                                             unsigned short* __restrict__ dwfc1, unsigned short* __restrict__ dwfc2,
                                             const float* __restrict__ x, const float* __restrict__ g,
                                             const float* __restrict__ b, unsigned short* __restrict__ xln) {
    int bid = blockIdx.x;
    if (bid < 8960) {
        int i = (bid * 256 + threadIdx.x) * 4;
        const float* s; unsigned short* d; int off;
        if (i < 4194304)      { s = wdown; d = dwdown; off = i; }
        else if (i < 8388608) { s = wup;   d = dwup;   off = i - 4194304; }
        else if (i < 8585216) { s = wqkv;  d = dwqkv;  off = i - 8388608; }
        else if (i < 8650752) { s = wproj; d = dwproj; off = i - 8585216; }
        else if (i < 8912896) { s = wfc1;  d = dwfc1;  off = i - 8650752; }
        else                  { s = wfc2;  d = dwfc2;  off = i - 8912896; }
        float4 v = *reinterpret_cast<const float4*>(s + off);
        ushort4 o;
        o.x = f2bf(v.x); o.y = f2bf(v.y); o.z = f2bf(v.z); o.w = f2bf(v.w);
        *reinterpret_cast<ushort4*>(d + off) = o;
    } else {
        int wave = threadIdx.x >> 6, lane = threadIdx.x & 63;
        long long pix = (long long)(bid - 8960) * 4 + wave;
        const float* row = x + pix * 256;
        float4 v = *reinterpret_cast<const float4*>(row + lane * 4);
        float s = v.x + v.y + v.z + v.w;
        float s2 = v.x * v.x + v.y * v.y + v.z * v.z + v.w * v.w;
        s = wave_sum(s); s2 = wave_sum(s2);
        float mean = s * (1.f / 256.f);
        float rstd = rsqrtf(s2 * (1.f / 256.f) - mean * mean + 1e-5f);
        float4 gg = *reinterpret_cast<const float4*>(g + lane * 4);
        float4 bb = *reinterpret_cast<const float4*>(b + lane * 4);
        ushort4 ov;
        ov.x = f2bf((v.x - mean) * rstd * gg.x + bb.x);
        ov.y = f2bf((v.y - mean) * rstd * gg.y + bb.y);
        ov.z = f2bf((v.z - mean) * rstd * gg.z + bb.z);
        ov.w = f2bf((v.w - mean) * rstd * gg.w + bb.w);
        *reinterpret_cast<ushort4*>(xln + pix * 256 + lane * 4) = ov;
    }
}

// ---------------- down-proj v2: split-K(16) 128x128 LDS-staged MFMA GEMM ----------------
__global__ __launch_bounds__(256, 2) void k_gemm_down2(const unsigned short* __restrict__ xln,
                                                       const unsigned short* __restrict__ wd,
                                                       float* __restrict__ part) {
    __shared__ alignas(16) unsigned short As[128 * 64];
    __shared__ alignas(16) unsigned short Bs[128 * 64];
    int wave = threadIdx.x >> 6, lane = threadIdx.x & 63, quad = lane >> 4, l16 = lane & 15;
    int mt = blockIdx.x * 128, nt = blockIdx.y * 128, k0 = blockIdx.z * 1024;
    int wm = wave & 1, wn = wave >> 1;
    int srow = wave * 32 + (lane >> 3);   // staging row (+ i*8)
    int schunk = lane & 7;                // 16B chunk within 128B row
    f32x4 acc[4][4] = {};
    for (int s = 0; s < 16; s++) {
        int kg = k0 + s * 64;
        int p0 = kg >> 11, p1 = (kg >> 8) & 7, cbase = kg & 255;
#pragma unroll
        for (int i = 0; i < 4; i++) {
            int row = srow + i * 8;
            int m = mt + row;
            int bb = m >> 10, r0 = (m >> 5) & 31, r1 = m & 31;
            int c = cbase + ((schunk ^ (row & 7)) << 3);
            const unsigned short* g = xln +
                ((((long long)(bb * 256 + r0 * 8 + p0)) * 256 + (r1 * 8 + p1)) << 8) + c;
            ASYNC16(g, &As[(wave * 32 + i * 8) * 64]);
        }
#pragma unroll
        for (int i = 0; i < 4; i++) {
            int row = srow + i * 8;
            int n = nt + row;
            const unsigned short* g = wd + (long long)n * 16384 + kg + ((schunk ^ (row & 7)) << 3);
            ASYNC16(g, &Bs[(wave * 32 + i * 8) * 64]);
        }
        __syncthreads();
#pragma unroll
        for (int sub = 0; sub < 2; sub++) {
            int c = sub * 4 + quad;
            bf16x8 af[4], bfr[4];
#pragma unroll
            for (int mi = 0; mi < 4; mi++) {
                int row = wm * 64 + mi * 16 + l16;
                af[mi] = *reinterpret_cast<const bf16x8*>(&As[row * 64 + ((c ^ (row & 7)) << 3)]);
            }
#pragma unroll
            for (int ni = 0; ni < 4; ni++) {
                int row = wn * 64 + ni * 16 + l16;
                bfr[ni] = *reinterpret_cast<const bf16x8*>(&Bs[row * 64 + ((c ^ (row & 7)) << 3)]);
            }
#pragma unroll
            for (int mi = 0; mi < 4; mi++)
#pragma unroll
                for (int ni = 0; ni < 4; ni++)
                    acc[mi][ni] = MFMA16(af[mi], bfr[ni], acc[mi][ni]);
        }
        __syncthreads();
    }
    float* pb = part + (long long)blockIdx.z * 524288;
#pragma unroll
    for (int mi = 0; mi < 4; mi++)
#pragma unroll
        for (int ni = 0; ni < 4; ni++) {
            int n = nt + wn * 64 + ni * 16 + l16;
#pragma unroll
            for (int r = 0; r < 4; r++) {
                int m = mt + wm * 64 + mi * 16 + quad * 4 + r;
                pb[(long long)m * 256 + n] = acc[mi][ni][r];
            }
        }
}

// ---------------- split-K reduce + bias + bf16 ----------------
__global__ __launch_bounds__(256) void k_red(const float* __restrict__ part,
                                             const float* __restrict__ bd,
                                             unsigned short* __restrict__ y) {
    int i = (blockIdx.x * 256 + threadIdx.x) * 4;
    float4 s = {0.f, 0.f, 0.f, 0.f};
#pragma unroll
    for (int p = 0; p < 16; p++) {
        float4 v = *reinterpret_cast<const float4*>(part + (long long)p * 524288 + i);
        s.x += v.x; s.y += v.y; s.z += v.z; s.w += v.w;
    }
    int n = i & 255;
    float4 bb = *reinterpret_cast<const float4*>(bd + n);
    ushort4 o;
    o.x = f2bf(s.x + bb.x); o.y = f2bf(s.y + bb.y);
    o.z = f2bf(s.z + bb.z); o.w = f2bf(s.w + bb.w);
    *reinterpret_cast<ushort4*>(y + i) = o;
}

// ---------------- qkv: [2048,256]x[768,256]^T, scatter to q, k, v^T (bf16) ----------------
__global__ __launch_bounds__(256) void k_gemm_qkv(const unsigned short* __restrict__ yd,
                                                  const unsigned short* __restrict__ wq,
                                                  const float* __restrict__ bq,
                                                  unsigned short* __restrict__ q,
                                                  unsigned short* __restrict__ k,
                                                  unsigned short* __restrict__ vT) {
    int wave = threadIdx.x >> 6, lane = threadIdx.x & 63, quad = lane >> 4, l16 = lane & 15;
    int m0 = blockIdx.x * 64 + wave * 16;
    int n0 = blockIdx.y * 64;
    const unsigned short* arow = yd + (long long)(m0 + l16) * 256;
    f32x4 acc[4] = {};
    for (int kb = 0; kb < 256; kb += 32) {
        bf16x8 a = *reinterpret_cast<const bf16x8*>(arow + kb + quad * 8);
#pragma unroll
        for (int ni = 0; ni < 4; ni++) {
            bf16x8 bv = *reinterpret_cast<const bf16x8*>(wq + (long long)(n0 + ni * 16 + l16) * 256 + kb + quad * 8);
            acc[ni] = MFMA16(a, bv, acc[ni]);
        }
    }
#pragma unroll
    for (int ni = 0; ni < 4; ni++) {
        int n = n0 + ni * 16 + l16;
        float bias = bq[n];
        int t = n >> 8, h = (n >> 5) & 7, d = n & 31;
#pragma unroll
        for (int r = 0; r < 4; r++) {
            int m = m0 + quad * 4 + r;
            int bh = ((m >> 10) << 3) | h;
            int l = m & 1023;
            unsigned short val = f2bf(acc[ni][r] + bias);
            if (t == 0)      q[((long long)bh * 1024 + l) * 32 + d] = val;
            else if (t == 1) k[((long long)bh * 1024 + l) * 32 + d] = val;
            else             vT[((long long)bh * 32 + d) * 1024 + l] = val;
        }
    }
}

// ---------------- fused flash attention: S=scale*qk^T+rpe, softmax, O=P@V ----------------
__global__ __launch_bounds__(256) void k_attn(const unsigned short* __restrict__ q,
                                              const unsigned short* __restrict__ k,
                                              const unsigned short* __restrict__ vT,
                                              const float* __restrict__ rpe,
                                              unsigned short* __restrict__ o) {
    __shared__ alignas(16) char Pl[4][16 * 128];   // per-wave [16 qi][64 kj] bf16, swizzled
    int wave = threadIdx.x >> 6, lane = threadIdx.x & 63, quad = lane >> 4, l16 = lane & 15;
    int bh = blockIdx.y, h = bh & 7;
    int m0 = blockIdx.x * 64 + wave * 16;
    const unsigned short* qb = q + (long long)bh * 32768;
    const unsigned short* kb = k + (long long)bh * 32768;
    const unsigned short* vb = vT + (long long)bh * 32768;
    char* pl = Pl[wave];
    const float scale = 0.17677669529663687f;  // 1/sqrt(32)
    int qi = m0 + l16;
    int qi0 = qi >> 5, qi1 = qi & 31;
    bf16x8 bq = *reinterpret_cast<const bf16x8*>(qb + qi * 32 + quad * 8);
    f32x4 o0 = {0.f, 0.f, 0.f, 0.f}, o1 = {0.f, 0.f, 0.f, 0.f};
    float m_run = -3.0e38f, l_run = 0.f;
    int swz = (l16 & 7) << 4;
    for (int t = 0; t < 16; t++) {
        // S^T tile: D[kj = t*64+ni*16+quad*4+r][qi = m0+l16]
        f32x4 st[4];
        __builtin_amdgcn_s_setprio(1);
#pragma unroll
        for (int ni = 0; ni < 4; ni++) {
            bf16x8 ak = *reinterpret_cast<const bf16x8*>(kb + (t * 64 + ni * 16 + l16) * 32 + quad * 8);
            f32x4 z = {0.f, 0.f, 0.f, 0.f};
            st[ni] = MFMA16(ak, bq, z);
        }
        __builtin_amdgcn_s_setprio(0);
        float vals[16];
        float tmax = -3.0e38f;
#pragma unroll
        for (int ni = 0; ni < 4; ni++)
#pragma unroll
            for (int r = 0; r < 4; r++) {
                int kj = t * 64 + ni * 16 + quad * 4 + r;
                int kj0 = kj >> 5, kj1 = kj & 31;
                int idx = (qi0 - kj0 + 31) * 63 + (qi1 - kj1 + 31);
                float sv = st[ni][r] * scale + rpe[idx * 8 + h];
                vals[ni * 4 + r] = sv;
                tmax = fmaxf(tmax, sv);
            }
        tmax = fmaxf(tmax, __shfl_xor(tmax, 16, 64));
        tmax = fmaxf(tmax, __shfl_xor(tmax, 32, 64));
        float m_new = fmaxf(m_run, tmax);
        float fac = __expf(m_run - m_new);
        float tsum = 0.f;
#pragma unroll
        for (int ni = 0; ni < 4; ni++) {
            ushort4 w4;
            float p0v = __expf(vals[ni * 4 + 0] - m_new);
            float p1v = __expf(vals[ni * 4 + 1] - m_new);
            float p2v = __expf(vals[ni * 4 + 2] - m_new);
            float p3v = __expf(vals[ni * 4 + 3] - m_new);
            tsum += p0v + p1v + p2v + p3v;
            w4.x = f2bf(p0v); w4.y = f2bf(p1v); w4.z = f2bf(p2v); w4.w = f2bf(p3v);
            *reinterpret_cast<ushort4*>(pl + l16 * 128 + ((ni * 32 + quad * 8) ^ swz)) = w4;
        }
        tsum += __shfl_xor(tsum, 16, 64);
        tsum += __shfl_xor(tsum, 32, 64);
        l_run = l_run * fac + tsum;
        m_run = m_new;
#pragma unroll
        for (int r = 0; r < 4; r++) { o0[r] *= fac; o1[r] *= fac; }
#pragma unroll
        for (int kk = 0; kk < 2; kk++) {
            bf16x8 pb = *reinterpret_cast<const bf16x8*>(pl + l16 * 128 + ((kk * 64 + quad * 16) ^ swz));
            bf16x8 av0 = *reinterpret_cast<const bf16x8*>(vb + (long long)(l16) * 1024 + t * 64 + kk * 32 + quad * 8);
            bf16x8 av1 = *reinterpret_cast<const bf16x8*>(vb + (long long)(16 + l16) * 1024 + t * 64 + kk * 32 + quad * 8);
            __builtin_amdgcn_s_setprio(1);
            o0 = MFMA16(av0, pb, o0);
            o1 = MFMA16(av1, pb, o1);
            __builtin_amdgcn_s_setprio(0);
        }
    }
    float inv = 1.f / l_run;
    int b_ = bh >> 3;
    long long base = ((long long)(b_ * 1024 + qi)) * 256 + h * 32;
    ushort4 w0, w1;
    w0.x = f2bf(o0[0] * inv); w0.y = f2bf(o0[1] * inv);
    w0.z = f2bf(o0[2] * inv); w0.w = f2bf(o0[3] * inv);
    w1.x = f2bf(o1[0] * inv); w1.y = f2bf(o1[1] * inv);
    w1.z = f2bf(o1[2] * inv); w1.w = f2bf(o1[3] * inv);
    *reinterpret_cast<ushort4*>(o + base + quad * 4) = w0;
    *reinterpret_cast<ushort4*>(o + base + 16 + quad * 4) = w1;
}

// ---------------- proj: [2048,256]x[256,256]^T -> bf16 ----------------
__global__ __launch_bounds__(256) void k_gemm_proj(const unsigned short* __restrict__ a_,
                                                   const unsigned short* __restrict__ w,
                                                   const float* __restrict__ bias,
                                                   unsigned short* __restrict__ y) {
    int wave = threadIdx.x >> 6, lane = threadIdx.x & 63, quad = lane >> 4, l16 = lane & 15;
    int m0 = blockIdx.x * 64 + wave * 16;
    int n0 = blockIdx.y * 64;
    const unsigned short* arow = a_ + (long long)(m0 + l16) * 256;
    f32x4 acc[4] = {};
    for (int kb = 0; kb < 256; kb += 32) {
        bf16x8 a = *reinterpret_cast<const bf16x8*>(arow + kb + quad * 8);
#pragma unroll
        for (int ni = 0; ni < 4; ni++) {
            bf16x8 bv = *reinterpret_cast<const bf16x8*>(w + (long long)(n0 + ni * 16 + l16) * 256 + kb + quad * 8);
            acc[ni] = MFMA16(a, bv, acc[ni]);
        }
    }
#pragma unroll
    for (int ni = 0; ni < 4; ni++) {
        int n = n0 + ni * 16 + l16;
        float bv = bias[n];
#pragma unroll
        for (int r = 0; r < 4; r++)
            y[(long long)(m0 + quad * 4 + r) * 256 + n] = f2bf(acc[ni][r] + bv);
    }
}

// ---------------- up-proj + fold + residual v2: LDS-staged weight panel ----------------
__global__ __launch_bounds__(256) void k_up_fold(const unsigned short* __restrict__ a_,
                                                 const unsigned short* __restrict__ w,
                                                 const float* __restrict__ bup,
                                                 const float* __restrict__ x,
                                                 float* __restrict__ out) {
    __shared__ alignas(16) unsigned short Bs[128 * 256];   // 64 KB
    int wave = threadIdx.x >> 6, lane = threadIdx.x & 63, quad = lane >> 4, l16 = lane & 15;
    int n0 = blockIdx.x * 128;
    int mbase = blockIdx.y * 512;
#pragma unroll
    for (int i = 0; i < 16; i++) {
        int R = i * 8 + wave * 2;                 // wave-uniform row base
        int r = R + (lane >> 5);                  // this lane's row
        int cg = (lane & 31) ^ (r & 7);           // pre-swizzled 16B-chunk in global
        const unsigned short* g = w + (long long)(n0 + r) * 256 + cg * 8;
        ASYNC16(g, &Bs[R * 256]);
    }
    __syncthreads();
    float bias8[8];
#pragma unroll
    for (int ni = 0; ni < 8; ni++) bias8[ni] = bup[n0 + ni * 16 + l16];
    for (int s = 0; s < 8; s++) {
        int mr = mbase + s * 64 + wave * 16;
        const unsigned short* arow = a_ + (long long)(mr + l16) * 256;
        f32x4 acc[8] = {};
#pragma unroll
        for (int kb = 0; kb < 8; kb++) {
            bf16x8 a = *reinterpret_cast<const bf16x8*>(arow + kb * 32 + quad * 8);
#pragma unroll
            for (int ni = 0; ni < 8; ni++) {
                int nr = ni * 16 + l16;
                bf16x8 bv = *reinterpret_cast<const bf16x8*>(
                    &Bs[nr * 256 + (((kb * 4 + quad) ^ (nr & 7)) << 3)]);
                acc[ni] = MFMA16(a, bv, acc[ni]);
            }
        }
#pragma unroll
        for (int ni = 0; ni < 8; ni++) {
            int n = n0 + ni * 16 + l16;
            int p0 = n >> 11, p1 = (n >> 8) & 7, c = n & 255;
#pragma unroll
            for (int r = 0; r < 4; r++) {
                int m = mr + quad * 4 + r;
                int bb = m >> 10, r0 = (m >> 5) & 31, r1 = m & 31;
                long long addr = ((long long)bb << 24) + (long long)(r0 * 8 + p0) * 65536 + (r1 * 8 + p1) * 256 + c;
                out[addr] = x[addr] + acc[ni][r] + bias8[ni];
            }
        }
    }
}

// ---------------- fused LN2 + MLP + residual, in-place on d_out ----------------
// v2 structure + FULL UNROLL of both kb loops (r8): the rolled trip-8 loops
// serialized each iteration's ds_read/global-load -> waitcnt -> MFMA chain;
// unrolling exposes the whole phase (32 ds_read + 16 B-loads + 64 MFMA) to
// the scheduler for m97-style counted-waitcnt pipelining. Register headroom:
// 60 used / 128 budget at (512,4). Spill tripwire: FETCH > 250 MB -> revert.
#define LP 264  // 256 + 8 pad: row stride 528 B -> bank step 4, 2-way max (free)
__global__ __launch_bounds__(512, 4) void k_mlp(float* __restrict__ xio,
                                                const float* __restrict__ g2,
                                                const float* __restrict__ b2,
                                                const unsigned short* __restrict__ w1,
                                                const float* __restrict__ bfc1,
                                                const unsigned short* __restrict__ w2,
                                                const float* __restrict__ bfc2) {
    __shared__ unsigned short Aln[64 * LP];
    __shared__ unsigned short Hc[64 * LP];
    int wave = threadIdx.x >> 6, lane = threadIdx.x & 63, quad = lane >> 4, l16 = lane & 15;
    long long m0 = (long long)blockIdx.x * 64;
    float4 gg = *reinterpret_cast<const float4*>(g2 + lane * 4);
    float4 bb = *reinterpret_cast<const float4*>(b2 + lane * 4);
#pragma unroll
    for (int i = 0; i < 8; i++) {
        int p = wave * 8 + i;
        float4 v = *reinterpret_cast<const float4*>(xio + (m0 + p) * 256 + lane * 4);
        float s = v.x + v.y + v.z + v.w;
        float s2 = v.x * v.x + v.y * v.y + v.z * v.z + v.w * v.w;
        s = wave_sum(s); s2 = wave_sum(s2);
        float mean = s * (1.f / 256.f);
        float rstd = rsqrtf(s2 * (1.f / 256.f) - mean * mean + 1e-5f);
        ushort4 o;
        o.x = f2bf((v.x - mean) * rstd * gg.x + bb.x);
        o.y = f2bf((v.y - mean) * rstd * gg.y + bb.y);
        o.z = f2bf((v.z - mean) * rstd * gg.z + bb.z);
        o.w = f2bf((v.w - mean) * rstd * gg.w + bb.w);
        *reinterpret_cast<ushort4*>(&Aln[p * LP + lane * 4]) = o;
    }
    __syncthreads();
    f32x4 acc2[4][2] = {};
    for (int ch = 0; ch < 4; ch++) {
        f32x4 acc1[4][2] = {};
#pragma unroll
        for (int kb = 0; kb < 256; kb += 32) {
            bf16x8 af[4];
#pragma unroll
            for (int mi = 0; mi < 4; mi++)
                af[mi] = *reinterpret_cast<const bf16x8*>(&Aln[(mi * 16 + l16) * LP + kb + quad * 8]);
#pragma unroll
            for (int ni = 0; ni < 2; ni++) {
                bf16x8 bv = *reinterpret_cast<const bf16x8*>(w1 + (long long)(ch * 256 + wave * 32 + ni * 16 + l16) * 256 + kb + quad * 8);
                __builtin_amdgcn_s_setprio(1);
#pragma unroll
                for (int mi = 0; mi < 4; mi++)
                    acc1[mi][ni] = MFMA16(af[mi], bv, acc1[mi][ni]);
                __builtin_amdgcn_s_setprio(0);
            }
        }
#pragma unroll
        for (int ni = 0; ni < 2; ni++) {
            int n = ch * 256 + wave * 32 + ni * 16 + l16;
            float bias = bfc1[n];
            int col = wave * 32 + ni * 16 + l16;
#pragma unroll
            for (int mi = 0; mi < 4; mi++) {
#pragma unroll
                for (int r = 0; r < 4; r++) {
                    float vv = acc1[mi][ni][r] + bias;
                    Hc[(mi * 16 + quad * 4 + r) * LP + col] = f2bf(gelu_fast(vv));
                }
            }
        }
        __syncthreads();
#pragma unroll
        for (int kb = 0; kb < 256; kb += 32) {
            bf16x8 af[4];
#pragma unroll
            for (int mi = 0; mi < 4; mi++)
                af[mi] = *reinterpret_cast<const bf16x8*>(&Hc[(mi * 16 + l16) * LP + kb + quad * 8]);
#pragma unroll
            for (int ni = 0; ni < 2; ni++) {
                bf16x8 bv = *reinterpret_cast<const bf16x8*>(w2 + (long long)(wave * 32 + ni * 16 + l16) * 1024 + ch * 256 + kb + quad * 8);
                __builtin_amdgcn_s_setprio(1);
#pragma unroll
                for (int mi = 0; mi < 4; mi++)
                    acc2[mi][ni] = MFMA16(af[mi], bv, acc2[mi][ni]);
                __builtin_amdgcn_s_setprio(0);
            }
        }
        __syncthreads();
    }
#pragma unroll
    for (int ni = 0; ni < 2; ni++) {
        int n = wave * 32 + ni * 16 + l16;
        float bias = bfc2[n];
#pragma unroll
        for (int mi = 0; mi < 4; mi++) {
#pragma unroll
            for (int r = 0; r < 4; r++) {
                long long row = m0 + mi * 16 + quad * 4 + r;
                float xv = xio[row * 256 + n];
                xio[row * 256 + n] = xv + acc2[mi][ni][r] + bias;
            }
        }
    }
}

extern "C" void kernel_launch(void* const* d_in, const int* in_sizes, int n_in,
                              void* d_out, int out_size, void* d_ws, size_t ws_size,
                              hipStream_t stream) {
    const float* x      = (const float*)d_in[0];
    const float* ln1_g  = (const float*)d_in[1];
    const float* ln1_b  = (const float*)d_in[2];
    const float* ln2_g  = (const float*)d_in[3];
    const float* ln2_b  = (const float*)d_in[4];
    const float* rpe    = (const float*)d_in[5];
    const float* w_down = (const float*)d_in[6];
    const float* b_down = (const float*)d_in[7];
    const float* w_up   = (const float*)d_in[8];
    const float* b_up   = (const float*)d_in[9];
    const float* w_qkv  = (const float*)d_in[10];
    const float* b_qkv  = (const float*)d_in[11];
    const float* w_proj = (const float*)d_in[12];
    const float* b_proj = (const float*)d_in[13];
    const float* w_fc1  = (const float*)d_in[14];
    const float* b_fc1  = (const float*)d_in[15];
    const float* w_fc2  = (const float*)d_in[16];
    const float* b_fc2  = (const float*)d_in[17];
    float* out = (float*)d_out;

    char* wp = (char*)d_ws;
    auto alloc = [&](size_t bytes) { void* p = (void*)wp; wp += (bytes + 255) & ~(size_t)255; return p; };
    unsigned short* wdown_bf = (unsigned short*)alloc(4194304 * 2);
    unsigned short* wup_bf   = (unsigned short*)alloc(4194304 * 2);
    unsigned short* wqkv_bf  = (unsigned short*)alloc(196608 * 2);
    unsigned short* wproj_bf = (unsigned short*)alloc(65536 * 2);
    unsigned short* wfc1_bf  = (unsigned short*)alloc(262144 * 2);
    unsigned short* wfc2_bf  = (unsigned short*)alloc(262144 * 2);
    unsigned short* ydown    = (unsigned short*)alloc(524288 * 2);
    unsigned short* qb       = (unsigned short*)alloc(524288 * 2);
    unsigned short* kb       = (unsigned short*)alloc(524288 * 2);
    unsigned short* vT       = (unsigned short*)alloc(524288 * 2);
    unsigned short* obf      = (unsigned short*)alloc(524288 * 2);
    unsigned short* oproj    = (unsigned short*)alloc(524288 * 2);

    // Big temporaries live inside d_out (134.2 MB); all dead before k_up_fold
    // overwrites the whole buffer with x2.
    //   xln:  [0, 67.1 MB)        -- dead after k_gemm_down2
    //   part: [100.7, 134.2 MB)   -- 16 x 2 MB fp32 split-K partials
    unsigned short* xln = (unsigned short*)d_out;
    float* part         = (float*)((char*)d_out + 100663296);

    // one preamble launch: 8960 cvt blocks + 32768 LN blocks
    k_pre<<<41728, 256, 0, stream>>>(w_down, w_up, w_qkv, w_proj, w_fc1, w_fc2,
                                     wdown_bf, wup_bf, wqkv_bf, wproj_bf, wfc1_bf, wfc2_bf,
                                     x, ln1_g, ln1_b, xln);
    k_gemm_down2<<<dim3(16, 2, 16), 256, 0, stream>>>(xln, wdown_bf, part);
    k_red<<<512, 256, 0, stream>>>(part, b_down, ydown);
    k_gemm_qkv<<<dim3(32, 12), 256, 0, stream>>>(ydown, wqkv_bf, b_qkv, qb, kb, vT);
    k_attn<<<dim3(16, 16), 256, 0, stream>>>(qb, kb, vT, rpe, obf);
    k_gemm_proj<<<dim3(32, 4), 256, 0, stream>>>(obf, wproj_bf, b_proj, oproj);
    k_up_fold<<<dim3(128, 4), 256, 0, stream>>>(oproj, wup_bf, b_up, x, out);
    k_mlp<<<2048, 512, 0, stream>>>(out, ln2_g, ln2_b, wfc1_bf, b_fc1, wfc2_bf, b_fc2);
}

// Round 9
// 493.955 us; speedup vs baseline: 2.1281x; 1.0222x over previous
//
#include <hip/hip_runtime.h>

typedef __attribute__((ext_vector_type(8))) __bf16 bf16x8;
typedef __attribute__((ext_vector_type(4))) float f32x4;

#define MFMA16(a, b, c) __builtin_amdgcn_mfma_f32_16x16x32_bf16((a), (b), (c), 0, 0, 0)

// async global->LDS, 16B per lane; LDS dest = wave-uniform base + lane*16
#define ASYNC16(g, l) __builtin_amdgcn_global_load_lds( \
    (const __attribute__((address_space(1))) unsigned int*)(g), \
    (__attribute__((address_space(3))) unsigned int*)(l), 16, 0, 0)

// fp32 -> bf16 RTNE via compiler cast
__device__ __forceinline__ unsigned short f2bf(float f) {
    return __builtin_bit_cast(unsigned short, (__bf16)f);
}

__device__ __forceinline__ float wave_sum(float v) {
#pragma unroll
    for (int off = 32; off; off >>= 1) v += __shfl_xor(v, off, 64);
    return v;
}

// tanh-form GELU: x*sigmoid(1.5957691x + 0.0713548x^3).
__device__ __forceinline__ float gelu_fast(float v) {
    float z = v * fmaf(v * v, 0.0713548162f, 1.5957691216f);
    float e = __expf(-z);
    return v * __builtin_amdgcn_rcpf(1.f + e);
}

// ---------------- fused preamble: all 6 weight casts + LN1, one launch ----------------
__global__ __launch_bounds__(256) void k_pre(const float* __restrict__ wdown, const float* __restrict__ wup,
                                             const float* __restrict__ wqkv, const float* __restrict__ wproj,
                                             const float* __restrict__ wfc1, const float* __restrict__ wfc2,
                                             unsigned short* __restrict__ dwdown, unsigned short* __restrict__ dwup,
                                             unsigned short* __restrict__ dwqkv, unsigned short* __restrict__ dwproj,
                                             unsigned short* __restrict__ dwfc1, unsigned short* __restrict__ dwfc2,
                                             const float* __restrict__ x, const float* __restrict__ g,
                                             const float* __restrict__ b, unsigned short* __restrict__ xln) {
    int bid = blockIdx.x;
    if (bid < 8960) {
        int i = (bid * 256 + threadIdx.x) * 4;
        const float* s; unsigned short* d; int off;
        if (i < 4194304)      { s = wdown; d = dwdown; off = i; }
        else if (i < 8388608) { s = wup;   d = dwup;   off = i - 4194304; }
        else if (i < 8585216) { s = wqkv;  d = dwqkv;  off = i - 8388608; }
        else if (i < 8650752) { s = wproj; d = dwproj; off = i - 8585216; }
        else if (i < 8912896) { s = wfc1;  d = dwfc1;  off = i - 8650752; }
        else                  { s = wfc2;  d = dwfc2;  off = i - 8912896; }
        float4 v = *reinterpret_cast<const float4*>(s + off);
        ushort4 o;
        o.x = f2bf(v.x); o.y = f2bf(v.y); o.z = f2bf(v.z); o.w = f2bf(v.w);
        *reinterpret_cast<ushort4*>(d + off) = o;
    } else {
        int wave = threadIdx.x >> 6, lane = threadIdx.x & 63;
        long long pix = (long long)(bid - 8960) * 4 + wave;
        const float* row = x + pix * 256;
        float4 v = *reinterpret_cast<const float4*>(row + lane * 4);
        float s = v.x + v.y + v.z + v.w;
        float s2 = v.x * v.x + v.y * v.y + v.z * v.z + v.w * v.w;
        s = wave_sum(s); s2 = wave_sum(s2);
        float mean = s * (1.f / 256.f);
        float rstd = rsqrtf(s2 * (1.f / 256.f) - mean * mean + 1e-5f);
        float4 gg = *reinterpret_cast<const float4*>(g + lane * 4);
        float4 bb = *reinterpret_cast<const float4*>(b + lane * 4);
        ushort4 ov;
        ov.x = f2bf((v.x - mean) * rstd * gg.x + bb.x);
        ov.y = f2bf((v.y - mean) * rstd * gg.y + bb.y);
        ov.z = f2bf((v.z - mean) * rstd * gg.z + bb.z);
        ov.w = f2bf((v.w - mean) * rstd * gg.w + bb.w);
        *reinterpret_cast<ushort4*>(xln + pix * 256 + lane * 4) = ov;
    }
}

// ---------------- down-proj v2: split-K(16) 128x128 LDS-staged MFMA GEMM ----------------
__global__ __launch_bounds__(256, 2) void k_gemm_down2(const unsigned short* __restrict__ xln,
                                                       const unsigned short* __restrict__ wd,
                                                       float* __restrict__ part) {
    __shared__ alignas(16) unsigned short As[128 * 64];
    __shared__ alignas(16) unsigned short Bs[128 * 64];
    int wave = threadIdx.x >> 6, lane = threadIdx.x & 63, quad = lane >> 4, l16 = lane & 15;
    int mt = blockIdx.x * 128, nt = blockIdx.y * 128, k0 = blockIdx.z * 1024;
    int wm = wave & 1, wn = wave >> 1;
    int srow = wave * 32 + (lane >> 3);   // staging row (+ i*8)
    int schunk = lane & 7;                // 16B chunk within 128B row
    f32x4 acc[4][4] = {};
    for (int s = 0; s < 16; s++) {
        int kg = k0 + s * 64;
        int p0 = kg >> 11, p1 = (kg >> 8) & 7, cbase = kg & 255;
#pragma unroll
        for (int i = 0; i < 4; i++) {
            int row = srow + i * 8;
            int m = mt + row;
            int bb = m >> 10, r0 = (m >> 5) & 31, r1 = m & 31;
            int c = cbase + ((schunk ^ (row & 7)) << 3);
            const unsigned short* g = xln +
                ((((long long)(bb * 256 + r0 * 8 + p0)) * 256 + (r1 * 8 + p1)) << 8) + c;
            ASYNC16(g, &As[(wave * 32 + i * 8) * 64]);
        }
#pragma unroll
        for (int i = 0; i < 4; i++) {
            int row = srow + i * 8;
            int n = nt + row;
            const unsigned short* g = wd + (long long)n * 16384 + kg + ((schunk ^ (row & 7)) << 3);
            ASYNC16(g, &Bs[(wave * 32 + i * 8) * 64]);
        }
        __syncthreads();
#pragma unroll
        for (int sub = 0; sub < 2; sub++) {
            int c = sub * 4 + quad;
            bf16x8 af[4], bfr[4];
#pragma unroll
            for (int mi = 0; mi < 4; mi++) {
                int row = wm * 64 + mi * 16 + l16;
                af[mi] = *reinterpret_cast<const bf16x8*>(&As[row * 64 + ((c ^ (row & 7)) << 3)]);
            }
#pragma unroll
            for (int ni = 0; ni < 4; ni++) {
                int row = wn * 64 + ni * 16 + l16;
                bfr[ni] = *reinterpret_cast<const bf16x8*>(&Bs[row * 64 + ((c ^ (row & 7)) << 3)]);
            }
#pragma unroll
            for (int mi = 0; mi < 4; mi++)
#pragma unroll
                for (int ni = 0; ni < 4; ni++)
                    acc[mi][ni] = MFMA16(af[mi], bfr[ni], acc[mi][ni]);
        }
        __syncthreads();
    }
    float* pb = part + (long long)blockIdx.z * 524288;
#pragma unroll
    for (int mi = 0; mi < 4; mi++)
#pragma unroll
        for (int ni = 0; ni < 4; ni++) {
            int n = nt + wn * 64 + ni * 16 + l16;
#pragma unroll
            for (int r = 0; r < 4; r++) {
                int m = mt + wm * 64 + mi * 16 + quad * 4 + r;
                pb[(long long)m * 256 + n] = acc[mi][ni][r];
            }
        }
}

// ---------------- split-K reduce + bias + bf16 ----------------
__global__ __launch_bounds__(256) void k_red(const float* __restrict__ part,
                                             const float* __restrict__ bd,
                                             unsigned short* __restrict__ y) {
    int i = (blockIdx.x * 256 + threadIdx.x) * 4;
    float4 s = {0.f, 0.f, 0.f, 0.f};
#pragma unroll
    for (int p = 0; p < 16; p++) {
        float4 v = *reinterpret_cast<const float4*>(part + (long long)p * 524288 + i);
        s.x += v.x; s.y += v.y; s.z += v.z; s.w += v.w;
    }
    int n = i & 255;
    float4 bb = *reinterpret_cast<const float4*>(bd + n);
    ushort4 o;
    o.x = f2bf(s.x + bb.x); o.y = f2bf(s.y + bb.y);
    o.z = f2bf(s.z + bb.z); o.w = f2bf(s.w + bb.w);
    *reinterpret_cast<ushort4*>(y + i) = o;
}

// ---------------- qkv: [2048,256]x[768,256]^T, scatter to q, k, v^T (bf16) ----------------
__global__ __launch_bounds__(256) void k_gemm_qkv(const unsigned short* __restrict__ yd,
                                                  const unsigned short* __restrict__ wq,
                                                  const float* __restrict__ bq,
                                                  unsigned short* __restrict__ q,
                                                  unsigned short* __restrict__ k,
                                                  unsigned short* __restrict__ vT) {
    int wave = threadIdx.x >> 6, lane = threadIdx.x & 63, quad = lane >> 4, l16 = lane & 15;
    int m0 = blockIdx.x * 64 + wave * 16;
    int n0 = blockIdx.y * 64;
    const unsigned short* arow = yd + (long long)(m0 + l16) * 256;
    f32x4 acc[4] = {};
    for (int kb = 0; kb < 256; kb += 32) {
        bf16x8 a = *reinterpret_cast<const bf16x8*>(arow + kb + quad * 8);
#pragma unroll
        for (int ni = 0; ni < 4; ni++) {
            bf16x8 bv = *reinterpret_cast<const bf16x8*>(wq + (long long)(n0 + ni * 16 + l16) * 256 + kb + quad * 8);
            acc[ni] = MFMA16(a, bv, acc[ni]);
        }
    }
#pragma unroll
    for (int ni = 0; ni < 4; ni++) {
        int n = n0 + ni * 16 + l16;
        float bias = bq[n];
        int t = n >> 8, h = (n >> 5) & 7, d = n & 31;
#pragma unroll
        for (int r = 0; r < 4; r++) {
            int m = m0 + quad * 4 + r;
            int bh = ((m >> 10) << 3) | h;
            int l = m & 1023;
            unsigned short val = f2bf(acc[ni][r] + bias);
            if (t == 0)      q[((long long)bh * 1024 + l) * 32 + d] = val;
            else if (t == 1) k[((long long)bh * 1024 + l) * 32 + d] = val;
            else             vT[((long long)bh * 32 + d) * 1024 + l] = val;
        }
    }
}

// ---------------- fused flash attention: S=scale*qk^T+rpe, softmax, O=P@V ----------------
__global__ __launch_bounds__(256) void k_attn(const unsigned short* __restrict__ q,
                                              const unsigned short* __restrict__ k,
                                              const unsigned short* __restrict__ vT,
                                              const float* __restrict__ rpe,
                                              unsigned short* __restrict__ o) {
    __shared__ alignas(16) char Pl[4][16 * 128];   // per-wave [16 qi][64 kj] bf16, swizzled
    int wave = threadIdx.x >> 6, lane = threadIdx.x & 63, quad = lane >> 4, l16 = lane & 15;
    int bh = blockIdx.y, h = bh & 7;
    int m0 = blockIdx.x * 64 + wave * 16;
    const unsigned short* qb = q + (long long)bh * 32768;
    const unsigned short* kb = k + (long long)bh * 32768;
    const unsigned short* vb = vT + (long long)bh * 32768;
    char* pl = Pl[wave];
    const float scale = 0.17677669529663687f;  // 1/sqrt(32)
    int qi = m0 + l16;
    int qi0 = qi >> 5, qi1 = qi & 31;
    bf16x8 bq = *reinterpret_cast<const bf16x8*>(qb + qi * 32 + quad * 8);
    f32x4 o0 = {0.f, 0.f, 0.f, 0.f}, o1 = {0.f, 0.f, 0.f, 0.f};
    float m_run = -3.0e38f, l_run = 0.f;
    int swz = (l16 & 7) << 4;
    for (int t = 0; t < 16; t++) {
        // S^T tile: D[kj = t*64+ni*16+quad*4+r][qi = m0+l16]
        f32x4 st[4];
        __builtin_amdgcn_s_setprio(1);
#pragma unroll
        for (int ni = 0; ni < 4; ni++) {
            bf16x8 ak = *reinterpret_cast<const bf16x8*>(kb + (t * 64 + ni * 16 + l16) * 32 + quad * 8);
            f32x4 z = {0.f, 0.f, 0.f, 0.f};
            st[ni] = MFMA16(ak, bq, z);
        }
        __builtin_amdgcn_s_setprio(0);
        float vals[16];
        float tmax = -3.0e38f;
#pragma unroll
        for (int ni = 0; ni < 4; ni++)
#pragma unroll
            for (int r = 0; r < 4; r++) {
                int kj = t * 64 + ni * 16 + quad * 4 + r;
                int kj0 = kj >> 5, kj1 = kj & 31;
                int idx = (qi0 - kj0 + 31) * 63 + (qi1 - kj1 + 31);
                float sv = st[ni][r] * scale + rpe[idx * 8 + h];
                vals[ni * 4 + r] = sv;
                tmax = fmaxf(tmax, sv);
            }
        tmax = fmaxf(tmax, __shfl_xor(tmax, 16, 64));
        tmax = fmaxf(tmax, __shfl_xor(tmax, 32, 64));
        float m_new = fmaxf(m_run, tmax);
        float fac = __expf(m_run - m_new);
        float tsum = 0.f;
#pragma unroll
        for (int ni = 0; ni < 4; ni++) {
            ushort4 w4;
            float p0v = __expf(vals[ni * 4 + 0] - m_new);
            float p1v = __expf(vals[ni * 4 + 1] - m_new);
            float p2v = __expf(vals[ni * 4 + 2] - m_new);
            float p3v = __expf(vals[ni * 4 + 3] - m_new);
            tsum += p0v + p1v + p2v + p3v;
            w4.x = f2bf(p0v); w4.y = f2bf(p1v); w4.z = f2bf(p2v); w4.w = f2bf(p3v);
            *reinterpret_cast<ushort4*>(pl + l16 * 128 + ((ni * 32 + quad * 8) ^ swz)) = w4;
        }
        tsum += __shfl_xor(tsum, 16, 64);
        tsum += __shfl_xor(tsum, 32, 64);
        l_run = l_run * fac + tsum;
        m_run = m_new;
#pragma unroll
        for (int r = 0; r < 4; r++) { o0[r] *= fac; o1[r] *= fac; }
#pragma unroll
        for (int kk = 0; kk < 2; kk++) {
            bf16x8 pb = *reinterpret_cast<const bf16x8*>(pl + l16 * 128 + ((kk * 64 + quad * 16) ^ swz));
            bf16x8 av0 = *reinterpret_cast<const bf16x8*>(vb + (long long)(l16) * 1024 + t * 64 + kk * 32 + quad * 8);
            bf16x8 av1 = *reinterpret_cast<const bf16x8*>(vb + (long long)(16 + l16) * 1024 + t * 64 + kk * 32 + quad * 8);
            __builtin_amdgcn_s_setprio(1);
            o0 = MFMA16(av0, pb, o0);
            o1 = MFMA16(av1, pb, o1);
            __builtin_amdgcn_s_setprio(0);
        }
    }
    float inv = 1.f / l_run;
    int b_ = bh >> 3;
    long long base = ((long long)(b_ * 1024 + qi)) * 256 + h * 32;
    ushort4 w0, w1;
    w0.x = f2bf(o0[0] * inv); w0.y = f2bf(o0[1] * inv);
    w0.z = f2bf(o0[2] * inv); w0.w = f2bf(o0[3] * inv);
    w1.x = f2bf(o1[0] * inv); w1.y = f2bf(o1[1] * inv);
    w1.z = f2bf(o1[2] * inv); w1.w = f2bf(o1[3] * inv);
    *reinterpret_cast<ushort4*>(o + base + quad * 4) = w0;
    *reinterpret_cast<ushort4*>(o + base + 16 + quad * 4) = w1;
}

// ---------------- proj: [2048,256]x[256,256]^T -> bf16 ----------------
__global__ __launch_bounds__(256) void k_gemm_proj(const unsigned short* __restrict__ a_,
                                                   const unsigned short* __restrict__ w,
                                                   const float* __restrict__ bias,
                                                   unsigned short* __restrict__ y) {
    int wave = threadIdx.x >> 6, lane = threadIdx.x & 63, quad = lane >> 4, l16 = lane & 15;
    int m0 = blockIdx.x * 64 + wave * 16;
    int n0 = blockIdx.y * 64;
    const unsigned short* arow = a_ + (long long)(m0 + l16) * 256;
    f32x4 acc[4] = {};
    for (int kb = 0; kb < 256; kb += 32) {
        bf16x8 a = *reinterpret_cast<const bf16x8*>(arow + kb + quad * 8);
#pragma unroll
        for (int ni = 0; ni < 4; ni++) {
            bf16x8 bv = *reinterpret_cast<const bf16x8*>(w + (long long)(n0 + ni * 16 + l16) * 256 + kb + quad * 8);
            acc[ni] = MFMA16(a, bv, acc[ni]);
        }
    }
#pragma unroll
    for (int ni = 0; ni < 4; ni++) {
        int n = n0 + ni * 16 + l16;
        float bv = bias[n];
#pragma unroll
        for (int r = 0; r < 4; r++)
            y[(long long)(m0 + quad * 4 + r) * 256 + n] = f2bf(acc[ni][r] + bv);
    }
}

// ---------------- up-proj + fold + residual v2: LDS-staged weight panel ----------------
__global__ __launch_bounds__(256) void k_up_fold(const unsigned short* __restrict__ a_,
                                                 const unsigned short* __restrict__ w,
                                                 const float* __restrict__ bup,
                                                 const float* __restrict__ x,
                                                 float* __restrict__ out) {
    __shared__ alignas(16) unsigned short Bs[128 * 256];   // 64 KB
    int wave = threadIdx.x >> 6, lane = threadIdx.x & 63, quad = lane >> 4, l16 = lane & 15;
    int n0 = blockIdx.x * 128;
    int mbase = blockIdx.y * 512;
#pragma unroll
    for (int i = 0; i < 16; i++) {
        int R = i * 8 + wave * 2;                 // wave-uniform row base
        int r = R + (lane >> 5);                  // this lane's row
        int cg = (lane & 31) ^ (r & 7);           // pre-swizzled 16B-chunk in global
        const unsigned short* g = w + (long long)(n0 + r) * 256 + cg * 8;
        ASYNC16(g, &Bs[R * 256]);
    }
    __syncthreads();
    float bias8[8];
#pragma unroll
    for (int ni = 0; ni < 8; ni++) bias8[ni] = bup[n0 + ni * 16 + l16];
    for (int s = 0; s < 8; s++) {
        int mr = mbase + s * 64 + wave * 16;
        const unsigned short* arow = a_ + (long long)(mr + l16) * 256;
        f32x4 acc[8] = {};
#pragma unroll
        for (int kb = 0; kb < 8; kb++) {
            bf16x8 a = *reinterpret_cast<const bf16x8*>(arow + kb * 32 + quad * 8);
#pragma unroll
            for (int ni = 0; ni < 8; ni++) {
                int nr = ni * 16 + l16;
                bf16x8 bv = *reinterpret_cast<const bf16x8*>(
                    &Bs[nr * 256 + (((kb * 4 + quad) ^ (nr & 7)) << 3)]);
                acc[ni] = MFMA16(a, bv, acc[ni]);
            }
        }
#pragma unroll
        for (int ni = 0; ni < 8; ni++) {
            int n = n0 + ni * 16 + l16;
            int p0 = n >> 11, p1 = (n >> 8) & 7, c = n & 255;
#pragma unroll
            for (int r = 0; r < 4; r++) {
                int m = mr + quad * 4 + r;
                int bb = m >> 10, r0 = (m >> 5) & 31, r1 = m & 31;
                long long addr = ((long long)bb << 24) + (long long)(r0 * 8 + p0) * 65536 + (r1 * 8 + p1) * 256 + c;
                out[addr] = x[addr] + acc[ni][r] + bias8[ni];
            }
        }
    }
}

// ---------------- fused LN2 + MLP + residual, in-place on d_out ----------------
// v7 "pipe": T3-lite software pipeline. 8 chunks of 128 mid-cols; Hc is
// DOUBLE-BUFFERED 64x128 (LH=136 pad, 17KB x2); per chunk ONE barrier, then
// fc2(ch) [Hc[ch&1]+w2] runs merged with fc1(ch+1) [Aln+w1] (independent
// data), gelu writes Hc[(ch+1)&1]. Barriers 17 -> 10; 2x independent work
// per drain point. Register budget respected (the v3 failure): narrow fc1
// slice acc1[4]=16 regs (not [4][2]); live ~105 < 128 @ (512,4). LDS
// 33.8+34.8 = 68.6KB <= 80 -> still 2 blocks/CU.
// Tripwires: FETCH > 250MB = spill -> revert to r8; absmax != 0.03125 = race.
#define LP 264  // Aln pad: 528B stride -> 2-way max (free)
#define LH 136  // Hc pad: 272B stride -> 2-way max (free)
__global__ __launch_bounds__(512, 4) void k_mlp(float* __restrict__ xio,
                                                const float* __restrict__ g2,
                                                const float* __restrict__ b2,
                                                const unsigned short* __restrict__ w1,
                                                const float* __restrict__ bfc1,
                                                const unsigned short* __restrict__ w2,
                                                const float* __restrict__ bfc2) {
    __shared__ unsigned short Aln[64 * LP];
    __shared__ unsigned short Hc[2][64 * LH];
    int wave = threadIdx.x >> 6, lane = threadIdx.x & 63, quad = lane >> 4, l16 = lane & 15;
    long long m0 = (long long)blockIdx.x * 64;
    float4 gg = *reinterpret_cast<const float4*>(g2 + lane * 4);
    float4 bb = *reinterpret_cast<const float4*>(b2 + lane * 4);
#pragma unroll
    for (int i = 0; i < 8; i++) {
        int p = wave * 8 + i;
        float4 v = *reinterpret_cast<const float4*>(xio + (m0 + p) * 256 + lane * 4);
        float s = v.x + v.y + v.z + v.w;
        float s2 = v.x * v.x + v.y * v.y + v.z * v.z + v.w * v.w;
        s = wave_sum(s); s2 = wave_sum(s2);
        float mean = s * (1.f / 256.f);
        float rstd = rsqrtf(s2 * (1.f / 256.f) - mean * mean + 1e-5f);
        ushort4 o;
        o.x = f2bf((v.x - mean) * rstd * gg.x + bb.x);
        o.y = f2bf((v.y - mean) * rstd * gg.y + bb.y);
        o.z = f2bf((v.z - mean) * rstd * gg.z + bb.z);
        o.w = f2bf((v.w - mean) * rstd * gg.w + bb.w);
        *reinterpret_cast<ushort4*>(&Aln[p * LP + lane * 4]) = o;
    }
    __syncthreads();
    int col = wave * 16 + l16;   // this wave's fc1 column within a chunk
    // prologue: fc1 chunk 0 -> gelu -> Hc[0]
    {
        f32x4 acc1[4] = {};
        const unsigned short* w1c = w1 + (long long)(wave * 16 + l16) * 256;
#pragma unroll
        for (int kb = 0; kb < 256; kb += 32) {
            bf16x8 bv = *reinterpret_cast<const bf16x8*>(w1c + kb + quad * 8);
#pragma unroll
            for (int mi = 0; mi < 4; mi++) {
                bf16x8 aa = *reinterpret_cast<const bf16x8*>(&Aln[(mi * 16 + l16) * LP + kb + quad * 8]);
                acc1[mi] = MFMA16(aa, bv, acc1[mi]);
            }
        }
        float bias = bfc1[wave * 16 + l16];
#pragma unroll
        for (int mi = 0; mi < 4; mi++)
#pragma unroll
            for (int r = 0; r < 4; r++)
                Hc[0][(mi * 16 + quad * 4 + r) * LH + col] = f2bf(gelu_fast(acc1[mi][r] + bias));
    }
    f32x4 acc2[4][2] = {};
    for (int ch = 0; ch < 8; ch++) {
        __syncthreads();   // Hc[ch&1] ready; all reads of Hc[(ch+1)&1] (from ch-1) done
        int cur = ch & 1;
        const unsigned short* w2c = w2 + (long long)(wave * 32) * 1024 + ch * 128;
        const unsigned short* w1n = w1 + (long long)(((ch + 1) & 7) * 128 + wave * 16 + l16) * 256;
        bool do1 = (ch < 7);
        f32x4 nacc1[4] = {};
#pragma unroll
        for (int s = 0; s < 4; s++) {
            // fc2(ch), K-slice s*32 within chunk
            bf16x8 ah[4];
#pragma unroll
            for (int mi = 0; mi < 4; mi++)
                ah[mi] = *reinterpret_cast<const bf16x8*>(&Hc[cur][(mi * 16 + l16) * LH + s * 32 + quad * 8]);
#pragma unroll
            for (int ni = 0; ni < 2; ni++) {
                bf16x8 bv = *reinterpret_cast<const bf16x8*>(w2c + (long long)(ni * 16 + l16) * 1024 + s * 32 + quad * 8);
#pragma unroll
                for (int mi = 0; mi < 4; mi++)
                    acc2[mi][ni] = MFMA16(ah[mi], bv, acc2[mi][ni]);
            }
            // fc1(ch+1), two K-slices (independent of fc2's data)
            if (do1) {
#pragma unroll
                for (int t = 0; t < 2; t++) {
                    int kb = (s * 2 + t) * 32;
                    bf16x8 bv = *reinterpret_cast<const bf16x8*>(w1n + kb + quad * 8);
#pragma unroll
                    for (int mi = 0; mi < 4; mi++) {
                        bf16x8 aa = *reinterpret_cast<const bf16x8*>(&Aln[(mi * 16 + l16) * LP + kb + quad * 8]);
                        nacc1[mi] = MFMA16(aa, bv, nacc1[mi]);
                    }
                }
            }
        }
        if (do1) {
            float bias = bfc1[(ch + 1) * 128 + wave * 16 + l16];
#pragma unroll
            for (int mi = 0; mi < 4; mi++)
#pragma unroll
                for (int r = 0; r < 4; r++)
                    Hc[cur ^ 1][(mi * 16 + quad * 4 + r) * LH + col] = f2bf(gelu_fast(nacc1[mi][r] + bias));
        }
    }
#pragma unroll
    for (int ni = 0; ni < 2; ni++) {
        int n = wave * 32 + ni * 16 + l16;
        float bias = bfc2[n];
#pragma unroll
        for (int mi = 0; mi < 4; mi++) {
#pragma unroll
            for (int r = 0; r < 4; r++) {
                long long row = m0 + mi * 16 + quad * 4 + r;
                float xv = xio[row * 256 + n];
                xio[row * 256 + n] = xv + acc2[mi][ni][r] + bias;
            }
        }
    }
}

extern "C" void kernel_launch(void* const* d_in, const int* in_sizes, int n_in,
                              void* d_out, int out_size, void* d_ws, size_t ws_size,
                              hipStream_t stream) {
    const float* x      = (const float*)d_in[0];
    const float* ln1_g  = (const float*)d_in[1];
    const float* ln1_b  = (const float*)d_in[2];
    const float* ln2_g  = (const float*)d_in[3];
    const float* ln2_b  = (const float*)d_in[4];
    const float* rpe    = (const float*)d_in[5];
    const float* w_down = (const float*)d_in[6];
    const float* b_down = (const float*)d_in[7];
    const float* w_up   = (const float*)d_in[8];
    const float* b_up   = (const float*)d_in[9];
    const float* w_qkv  = (const float*)d_in[10];
    const float* b_qkv  = (const float*)d_in[11];
    const float* w_proj = (const float*)d_in[12];
    const float* b_proj = (const float*)d_in[13];
    const float* w_fc1  = (const float*)d_in[14];
    const float* b_fc1  = (const float*)d_in[15];
    const float* w_fc2  = (const float*)d_in[16];
    const float* b_fc2  = (const float*)d_in[17];
    float* out = (float*)d_out;

    char* wp = (char*)d_ws;
    auto alloc = [&](size_t bytes) { void* p = (void*)wp; wp += (bytes + 255) & ~(size_t)255; return p; };
    unsigned short* wdown_bf = (unsigned short*)alloc(4194304 * 2);
    unsigned short* wup_bf   = (unsigned short*)alloc(4194304 * 2);
    unsigned short* wqkv_bf  = (unsigned short*)alloc(196608 * 2);
    unsigned short* wproj_bf = (unsigned short*)alloc(65536 * 2);
    unsigned short* wfc1_bf  = (unsigned short*)alloc(262144 * 2);
    unsigned short* wfc2_bf  = (unsigned short*)alloc(262144 * 2);
    unsigned short* ydown    = (unsigned short*)alloc(524288 * 2);
    unsigned short* qb       = (unsigned short*)alloc(524288 * 2);
    unsigned short* kb       = (unsigned short*)alloc(524288 * 2);
    unsigned short* vT       = (unsigned short*)alloc(524288 * 2);
    unsigned short* obf      = (unsigned short*)alloc(524288 * 2);
    unsigned short* oproj    = (unsigned short*)alloc(524288 * 2);

    // Big temporaries live inside d_out (134.2 MB); all dead before k_up_fold
    // overwrites the whole buffer with x2.
    //   xln:  [0, 67.1 MB)        -- dead after k_gemm_down2
    //   part: [100.7, 134.2 MB)   -- 16 x 2 MB fp32 split-K partials
    unsigned short* xln = (unsigned short*)d_out;
    float* part         = (float*)((char*)d_out + 100663296);

    // one preamble launch: 8960 cvt blocks + 32768 LN blocks
    k_pre<<<41728, 256, 0, stream>>>(w_down, w_up, w_qkv, w_proj, w_fc1, w_fc2,
                                     wdown_bf, wup_bf, wqkv_bf, wproj_bf, wfc1_bf, wfc2_bf,
                                     x, ln1_g, ln1_b, xln);
    k_gemm_down2<<<dim3(16, 2, 16), 256, 0, stream>>>(xln, wdown_bf, part);
    k_red<<<512, 256, 0, stream>>>(part, b_down, ydown);
    k_gemm_qkv<<<dim3(32, 12), 256, 0, stream>>>(ydown, wqkv_bf, b_qkv, qb, kb, vT);
    k_attn<<<dim3(16, 16), 256, 0, stream>>>(qb, kb, vT, rpe, obf);
    k_gemm_proj<<<dim3(32, 4), 256, 0, stream>>>(obf, wproj_bf, b_proj, oproj);
    k_up_fold<<<dim3(128, 4), 256, 0, stream>>>(oproj, wup_bf, b_up, x, out);
    k_mlp<<<2048, 512, 0, stream>>>(out, ln2_g, ln2_b, wfc1_bf, b_fc1, wfc2_bf, b_fc2);
}